// Round 5
// baseline (341.867 us; speedup 1.0000x reference)
//
#include <hip/hip_runtime.h>
#include <math.h>

// Problem constants
#define BB 4
#define CINC 256
#define COUTC 128
#define HH 64
#define WW 64
#define OHH 128
#define OWW 128

typedef unsigned short u16;
typedef __attribute__((ext_vector_type(8))) short bf16x8;
typedef __attribute__((ext_vector_type(4))) float f32x4;

__device__ __forceinline__ u16 f2bf(float f) {
  unsigned int u = __float_as_uint(f);
  unsigned int r = u + 0x7FFFu + ((u >> 16) & 1u);  // RNE
  return (u16)(r >> 16);
}

// ---------------- K0t: dcn_w [o][c*9+q] -> bf16 wA[o][q*256+c]  (K reordered so a
// 32-wide K-chunk has constant tap q; contiguous k for MFMA A-frags)
__global__ __launch_bounds__(256) void k0t(const float* __restrict__ dcn_w, u16* __restrict__ wA) {
  int tid = blockIdx.x * 256 + threadIdx.x;
  if (tid >= COUTC * CINC * 9) return;
  int o = tid / 2304;
  int ckr = tid - o * 2304;
  int q = ckr >> 8;
  int c = ckr & 255;
  wA[tid] = f2bf(dcn_w[o * 2304 + c * 9 + q]);
}

// ---------------- K0o: off_w -> hi/lo bf16 split, padded to 32 rows.
// wOk[row][q*256+c] hi at [0, 73728), lo at [73728, 147456). rows 27..31 = 0.
__global__ __launch_bounds__(256) void k0o(const float* __restrict__ off_w, u16* __restrict__ wOk) {
  int tid = blockIdx.x * 256 + threadIdx.x;
  if (tid >= 32 * 2304) return;
  int row = tid / 2304;
  int kr = tid - row * 2304;
  int q = kr >> 8, c = kr & 255;
  float w = (row < 27) ? off_w[(row * CINC + c) * 9 + q] : 0.f;
  u16 hi = f2bf(w);
  float hf = __uint_as_float((unsigned)hi << 16);
  u16 lo = f2bf(w - hf);
  wOk[tid] = hi;
  wOk[73728 + tid] = lo;
}

// ---------------- K4w: pack up_w into 4 parity-class bf16 A-matrices.
__global__ __launch_bounds__(256) void k4w(const float* __restrict__ up_w, u16* __restrict__ Apk) {
  int tid = blockIdx.x * 256 + threadIdx.x;
  if (tid >= 4 * COUTC * 512) return;
  int kp = tid & 511;
  int o = (tid >> 9) & 127;
  int pq = tid >> 16;
  int p = pq >> 1, q = pq & 1;
  int ky = kp >> 8, kx = (kp >> 7) & 1, i = kp & 127;
  float v = up_w[((i * COUTC + o) * 4 + (3 - (p + 2 * ky))) * 4 + (3 - (q + 2 * kx))];
  Apk[tid] = f2bf(v);
}

// ---------------- K2t: transpose x[b][c][y][w] -> xT[b][y][w][c] (f32, channel-last).
__global__ __launch_bounds__(256) void k2t(const float* __restrict__ x, float* __restrict__ xT) {
  int y = blockIdx.x, cq = blockIdx.y, b = blockIdx.z;
  __shared__ float tile[64][65];
  int t = threadIdx.x;
  int tx = t & 63;
  int tg = t >> 6;
#pragma unroll
  for (int i = 0; i < 16; i++) {
    int c = tg * 16 + i;
    tile[c][tx] = x[((size_t)(b * CINC + cq * 64 + c) * HH + y) * WW + tx];
  }
  __syncthreads();
#pragma unroll
  for (int i = 0; i < 16; i++) {
    int xc = tg * 16 + i;
    xT[((size_t)(b * HH + y) * WW + xc) * CINC + cq * 64 + tx] = tile[tx][xc];
  }
}

// ---------------- K1m: offset conv as MFMA GEMM, fused bias+transform epilogue.
__global__ __launch_bounds__(256) void k1m(const float* __restrict__ xT,
                                           const u16* __restrict__ wOk,
                                           const float* __restrict__ off_b,
                                           float* __restrict__ pyg,
                                           float* __restrict__ pxg,
                                           float* __restrict__ mg) {
  int h = blockIdx.x, b = blockIdx.y;
  int t = threadIdx.x;
  int pt = t >> 6;
  int lane15 = t & 15;
  int quad = (t >> 4) & 3;

  const u16* wh0 = wOk + (size_t)lane15 * 2304 + quad * 8;
  const u16* wh1 = wh0 + 16 * 2304;
  const u16* wl0 = wh0 + 73728;
  const u16* wl1 = wh1 + 73728;

  f32x4 acc[2];
  acc[0] = (f32x4){0.f, 0.f, 0.f, 0.f};
  acc[1] = (f32x4){0.f, 0.f, 0.f, 0.f};

  for (int q = 0; q < 9; q++) {
    int y = h + q / 3 - 1;
    if ((unsigned)y >= 64u) continue;
    int xc = pt * 16 + lane15 + (q % 3) - 1;
    bool xok = (unsigned)xc < 64u;
    int xcc = min(max(xc, 0), 63);
    const float* bsrc = xT + (((size_t)(b * 64 + y) * 64 + xcc) * 256) + quad * 8;
#pragma unroll
    for (int c8 = 0; c8 < 8; c8++) {
      f32x4 v0 = *(const f32x4*)(bsrc + c8 * 32);
      f32x4 v1 = *(const f32x4*)(bsrc + c8 * 32 + 4);
      if (!xok) {
        v0 = (f32x4){0.f, 0.f, 0.f, 0.f};
        v1 = (f32x4){0.f, 0.f, 0.f, 0.f};
      }
      bf16x8 xh, xl;
#pragma unroll
      for (int j = 0; j < 4; j++) {
        u16 hv = f2bf(v0[j]);
        xh[j] = (short)hv;
        xl[j] = (short)f2bf(v0[j] - __uint_as_float((unsigned)hv << 16));
        u16 hv2 = f2bf(v1[j]);
        xh[4 + j] = (short)hv2;
        xl[4 + j] = (short)f2bf(v1[j] - __uint_as_float((unsigned)hv2 << 16));
      }
      int kk = (q * 8 + c8) * 32;
      bf16x8 ah0 = *(const bf16x8*)(wh0 + kk);
      bf16x8 ah1 = *(const bf16x8*)(wh1 + kk);
      bf16x8 al0 = *(const bf16x8*)(wl0 + kk);
      bf16x8 al1 = *(const bf16x8*)(wl1 + kk);
      acc[0] = __builtin_amdgcn_mfma_f32_16x16x32_bf16(ah0, xh, acc[0], 0, 0, 0);
      acc[0] = __builtin_amdgcn_mfma_f32_16x16x32_bf16(ah0, xl, acc[0], 0, 0, 0);
      acc[0] = __builtin_amdgcn_mfma_f32_16x16x32_bf16(al0, xh, acc[0], 0, 0, 0);
      acc[1] = __builtin_amdgcn_mfma_f32_16x16x32_bf16(ah1, xh, acc[1], 0, 0, 0);
      acc[1] = __builtin_amdgcn_mfma_f32_16x16x32_bf16(ah1, xl, acc[1], 0, 0, 0);
      acc[1] = __builtin_amdgcn_mfma_f32_16x16x32_bf16(al1, xh, acc[1], 0, 0, 0);
    }
  }

  int px = pt * 16 + lane15;
#pragma unroll
  for (int tr = 0; tr < 2; tr++) {
#pragma unroll
    for (int i = 0; i < 4; i++) {
      int oc = tr * 16 + quad * 4 + i;
      if (oc >= 27) continue;
      float v = acc[tr][i] + off_b[oc];
      if (oc < 9) {
        pyg[((b * 9 + oc) * 64 + h) * 64 + px] = v + (float)(oc / 3) - 1.f + (float)h;
      } else if (oc < 18) {
        int k = oc - 9;
        pxg[((b * 9 + k) * 64 + h) * 64 + px] = v + (float)(k % 3) - 1.f + (float)px;
      } else {
        int k = oc - 18;
        mg[((b * 9 + k) * 64 + h) * 64 + px] = 1.f / (1.f + expf(-v));
      }
    }
  }
}

// ---------------- gather: 4 corners x 8 contiguous channels from channel-last xT.
__device__ __forceinline__ void gatherC(const float* __restrict__ base,
                                        int sA0, int sA1, int sB0, int sB1,
                                        f32x4* rx) {
  const float* pA0 = base + (size_t)sA0 * CINC;
  const float* pA1 = base + (size_t)sA1 * CINC;
  const float* pB0 = base + (size_t)sB0 * CINC;
  const float* pB1 = base + (size_t)sB1 * CINC;
  rx[0] = *(const f32x4*)pA0;
  rx[1] = *(const f32x4*)(pA0 + 4);
  rx[2] = *(const f32x4*)pA1;
  rx[3] = *(const f32x4*)(pA1 + 4);
  rx[4] = *(const f32x4*)pB0;
  rx[5] = *(const f32x4*)(pB0 + 4);
  rx[6] = *(const f32x4*)pB1;
  rx[7] = *(const f32x4*)(pB1 + 4);
}

// ---------------- K2m: deformable conv, split-K(4), bf16 MFMA GEMM — REGISTER-ONLY.
// grid (4,64,4)=(ks,h,b), 256 thr. Thread (wave,quad,l15) owns px=wave*16+l15 and
// channel slice quad*8 of each 32-K chunk: its gathered+packed bf16x8 IS the MFMA
// B-fragment (B col=l15, k=quad*8+j). No LDS, no barriers — waves fully independent,
// TLP hides gather latency. Each wave runs all 8 cout-tiles (A-frags from L2-resident
// wA, row=tr*16+l15, k=quad*8+j). Descriptors recomputed per q (6 live VGPR).
// C/D: col=l15 (px within wave tile), row=quad*4+i (cout within tr tile).
__global__ __launch_bounds__(256) void k2m(const float* __restrict__ xT,
                                           const u16* __restrict__ wA,
                                           const float* __restrict__ pyg,
                                           const float* __restrict__ pxg,
                                           const float* __restrict__ mg,
                                           float* __restrict__ part2) {
  int ks = blockIdx.x, h = blockIdx.y, b = blockIdx.z;
  int t = threadIdx.x;
  int wave = t >> 6;
  int lane15 = t & 15;
  int quad = (t >> 4) & 3;
  int px = wave * 16 + lane15;

  f32x4 acc[8];
#pragma unroll
  for (int i = 0; i < 8; i++) acc[i] = (f32x4){0.f, 0.f, 0.f, 0.f};

  const float* xTb = xT + (size_t)b * 4096 * CINC;
  const u16* wAr = wA + (size_t)lane15 * 2304 + quad * 8;

  for (int q = 0; q < 9; q++) {
    // ---- per-(q,px) bilinear descriptor (4 quads of same px broadcast-load) ----
    int gi = ((b * 9 + q) * HH + h) * WW + px;
    float py = pyg[gi], pxx = pxg[gi], m = mg[gi];
    float y0f = floorf(py), x0f = floorf(pxx);
    float wy = py - y0f, wx = pxx - x0f;
    int y0 = (int)y0f, x0 = (int)x0f;
    bool vy0 = (unsigned)y0 < 64u, vy1 = (unsigned)(y0 + 1) < 64u;
    bool vx0 = (unsigned)x0 < 64u, vx1 = (unsigned)(x0 + 1) < 64u;
    int y0c = min(max(y0, 0), 63), y1c = min(max(y0 + 1, 0), 63);
    int x0c = min(max(x0, 0), 63), x1c = min(max(x0 + 1, 0), 63);
    float dw0 = (vy0 && vx0) ? (1.f - wy) * (1.f - wx) * m : 0.f;
    float dw1 = (vy0 && vx1) ? (1.f - wy) * wx * m : 0.f;
    float dw2 = (vy1 && vx0) ? wy * (1.f - wx) * m : 0.f;
    float dw3 = (vy1 && vx1) ? wy * wx * m : 0.f;
    int sA0 = y0c * 64 + x0c, sA1 = y0c * 64 + x1c;
    int sB0 = y1c * 64 + x0c, sB1 = y1c * 64 + x1c;

#pragma unroll
    for (int c32 = 0; c32 < 2; c32++) {
      int cb = ks * 64 + c32 * 32 + quad * 8;
      f32x4 rx[8];
      gatherC(xTb + cb, sA0, sA1, sB0, sB1, rx);
      float v[8];
#pragma unroll
      for (int j = 0; j < 4; j++) {
        v[j]     = dw0 * rx[0][j] + dw1 * rx[2][j] + dw2 * rx[4][j] + dw3 * rx[6][j];
        v[4 + j] = dw0 * rx[1][j] + dw1 * rx[3][j] + dw2 * rx[5][j] + dw3 * rx[7][j];
      }
      bf16x8 bfr;
#pragma unroll
      for (int j = 0; j < 8; j++) bfr[j] = (short)f2bf(v[j]);

      int kb = q * 256 + ks * 64 + c32 * 32;
#pragma unroll
      for (int tr = 0; tr < 8; tr++) {
        bf16x8 a = *(const bf16x8*)(wAr + (size_t)tr * 16 * 2304 + kb);
        acc[tr] = __builtin_amdgcn_mfma_f32_16x16x32_bf16(a, bfr, acc[tr], 0, 0, 0);
      }
    }
  }

  // write partials: part2[ks][b][o][h][w]; o = tr*16 + quad*4 + i, w = px
  float* pb = part2 + (size_t)ks * BB * COUTC * 4096;
#pragma unroll
  for (int tr = 0; tr < 8; tr++) {
    int o0 = tr * 16 + quad * 4;
#pragma unroll
    for (int i = 0; i < 4; i++)
      pb[((b * COUTC + o0 + i) * HH + h) * WW + px] = acc[tr][i];
  }
}

// ---------------- K2r: sum 4 partials + bias -> out1
__global__ __launch_bounds__(256) void k2r(const float* __restrict__ part2,
                                           const float* __restrict__ dcn_b,
                                           float* __restrict__ out1) {
  int tid = blockIdx.x * 256 + threadIdx.x;
  if (tid >= BB * COUTC * HH * WW) return;
  int o = (tid >> 12) & 127;
  const int S = BB * COUTC * 4096;
  out1[tid] = part2[tid] + part2[tid + S] + part2[tid + 2 * S] + part2[tid + 3 * S] + dcn_b[o];
}

// ---------------- BN stats: single-pass split reduction (sum + sumsq).
template <int PLANEF4, int NCHUNK>
__global__ __launch_bounds__(256) void bn_part(const float* __restrict__ src,
                                               float* __restrict__ psum,
                                               float* __restrict__ pssq) {
  int c = blockIdx.x, chunk = blockIdx.y, t = threadIdx.x;
  constexpr int PER = (BB * PLANEF4) / NCHUNK;  // float4s per chunk
  float s = 0.f, s2 = 0.f;
#pragma unroll
  for (int i = 0; i < PER / 256; i++) {
    int f = chunk * PER + i * 256 + t;
    int b = f / PLANEF4;  // compile-time divisor -> shifts
    int sp = f - b * PLANEF4;
    const float4 v = *(const float4*)&src[((size_t)(b * COUTC + c) * PLANEF4 + sp) * 4];
    s += v.x + v.y + v.z + v.w;
    s2 += v.x * v.x + v.y * v.y + v.z * v.z + v.w * v.w;
  }
#pragma unroll
  for (int off = 32; off > 0; off >>= 1) {
    s += __shfl_down(s, off);
    s2 += __shfl_down(s2, off);
  }
  __shared__ float rs[4], rq[4];
  int wv = t >> 6;
  if ((t & 63) == 0) { rs[wv] = s; rq[wv] = s2; }
  __syncthreads();
  if (t == 0) {
    psum[c * NCHUNK + chunk] = rs[0] + rs[1] + rs[2] + rs[3];
    pssq[c * NCHUNK + chunk] = rq[0] + rq[1] + rq[2] + rq[3];
  }
}

// finalize: 1 block x 128 threads; per-channel scale/shift from partials
__global__ __launch_bounds__(128) void bn_fin(const float* __restrict__ psum,
                                              const float* __restrict__ pssq,
                                              const float* __restrict__ g,
                                              const float* __restrict__ bt,
                                              float* __restrict__ scale,
                                              float* __restrict__ shift,
                                              int nchunk, float invN) {
  int c = threadIdx.x;
  float S = 0.f, Q = 0.f;
  for (int i = 0; i < nchunk; i++) {
    S += psum[c * nchunk + i];
    Q += pssq[c * nchunk + i];
  }
  float mu = S * invN;
  float var = Q * invN - mu * mu;
  float sc = g[c] * rsqrtf(var + 1e-5f);
  scale[c] = sc;
  shift[c] = bt[c] - mu * sc;
}

// ---------------- K4a: bn1+relu apply, bf16 convert, channel-last transpose.
__global__ __launch_bounds__(256) void k4a(const float* __restrict__ out1,
                                           const float* __restrict__ s1,
                                           const float* __restrict__ sh1,
                                           u16* __restrict__ yT) {
  int m = blockIdx.x, b = blockIdx.y;
  __shared__ __align__(16) u16 T2[64 * 136];
  int t = threadIdx.x;
  for (int e = t; e < 2048; e += 256) {
    int w4 = e & 15, c = e >> 4;
    float4 r = *(const float4*)&out1[((b * COUTC + c) * HH + m) * WW + w4 * 4];
    float sc = s1[c], sh = sh1[c];
    T2[(w4 * 4 + 0) * 136 + c] = f2bf(fmaxf(fmaf(r.x, sc, sh), 0.f));
    T2[(w4 * 4 + 1) * 136 + c] = f2bf(fmaxf(fmaf(r.y, sc, sh), 0.f));
    T2[(w4 * 4 + 2) * 136 + c] = f2bf(fmaxf(fmaf(r.z, sc, sh), 0.f));
    T2[(w4 * 4 + 3) * 136 + c] = f2bf(fmaxf(fmaf(r.w, sc, sh), 0.f));
  }
  __syncthreads();
  for (int e = t; e < 1024; e += 256) {
    int g2 = e * 8;
    int w = g2 >> 7, i = g2 & 127;
    *(bf16x8*)&yT[((size_t)(b * 64 + m) * 64 + w) * 128 + i] =
        *(const bf16x8*)&T2[w * 136 + i];
  }
}

// ---------------- K4m: transposed conv as bf16 MFMA GEMM.
__global__ __launch_bounds__(256) void k4m(const u16* __restrict__ yT,
                                           const u16* __restrict__ Apk,
                                           float* __restrict__ out2) {
  int oh = blockIdx.x, b = blockIdx.y;
  int a = oh >> 1, p = oh & 1;
  __shared__ __align__(16) u16 T[2][66 * 136];
  int t = threadIdx.x;
  int wave = t >> 6, lane15 = t & 15, quad = (t >> 4) & 3;

  // zero border cols: 2 bufs x 2 cols x 128 ch
  for (int e = t; e < 512; e += 256) {
    int ky = e >> 8;
    int rem = e & 255;
    int colp = (rem >> 7) * 65;
    int i = rem & 127;
    T[ky][colp * 136 + i] = 0;
  }
  // stage both tap rows (r = a+p+ky-1); contiguous 16KB copy each
#pragma unroll
  for (int ky = 0; ky < 2; ky++) {
    int r = a + p + ky - 1;
    bool ok = ((unsigned)r < 64u);
    const u16* src = yT + ((size_t)(b * 64 + r) * 64) * 128;
#pragma unroll
    for (int it = 0; it < 4; it++) {
      int g2 = (it * 256 + t) * 8;
      int col = g2 >> 7, i = g2 & 127;
      bf16x8 v = (bf16x8){0, 0, 0, 0, 0, 0, 0, 0};
      if (ok) v = *(const bf16x8*)(src + g2);
      *(bf16x8*)&T[ky][(col + 1) * 136 + i] = v;
    }
  }
  __syncthreads();

  f32x4 acc[2][2][4];  // [q][tr][pc]
#pragma unroll
  for (int q = 0; q < 2; q++)
#pragma unroll
    for (int tr = 0; tr < 2; tr++)
#pragma unroll
      for (int pc = 0; pc < 4; pc++) acc[q][tr][pc] = (f32x4){0.f, 0.f, 0.f, 0.f};

  int row0 = wave * 32 + lane15;
  const u16* A0 = Apk + ((size_t)(p * 2 + 0) * 128) * 512;
  const u16* A1 = Apk + ((size_t)(p * 2 + 1) * 128) * 512;

#pragma unroll
  for (int ky = 0; ky < 2; ky++)
#pragma unroll
    for (int kx = 0; kx < 2; kx++)
#pragma unroll
      for (int c4 = 0; c4 < 4; c4++) {
        int kb = (ky * 2 + kx) * 128 + c4 * 32 + quad * 8;
        bf16x8 a00 = *(const bf16x8*)(A0 + (size_t)row0 * 512 + kb);
        bf16x8 a01 = *(const bf16x8*)(A0 + (size_t)(row0 + 16) * 512 + kb);
        bf16x8 a10 = *(const bf16x8*)(A1 + (size_t)row0 * 512 + kb);
        bf16x8 a11 = *(const bf16x8*)(A1 + (size_t)(row0 + 16) * 512 + kb);
        const u16* tb = &T[ky][(lane15 + kx) * 136 + c4 * 32 + quad * 8];
#pragma unroll
        for (int pc = 0; pc < 4; pc++) {
          bf16x8 b0 = *(const bf16x8*)(tb + (pc * 16) * 136);
          bf16x8 b1 = *(const bf16x8*)(tb + (pc * 16 + 1) * 136);
          acc[0][0][pc] = __builtin_amdgcn_mfma_f32_16x16x32_bf16(a00, b0, acc[0][0][pc], 0, 0, 0);
          acc[0][1][pc] = __builtin_amdgcn_mfma_f32_16x16x32_bf16(a01, b0, acc[0][1][pc], 0, 0, 0);
          acc[1][0][pc] = __builtin_amdgcn_mfma_f32_16x16x32_bf16(a10, b1, acc[1][0][pc], 0, 0, 0);
          acc[1][1][pc] = __builtin_amdgcn_mfma_f32_16x16x32_bf16(a11, b1, acc[1][1][pc], 0, 0, 0);
        }
      }

  // epilogue: C/D col=lane&15 (px), row=quad*4+i (cout). ow = 2*px + q -> float2.
#pragma unroll
  for (int tr = 0; tr < 2; tr++) {
    int o0 = wave * 32 + tr * 16 + quad * 4;
#pragma unroll
    for (int pc = 0; pc < 4; pc++) {
      f32x4 v0 = acc[0][tr][pc];
      f32x4 v1 = acc[1][tr][pc];
      int cw = pc * 32 + 2 * lane15;
#pragma unroll
      for (int i = 0; i < 4; i++) {
        float2 w2;
        w2.x = v0[i];
        w2.y = v1[i];
        *(float2*)&out2[(((size_t)b * COUTC + o0 + i) * OHH + oh) * OWW + cw] = w2;
      }
    }
  }
}

// ---------------- K6: bn2+relu apply (f32 out)
__global__ __launch_bounds__(256) void k6s(const float* __restrict__ out2,
                                           const float* __restrict__ scale2,
                                           const float* __restrict__ shift2,
                                           float* __restrict__ outp) {
  int tid = blockIdx.x * 256 + threadIdx.x;
  if (tid >= BB * COUTC * OHH * OWW) return;
  int c = (tid >> 14) & 127;
  outp[tid] = fmaxf(fmaf(out2[tid], scale2[c], shift2[c]), 0.f);
}

// ---------------- launch
extern "C" void kernel_launch(void* const* d_in, const int* in_sizes, int n_in,
                              void* d_out, int out_size, void* d_ws, size_t ws_size,
                              hipStream_t stream) {
  const float* x     = (const float*)d_in[0];
  const float* off_w = (const float*)d_in[1];
  const float* off_b = (const float*)d_in[2];
  const float* dcn_w = (const float*)d_in[3];
  const float* dcn_b = (const float*)d_in[4];
  const float* bn1_g = (const float*)d_in[5];
  const float* bn1_b = (const float*)d_in[6];
  const float* up_w  = (const float*)d_in[7];
  const float* bn2_g = (const float*)d_in[8];
  const float* bn2_b = (const float*)d_in[9];

  float* ws = (float*)d_ws;
  float* pyg  = ws;                              // 147456
  float* pxg  = pyg + BB * 9 * HH * WW;          // 147456
  float* mg   = pxg + BB * 9 * HH * WW;          // 147456
  float* out1 = mg + BB * 9 * HH * WW;           // 2097152
  float* scale1 = out1 + BB * COUTC * HH * WW;   // 128
  float* shift1 = scale1 + 128;                  // 128
  float* out2 = shift1 + 128;                    // 8388608
  float* scale2 = out2 + BB * COUTC * OHH * OWW; // 128
  float* shift2 = scale2 + 128;                  // 128
  float* w_t = shift2 + 128;                     // 294912 floats reserved
  float* wt4 = w_t + COUTC * CINC * 9;           // 262144 floats (Apk uses as u16)
  float* part2 = wt4 + 4 * COUTC * COUTC * 4;    // 4 * 2097152
  u16* wA = (u16*)w_t;                           // 128*2304 bf16 (first half of w_t region)
  u16* wOk = (u16*)(w_t + 147456);               // 2*32*2304 bf16 hi/lo (second half)
  u16* Apk = (u16*)wt4;                          // 4*128*512 bf16 = 512KB
  // xT (f32 channel-last, 4.19M floats) overlaid on out2 region:
  // lifetime k2t..k2m, dead before k4m writes out2.
  float* xT = out2;
  // bn stats partials overlaid on part2 start (dead after k2r)
  float* psum = part2;            // up to 128*16
  float* pssq = part2 + 128 * 16; // up to 128*16
  // yT (bf16 4MB) overlaid past the stats partials in the part2 region
  u16* yT = (u16*)(part2 + 8192);

  const int N4 = BB * COUTC * OHH * OWW;  // 8388608
  const int N2 = BB * COUTC * HH * WW;    // 2097152

  k0t<<<(COUTC * CINC * 9 + 255) / 256, 256, 0, stream>>>(dcn_w, wA);
  k0o<<<(32 * 2304 + 255) / 256, 256, 0, stream>>>(off_w, wOk);
  k4w<<<(4 * COUTC * 512 + 255) / 256, 256, 0, stream>>>(up_w, Apk);
  // channel-last transpose of x (into out2 region)
  k2t<<<dim3(64, 4, 4), 256, 0, stream>>>(x, xT);
  // offset conv via MFMA (fused bias + py/px/sigmoid epilogue)
  k1m<<<dim3(64, 4), 256, 0, stream>>>(xT, wOk, off_b, pyg, pxg, mg);
  // deformable conv via register-only MFMA (no LDS, no barriers)
  k2m<<<dim3(4, 64, 4), 256, 0, stream>>>(xT, wA, pyg, pxg, mg, part2);
  k2r<<<(N2 + 255) / 256, 256, 0, stream>>>(part2, dcn_b, out1);
  // bn1 stats
  bn_part<1024, 8><<<dim3(COUTC, 8), 256, 0, stream>>>(out1, psum, pssq);
  bn_fin<<<1, 128, 0, stream>>>(psum, pssq, bn1_g, bn1_b, scale1, shift1, 8,
                                1.f / 16384.f);
  // bn1 apply + transpose to bf16 channel-last
  k4a<<<dim3(64, 4), 256, 0, stream>>>(out1, scale1, shift1, yT);
  // transposed conv via MFMA
  k4m<<<dim3(128, 4), 256, 0, stream>>>(yT, Apk, out2);
  // bn2 stats
  bn_part<4096, 16><<<dim3(COUTC, 16), 256, 0, stream>>>(out2, psum, pssq);
  bn_fin<<<1, 128, 0, stream>>>(psum, pssq, bn2_g, bn2_b, scale2, shift2, 16,
                                1.f / 65536.f);
  k6s<<<(N4 + 255) / 256, 256, 0, stream>>>(out2, scale2, shift2, (float*)d_out);
}

// Round 6
// 338.038 us; speedup vs baseline: 1.0113x; 1.0113x over previous
//
#include <hip/hip_runtime.h>
#include <math.h>

// Problem constants
#define BB 4
#define CINC 256
#define COUTC 128
#define HH 64
#define WW 64
#define OHH 128
#define OWW 128

typedef unsigned short u16;
typedef __attribute__((ext_vector_type(8))) short bf16x8;
typedef __attribute__((ext_vector_type(4))) float f32x4;

__device__ __forceinline__ u16 f2bf(float f) {
  unsigned int u = __float_as_uint(f);
  unsigned int r = u + 0x7FFFu + ((u >> 16) & 1u);  // RNE
  return (u16)(r >> 16);
}

// ---------------- K0t: dcn_w [o][c*9+q] -> bf16 wA[o][q*256+c]
__global__ __launch_bounds__(256) void k0t(const float* __restrict__ dcn_w, u16* __restrict__ wA) {
  int tid = blockIdx.x * 256 + threadIdx.x;
  if (tid >= COUTC * CINC * 9) return;
  int o = tid / 2304;
  int ckr = tid - o * 2304;
  int q = ckr >> 8;
  int c = ckr & 255;
  wA[tid] = f2bf(dcn_w[o * 2304 + c * 9 + q]);
}

// ---------------- K0o: off_w -> hi/lo bf16 split, padded to 32 rows.
__global__ __launch_bounds__(256) void k0o(const float* __restrict__ off_w, u16* __restrict__ wOk) {
  int tid = blockIdx.x * 256 + threadIdx.x;
  if (tid >= 32 * 2304) return;
  int row = tid / 2304;
  int kr = tid - row * 2304;
  int q = kr >> 8, c = kr & 255;
  float w = (row < 27) ? off_w[(row * CINC + c) * 9 + q] : 0.f;
  u16 hi = f2bf(w);
  float hf = __uint_as_float((unsigned)hi << 16);
  u16 lo = f2bf(w - hf);
  wOk[tid] = hi;
  wOk[73728 + tid] = lo;
}

// ---------------- K4w: pack up_w into 4 parity-class bf16 A-matrices.
__global__ __launch_bounds__(256) void k4w(const float* __restrict__ up_w, u16* __restrict__ Apk) {
  int tid = blockIdx.x * 256 + threadIdx.x;
  if (tid >= 4 * COUTC * 512) return;
  int kp = tid & 511;
  int o = (tid >> 9) & 127;
  int pq = tid >> 16;
  int p = pq >> 1, q = pq & 1;
  int ky = kp >> 8, kx = (kp >> 7) & 1, i = kp & 127;
  float v = up_w[((i * COUTC + o) * 4 + (3 - (p + 2 * ky))) * 4 + (3 - (q + 2 * kx))];
  Apk[tid] = f2bf(v);
}

// ---------------- K2t: transpose x[b][c][y][w] -> xT[b][y][w][c] (f32, channel-last).
__global__ __launch_bounds__(256) void k2t(const float* __restrict__ x, float* __restrict__ xT) {
  int y = blockIdx.x, cq = blockIdx.y, b = blockIdx.z;
  __shared__ float tile[64][65];
  int t = threadIdx.x;
  int tx = t & 63;
  int tg = t >> 6;
#pragma unroll
  for (int i = 0; i < 16; i++) {
    int c = tg * 16 + i;
    tile[c][tx] = x[((size_t)(b * CINC + cq * 64 + c) * HH + y) * WW + tx];
  }
  __syncthreads();
#pragma unroll
  for (int i = 0; i < 16; i++) {
    int xc = tg * 16 + i;
    xT[((size_t)(b * HH + y) * WW + xc) * CINC + cq * 64 + tx] = tile[tx][xc];
  }
}

// ---------------- K1m: offset conv as MFMA GEMM, fused bias+transform epilogue.
__global__ __launch_bounds__(256) void k1m(const float* __restrict__ xT,
                                           const u16* __restrict__ wOk,
                                           const float* __restrict__ off_b,
                                           float* __restrict__ pyg,
                                           float* __restrict__ pxg,
                                           float* __restrict__ mg) {
  int h = blockIdx.x, b = blockIdx.y;
  int t = threadIdx.x;
  int pt = t >> 6;
  int lane15 = t & 15;
  int quad = (t >> 4) & 3;

  const u16* wh0 = wOk + (size_t)lane15 * 2304 + quad * 8;
  const u16* wh1 = wh0 + 16 * 2304;
  const u16* wl0 = wh0 + 73728;
  const u16* wl1 = wh1 + 73728;

  f32x4 acc[2];
  acc[0] = (f32x4){0.f, 0.f, 0.f, 0.f};
  acc[1] = (f32x4){0.f, 0.f, 0.f, 0.f};

  for (int q = 0; q < 9; q++) {
    int y = h + q / 3 - 1;
    if ((unsigned)y >= 64u) continue;
    int xc = pt * 16 + lane15 + (q % 3) - 1;
    bool xok = (unsigned)xc < 64u;
    int xcc = min(max(xc, 0), 63);
    const float* bsrc = xT + (((size_t)(b * 64 + y) * 64 + xcc) * 256) + quad * 8;
#pragma unroll
    for (int c8 = 0; c8 < 8; c8++) {
      f32x4 v0 = *(const f32x4*)(bsrc + c8 * 32);
      f32x4 v1 = *(const f32x4*)(bsrc + c8 * 32 + 4);
      if (!xok) {
        v0 = (f32x4){0.f, 0.f, 0.f, 0.f};
        v1 = (f32x4){0.f, 0.f, 0.f, 0.f};
      }
      bf16x8 xh, xl;
#pragma unroll
      for (int j = 0; j < 4; j++) {
        u16 hv = f2bf(v0[j]);
        xh[j] = (short)hv;
        xl[j] = (short)f2bf(v0[j] - __uint_as_float((unsigned)hv << 16));
        u16 hv2 = f2bf(v1[j]);
        xh[4 + j] = (short)hv2;
        xl[4 + j] = (short)f2bf(v1[j] - __uint_as_float((unsigned)hv2 << 16));
      }
      int kk = (q * 8 + c8) * 32;
      bf16x8 ah0 = *(const bf16x8*)(wh0 + kk);
      bf16x8 ah1 = *(const bf16x8*)(wh1 + kk);
      bf16x8 al0 = *(const bf16x8*)(wl0 + kk);
      bf16x8 al1 = *(const bf16x8*)(wl1 + kk);
      acc[0] = __builtin_amdgcn_mfma_f32_16x16x32_bf16(ah0, xh, acc[0], 0, 0, 0);
      acc[0] = __builtin_amdgcn_mfma_f32_16x16x32_bf16(ah0, xl, acc[0], 0, 0, 0);
      acc[0] = __builtin_amdgcn_mfma_f32_16x16x32_bf16(al0, xh, acc[0], 0, 0, 0);
      acc[1] = __builtin_amdgcn_mfma_f32_16x16x32_bf16(ah1, xh, acc[1], 0, 0, 0);
      acc[1] = __builtin_amdgcn_mfma_f32_16x16x32_bf16(ah1, xl, acc[1], 0, 0, 0);
      acc[1] = __builtin_amdgcn_mfma_f32_16x16x32_bf16(al1, xh, acc[1], 0, 0, 0);
    }
  }

  int px = pt * 16 + lane15;
#pragma unroll
  for (int tr = 0; tr < 2; tr++) {
#pragma unroll
    for (int i = 0; i < 4; i++) {
      int oc = tr * 16 + quad * 4 + i;
      if (oc >= 27) continue;
      float v = acc[tr][i] + off_b[oc];
      if (oc < 9) {
        pyg[((b * 9 + oc) * 64 + h) * 64 + px] = v + (float)(oc / 3) - 1.f + (float)h;
      } else if (oc < 18) {
        int k = oc - 9;
        pxg[((b * 9 + k) * 64 + h) * 64 + px] = v + (float)(k % 3) - 1.f + (float)px;
      } else {
        int k = oc - 18;
        mg[((b * 9 + k) * 64 + h) * 64 + px] = 1.f / (1.f + expf(-v));
      }
    }
  }
}

// ---------------- gather: 4 corners x 8 contiguous channels from channel-last xT.
__device__ __forceinline__ void gatherC(const float* __restrict__ base,
                                        int sA0, int sA1, int sB0, int sB1,
                                        f32x4* rx) {
  const float* pA0 = base + (size_t)sA0 * CINC;
  const float* pA1 = base + (size_t)sA1 * CINC;
  const float* pB0 = base + (size_t)sB0 * CINC;
  const float* pB1 = base + (size_t)sB1 * CINC;
  rx[0] = *(const f32x4*)pA0;
  rx[1] = *(const f32x4*)(pA0 + 4);
  rx[2] = *(const f32x4*)pA1;
  rx[3] = *(const f32x4*)(pA1 + 4);
  rx[4] = *(const f32x4*)pB0;
  rx[5] = *(const f32x4*)(pB0 + 4);
  rx[6] = *(const f32x4*)pB1;
  rx[7] = *(const f32x4*)(pB1 + 4);
}

// ---------------- K2m: deformable conv, split-K(4), register-only MFMA GEMM,
// q-level SW-pipelined. Thread (wave,quad,l15) owns px=wave*16+l15, channels quad*8:
// its packed bf16x8 IS the MFMA B-fragment (no LDS, no barriers). PIPELINE: the
// descriptors + all 16 gathers of tap q+1 are issued BEFORE the pack+16 MFMAs of
// tap q (double-buffered rx/dw/so, fully unrolled so ping-pong indices are
// compile-time -> registers). launch_bounds(256,2): VGPR<=256, 2 blocks/CU.
__global__ __launch_bounds__(256, 2) void k2m(const float* __restrict__ xT,
                                              const u16* __restrict__ wA,
                                              const float* __restrict__ pyg,
                                              const float* __restrict__ pxg,
                                              const float* __restrict__ mg,
                                              float* __restrict__ part2) {
  int ks = blockIdx.x, h = blockIdx.y, b = blockIdx.z;
  int t = threadIdx.x;
  int wave = t >> 6;
  int lane15 = t & 15;
  int quad = (t >> 4) & 3;
  int px = wave * 16 + lane15;

  f32x4 acc[8];
#pragma unroll
  for (int i = 0; i < 8; i++) acc[i] = (f32x4){0.f, 0.f, 0.f, 0.f};

  const float* xTb = xT + (size_t)b * 4096 * CINC + ks * 64 + quad * 8;
  const u16* wAr = wA + (size_t)lane15 * 2304 + quad * 8;

  float dw[2][4];
  int so[2][4];
  f32x4 rx[2][16];

  auto DESC = [&](int q, float* dwp, int* sop) {
    int gi = ((b * 9 + q) * HH + h) * WW + px;
    float py = pyg[gi], pxx = pxg[gi], m = mg[gi];
    float y0f = floorf(py), x0f = floorf(pxx);
    float wy = py - y0f, wx = pxx - x0f;
    int y0 = (int)y0f, x0 = (int)x0f;
    bool vy0 = (unsigned)y0 < 64u, vy1 = (unsigned)(y0 + 1) < 64u;
    bool vx0 = (unsigned)x0 < 64u, vx1 = (unsigned)(x0 + 1) < 64u;
    int y0c = min(max(y0, 0), 63), y1c = min(max(y0 + 1, 0), 63);
    int x0c = min(max(x0, 0), 63), x1c = min(max(x0 + 1, 0), 63);
    dwp[0] = (vy0 && vx0) ? (1.f - wy) * (1.f - wx) * m : 0.f;
    dwp[1] = (vy0 && vx1) ? (1.f - wy) * wx * m : 0.f;
    dwp[2] = (vy1 && vx0) ? wy * (1.f - wx) * m : 0.f;
    dwp[3] = (vy1 && vx1) ? wy * wx * m : 0.f;
    sop[0] = y0c * 64 + x0c;
    sop[1] = y0c * 64 + x1c;
    sop[2] = y1c * 64 + x0c;
    sop[3] = y1c * 64 + x1c;
  };

  // prologue: tap 0 descriptors + gathers (both 32-ch chunks)
  DESC(0, dw[0], so[0]);
  gatherC(xTb, so[0][0], so[0][1], so[0][2], so[0][3], &rx[0][0]);
  gatherC(xTb + 32, so[0][0], so[0][1], so[0][2], so[0][3], &rx[0][8]);

#pragma unroll
  for (int q = 0; q < 9; q++) {
    const int cur = q & 1, nxt = cur ^ 1;
    // issue tap q+1's descriptor loads + 16 gathers (land during this tap's MFMAs)
    if (q < 8) {
      DESC(q + 1, dw[nxt], so[nxt]);
      gatherC(xTb, so[nxt][0], so[nxt][1], so[nxt][2], so[nxt][3], &rx[nxt][0]);
      gatherC(xTb + 32, so[nxt][0], so[nxt][1], so[nxt][2], so[nxt][3], &rx[nxt][8]);
    }
#pragma unroll
    for (int c32 = 0; c32 < 2; c32++) {
      const f32x4* r = &rx[cur][c32 * 8];
      float v[8];
#pragma unroll
      for (int j = 0; j < 4; j++) {
        v[j] = dw[cur][0] * r[0][j] + dw[cur][1] * r[2][j] +
               dw[cur][2] * r[4][j] + dw[cur][3] * r[6][j];
        v[4 + j] = dw[cur][0] * r[1][j] + dw[cur][1] * r[3][j] +
                   dw[cur][2] * r[5][j] + dw[cur][3] * r[7][j];
      }
      bf16x8 bfr;
#pragma unroll
      for (int j = 0; j < 8; j++) bfr[j] = (short)f2bf(v[j]);

      int kb = q * 256 + ks * 64 + c32 * 32;
#pragma unroll
      for (int tr = 0; tr < 8; tr++) {
        bf16x8 a = *(const bf16x8*)(wAr + (size_t)tr * 16 * 2304 + kb);
        acc[tr] = __builtin_amdgcn_mfma_f32_16x16x32_bf16(a, bfr, acc[tr], 0, 0, 0);
      }
    }
  }

  // write partials: part2[ks][b][o][h][w]; o = tr*16 + quad*4 + i, w = px
  float* pb = part2 + (size_t)ks * BB * COUTC * 4096;
#pragma unroll
  for (int tr = 0; tr < 8; tr++) {
    int o0 = tr * 16 + quad * 4;
#pragma unroll
    for (int i = 0; i < 4; i++)
      pb[((b * COUTC + o0 + i) * HH + h) * WW + px] = acc[tr][i];
  }
}

// ---------------- K2r: sum 4 partials + bias -> out1
__global__ __launch_bounds__(256) void k2r(const float* __restrict__ part2,
                                           const float* __restrict__ dcn_b,
                                           float* __restrict__ out1) {
  int tid = blockIdx.x * 256 + threadIdx.x;
  if (tid >= BB * COUTC * HH * WW) return;
  int o = (tid >> 12) & 127;
  const int S = BB * COUTC * 4096;
  out1[tid] = part2[tid] + part2[tid + S] + part2[tid + 2 * S] + part2[tid + 3 * S] + dcn_b[o];
}

// ---------------- BN stats: single-pass split reduction (sum + sumsq).
template <int PLANEF4, int NCHUNK>
__global__ __launch_bounds__(256) void bn_part(const float* __restrict__ src,
                                               float* __restrict__ psum,
                                               float* __restrict__ pssq) {
  int c = blockIdx.x, chunk = blockIdx.y, t = threadIdx.x;
  constexpr int PER = (BB * PLANEF4) / NCHUNK;  // float4s per chunk
  float s = 0.f, s2 = 0.f;
#pragma unroll
  for (int i = 0; i < PER / 256; i++) {
    int f = chunk * PER + i * 256 + t;
    int b = f / PLANEF4;  // compile-time divisor -> shifts
    int sp = f - b * PLANEF4;
    const float4 v = *(const float4*)&src[((size_t)(b * COUTC + c) * PLANEF4 + sp) * 4];
    s += v.x + v.y + v.z + v.w;
    s2 += v.x * v.x + v.y * v.y + v.z * v.z + v.w * v.w;
  }
#pragma unroll
  for (int off = 32; off > 0; off >>= 1) {
    s += __shfl_down(s, off);
    s2 += __shfl_down(s2, off);
  }
  __shared__ float rs[4], rq[4];
  int wv = t >> 6;
  if ((t & 63) == 0) { rs[wv] = s; rq[wv] = s2; }
  __syncthreads();
  if (t == 0) {
    psum[c * NCHUNK + chunk] = rs[0] + rs[1] + rs[2] + rs[3];
    pssq[c * NCHUNK + chunk] = rq[0] + rq[1] + rq[2] + rq[3];
  }
}

// finalize: 1 block x 128 threads; per-channel scale/shift from partials
__global__ __launch_bounds__(128) void bn_fin(const float* __restrict__ psum,
                                              const float* __restrict__ pssq,
                                              const float* __restrict__ g,
                                              const float* __restrict__ bt,
                                              float* __restrict__ scale,
                                              float* __restrict__ shift,
                                              int nchunk, float invN) {
  int c = threadIdx.x;
  float S = 0.f, Q = 0.f;
  for (int i = 0; i < nchunk; i++) {
    S += psum[c * nchunk + i];
    Q += pssq[c * nchunk + i];
  }
  float mu = S * invN;
  float var = Q * invN - mu * mu;
  float sc = g[c] * rsqrtf(var + 1e-5f);
  scale[c] = sc;
  shift[c] = bt[c] - mu * sc;
}

// ---------------- K4a: bn1+relu apply, bf16 convert, channel-last transpose.
__global__ __launch_bounds__(256) void k4a(const float* __restrict__ out1,
                                           const float* __restrict__ s1,
                                           const float* __restrict__ sh1,
                                           u16* __restrict__ yT) {
  int m = blockIdx.x, b = blockIdx.y;
  __shared__ __align__(16) u16 T2[64 * 136];
  int t = threadIdx.x;
  for (int e = t; e < 2048; e += 256) {
    int w4 = e & 15, c = e >> 4;
    float4 r = *(const float4*)&out1[((b * COUTC + c) * HH + m) * WW + w4 * 4];
    float sc = s1[c], sh = sh1[c];
    T2[(w4 * 4 + 0) * 136 + c] = f2bf(fmaxf(fmaf(r.x, sc, sh), 0.f));
    T2[(w4 * 4 + 1) * 136 + c] = f2bf(fmaxf(fmaf(r.y, sc, sh), 0.f));
    T2[(w4 * 4 + 2) * 136 + c] = f2bf(fmaxf(fmaf(r.z, sc, sh), 0.f));
    T2[(w4 * 4 + 3) * 136 + c] = f2bf(fmaxf(fmaf(r.w, sc, sh), 0.f));
  }
  __syncthreads();
  for (int e = t; e < 1024; e += 256) {
    int g2 = e * 8;
    int w = g2 >> 7, i = g2 & 127;
    *(bf16x8*)&yT[((size_t)(b * 64 + m) * 64 + w) * 128 + i] =
        *(const bf16x8*)&T2[w * 136 + i];
  }
}

// ---------------- K4m: transposed conv as bf16 MFMA GEMM.
__global__ __launch_bounds__(256) void k4m(const u16* __restrict__ yT,
                                           const u16* __restrict__ Apk,
                                           float* __restrict__ out2) {
  int oh = blockIdx.x, b = blockIdx.y;
  int a = oh >> 1, p = oh & 1;
  __shared__ __align__(16) u16 T[2][66 * 136];
  int t = threadIdx.x;
  int wave = t >> 6, lane15 = t & 15, quad = (t >> 4) & 3;

  // zero border cols: 2 bufs x 2 cols x 128 ch
  for (int e = t; e < 512; e += 256) {
    int ky = e >> 8;
    int rem = e & 255;
    int colp = (rem >> 7) * 65;
    int i = rem & 127;
    T[ky][colp * 136 + i] = 0;
  }
  // stage both tap rows (r = a+p+ky-1); contiguous 16KB copy each
#pragma unroll
  for (int ky = 0; ky < 2; ky++) {
    int r = a + p + ky - 1;
    bool ok = ((unsigned)r < 64u);
    const u16* src = yT + ((size_t)(b * 64 + r) * 64) * 128;
#pragma unroll
    for (int it = 0; it < 4; it++) {
      int g2 = (it * 256 + t) * 8;
      int col = g2 >> 7, i = g2 & 127;
      bf16x8 v = (bf16x8){0, 0, 0, 0, 0, 0, 0, 0};
      if (ok) v = *(const bf16x8*)(src + g2);
      *(bf16x8*)&T[ky][(col + 1) * 136 + i] = v;
    }
  }
  __syncthreads();

  f32x4 acc[2][2][4];  // [q][tr][pc]
#pragma unroll
  for (int q = 0; q < 2; q++)
#pragma unroll
    for (int tr = 0; tr < 2; tr++)
#pragma unroll
      for (int pc = 0; pc < 4; pc++) acc[q][tr][pc] = (f32x4){0.f, 0.f, 0.f, 0.f};

  int row0 = wave * 32 + lane15;
  const u16* A0 = Apk + ((size_t)(p * 2 + 0) * 128) * 512;
  const u16* A1 = Apk + ((size_t)(p * 2 + 1) * 128) * 512;

#pragma unroll
  for (int ky = 0; ky < 2; ky++)
#pragma unroll
    for (int kx = 0; kx < 2; kx++)
#pragma unroll
      for (int c4 = 0; c4 < 4; c4++) {
        int kb = (ky * 2 + kx) * 128 + c4 * 32 + quad * 8;
        bf16x8 a00 = *(const bf16x8*)(A0 + (size_t)row0 * 512 + kb);
        bf16x8 a01 = *(const bf16x8*)(A0 + (size_t)(row0 + 16) * 512 + kb);
        bf16x8 a10 = *(const bf16x8*)(A1 + (size_t)row0 * 512 + kb);
        bf16x8 a11 = *(const bf16x8*)(A1 + (size_t)(row0 + 16) * 512 + kb);
        const u16* tb = &T[ky][(lane15 + kx) * 136 + c4 * 32 + quad * 8];
#pragma unroll
        for (int pc = 0; pc < 4; pc++) {
          bf16x8 b0 = *(const bf16x8*)(tb + (pc * 16) * 136);
          bf16x8 b1 = *(const bf16x8*)(tb + (pc * 16 + 1) * 136);
          acc[0][0][pc] = __builtin_amdgcn_mfma_f32_16x16x32_bf16(a00, b0, acc[0][0][pc], 0, 0, 0);
          acc[0][1][pc] = __builtin_amdgcn_mfma_f32_16x16x32_bf16(a01, b0, acc[0][1][pc], 0, 0, 0);
          acc[1][0][pc] = __builtin_amdgcn_mfma_f32_16x16x32_bf16(a10, b1, acc[1][0][pc], 0, 0, 0);
          acc[1][1][pc] = __builtin_amdgcn_mfma_f32_16x16x32_bf16(a11, b1, acc[1][1][pc], 0, 0, 0);
        }
      }

  // epilogue: C/D col=lane&15 (px), row=quad*4+i (cout). ow = 2*px + q -> float2.
#pragma unroll
  for (int tr = 0; tr < 2; tr++) {
    int o0 = wave * 32 + tr * 16 + quad * 4;
#pragma unroll
    for (int pc = 0; pc < 4; pc++) {
      f32x4 v0 = acc[0][tr][pc];
      f32x4 v1 = acc[1][tr][pc];
      int cw = pc * 32 + 2 * lane15;
#pragma unroll
      for (int i = 0; i < 4; i++) {
        float2 w2;
        w2.x = v0[i];
        w2.y = v1[i];
        *(float2*)&out2[(((size_t)b * COUTC + o0 + i) * OHH + oh) * OWW + cw] = w2;
      }
    }
  }
}

// ---------------- K6: bn2+relu apply (f32 out)
__global__ __launch_bounds__(256) void k6s(const float* __restrict__ out2,
                                           const float* __restrict__ scale2,
                                           const float* __restrict__ shift2,
                                           float* __restrict__ outp) {
  int tid = blockIdx.x * 256 + threadIdx.x;
  if (tid >= BB * COUTC * OHH * OWW) return;
  int c = (tid >> 14) & 127;
  outp[tid] = fmaxf(fmaf(out2[tid], scale2[c], shift2[c]), 0.f);
}

// ---------------- launch
extern "C" void kernel_launch(void* const* d_in, const int* in_sizes, int n_in,
                              void* d_out, int out_size, void* d_ws, size_t ws_size,
                              hipStream_t stream) {
  const float* x     = (const float*)d_in[0];
  const float* off_w = (const float*)d_in[1];
  const float* off_b = (const float*)d_in[2];
  const float* dcn_w = (const float*)d_in[3];
  const float* dcn_b = (const float*)d_in[4];
  const float* bn1_g = (const float*)d_in[5];
  const float* bn1_b = (const float*)d_in[6];
  const float* up_w  = (const float*)d_in[7];
  const float* bn2_g = (const float*)d_in[8];
  const float* bn2_b = (const float*)d_in[9];

  float* ws = (float*)d_ws;
  float* pyg  = ws;                              // 147456
  float* pxg  = pyg + BB * 9 * HH * WW;          // 147456
  float* mg   = pxg + BB * 9 * HH * WW;          // 147456
  float* out1 = mg + BB * 9 * HH * WW;           // 2097152
  float* scale1 = out1 + BB * COUTC * HH * WW;   // 128
  float* shift1 = scale1 + 128;                  // 128
  float* out2 = shift1 + 128;                    // 8388608
  float* scale2 = out2 + BB * COUTC * OHH * OWW; // 128
  float* shift2 = scale2 + 128;                  // 128
  float* w_t = shift2 + 128;                     // 294912 floats reserved
  float* wt4 = w_t + COUTC * CINC * 9;           // 262144 floats (Apk uses as u16)
  float* part2 = wt4 + 4 * COUTC * COUTC * 4;    // 4 * 2097152
  u16* wA = (u16*)w_t;                           // 128*2304 bf16 (first half of w_t region)
  u16* wOk = (u16*)(w_t + 147456);               // 2*32*2304 bf16 hi/lo (second half)
  u16* Apk = (u16*)wt4;                          // 4*128*512 bf16 = 512KB
  // xT (f32 channel-last, 4.19M floats) overlaid on out2 region:
  // lifetime k2t..k2m, dead before k4m writes out2.
  float* xT = out2;
  // bn stats partials overlaid on part2 start (dead after k2r)
  float* psum = part2;            // up to 128*16
  float* pssq = part2 + 128 * 16; // up to 128*16
  // yT (bf16 4MB) overlaid past the stats partials in the part2 region
  u16* yT = (u16*)(part2 + 8192);

  const int N4 = BB * COUTC * OHH * OWW;  // 8388608
  const int N2 = BB * COUTC * HH * WW;    // 2097152

  k0t<<<(COUTC * CINC * 9 + 255) / 256, 256, 0, stream>>>(dcn_w, wA);
  k0o<<<(32 * 2304 + 255) / 256, 256, 0, stream>>>(off_w, wOk);
  k4w<<<(4 * COUTC * 512 + 255) / 256, 256, 0, stream>>>(up_w, Apk);
  // channel-last transpose of x (into out2 region)
  k2t<<<dim3(64, 4, 4), 256, 0, stream>>>(x, xT);
  // offset conv via MFMA (fused bias + py/px/sigmoid epilogue)
  k1m<<<dim3(64, 4), 256, 0, stream>>>(xT, wOk, off_b, pyg, pxg, mg);
  // deformable conv via register-only, q-pipelined MFMA (no LDS, no barriers)
  k2m<<<dim3(4, 64, 4), 256, 0, stream>>>(xT, wA, pyg, pxg, mg, part2);
  k2r<<<(N2 + 255) / 256, 256, 0, stream>>>(part2, dcn_b, out1);
  // bn1 stats
  bn_part<1024, 8><<<dim3(COUTC, 8), 256, 0, stream>>>(out1, psum, pssq);
  bn_fin<<<1, 128, 0, stream>>>(psum, pssq, bn1_g, bn1_b, scale1, shift1, 8,
                                1.f / 16384.f);
  // bn1 apply + transpose to bf16 channel-last
  k4a<<<dim3(64, 4), 256, 0, stream>>>(out1, scale1, shift1, yT);
  // transposed conv via MFMA
  k4m<<<dim3(128, 4), 256, 0, stream>>>(yT, Apk, out2);
  // bn2 stats
  bn_part<4096, 16><<<dim3(COUTC, 16), 256, 0, stream>>>(out2, psum, pssq);
  bn_fin<<<1, 128, 0, stream>>>(psum, pssq, bn2_g, bn2_b, scale2, shift2, 16,
                                1.f / 65536.f);
  k6s<<<(N4 + 255) / 256, 256, 0, stream>>>(out2, scale2, shift2, (float*)d_out);
}

// Round 7
// 301.868 us; speedup vs baseline: 1.1325x; 1.1198x over previous
//
#include <hip/hip_runtime.h>
#include <math.h>

// Problem constants
#define BB 4
#define CINC 256
#define COUTC 128
#define HH 64
#define WW 64
#define OHH 128
#define OWW 128

typedef unsigned short u16;
typedef __attribute__((ext_vector_type(8))) short bf16x8;
typedef __attribute__((ext_vector_type(4))) float f32x4;

__device__ __forceinline__ u16 f2bf(float f) {
  unsigned int u = __float_as_uint(f);
  unsigned int r = u + 0x7FFFu + ((u >> 16) & 1u);  // RNE
  return (u16)(r >> 16);
}

// ---------------- K0t: dcn_w [o][c*9+q] -> bf16 wA[o][q*256+c]
__global__ __launch_bounds__(256) void k0t(const float* __restrict__ dcn_w, u16* __restrict__ wA) {
  int tid = blockIdx.x * 256 + threadIdx.x;
  if (tid >= COUTC * CINC * 9) return;
  int o = tid / 2304;
  int ckr = tid - o * 2304;
  int q = ckr >> 8;
  int c = ckr & 255;
  wA[tid] = f2bf(dcn_w[o * 2304 + c * 9 + q]);
}

// ---------------- K0o: off_w -> hi/lo bf16 split, padded to 32 rows.
__global__ __launch_bounds__(256) void k0o(const float* __restrict__ off_w, u16* __restrict__ wOk) {
  int tid = blockIdx.x * 256 + threadIdx.x;
  if (tid >= 32 * 2304) return;
  int row = tid / 2304;
  int kr = tid - row * 2304;
  int q = kr >> 8, c = kr & 255;
  float w = (row < 27) ? off_w[(row * CINC + c) * 9 + q] : 0.f;
  u16 hi = f2bf(w);
  float hf = __uint_as_float((unsigned)hi << 16);
  u16 lo = f2bf(w - hf);
  wOk[tid] = hi;
  wOk[73728 + tid] = lo;
}

// ---------------- K4w: pack up_w into 4 parity-class bf16 A-matrices.
__global__ __launch_bounds__(256) void k4w(const float* __restrict__ up_w, u16* __restrict__ Apk) {
  int tid = blockIdx.x * 256 + threadIdx.x;
  if (tid >= 4 * COUTC * 512) return;
  int kp = tid & 511;
  int o = (tid >> 9) & 127;
  int pq = tid >> 16;
  int p = pq >> 1, q = pq & 1;
  int ky = kp >> 8, kx = (kp >> 7) & 1, i = kp & 127;
  float v = up_w[((i * COUTC + o) * 4 + (3 - (p + 2 * ky))) * 4 + (3 - (q + 2 * kx))];
  Apk[tid] = f2bf(v);
}

// ---------------- K2t: transpose x -> xT f32 channel-last + hi/lo bf16 planes.
// xT[b][y][w][c] f32 (for k2m gathers); xTh/xTl bf16 (for k1m direct MFMA frags).
__global__ __launch_bounds__(256) void k2t(const float* __restrict__ x,
                                           float* __restrict__ xT,
                                           u16* __restrict__ xTh,
                                           u16* __restrict__ xTl) {
  int y = blockIdx.x, cq = blockIdx.y, b = blockIdx.z;
  __shared__ float tile[64][65];
  int t = threadIdx.x;
  int tx = t & 63;
  int tg = t >> 6;
#pragma unroll
  for (int i = 0; i < 16; i++) {
    int c = tg * 16 + i;
    tile[c][tx] = x[((size_t)(b * CINC + cq * 64 + c) * HH + y) * WW + tx];
  }
  __syncthreads();
#pragma unroll
  for (int i = 0; i < 16; i++) {
    int xc = tg * 16 + i;
    size_t idx = ((size_t)(b * HH + y) * WW + xc) * CINC + cq * 64 + tx;
    float v = tile[tx][xc];
    xT[idx] = v;
    u16 hi = f2bf(v);
    float hf = __uint_as_float((unsigned)hi << 16);
    xTh[idx] = hi;
    xTl[idx] = f2bf(v - hf);
  }
}

// ---------------- K1m: offset conv as MFMA GEMM, split-C(4) partials.
// grid (64 h, 4 b, 4 cs), 256 thr = 4 waves (px-tiles of 16). Each block does 64
// channels (2 c8-groups x 32). B-frags loaded DIRECTLY as bf16 from precomputed
// hi/lo planes (zero conversion VALU). hi/lo 3-term MFMA keeps f32 accuracy.
// Partials -> part1[cs][b][32][4096]; k1r reduces + bias + transform.
__global__ __launch_bounds__(256) void k1m(const u16* __restrict__ xTh,
                                           const u16* __restrict__ xTl,
                                           const u16* __restrict__ wOk,
                                           float* __restrict__ part1) {
  int h = blockIdx.x, b = blockIdx.y, cs = blockIdx.z;
  int t = threadIdx.x;
  int pt = t >> 6;
  int lane15 = t & 15;
  int quad = (t >> 4) & 3;

  const u16* wh0 = wOk + (size_t)lane15 * 2304 + quad * 8;
  const u16* wh1 = wh0 + 16 * 2304;
  const u16* wl0 = wh0 + 73728;
  const u16* wl1 = wh1 + 73728;

  f32x4 acc[2];
  acc[0] = (f32x4){0.f, 0.f, 0.f, 0.f};
  acc[1] = (f32x4){0.f, 0.f, 0.f, 0.f};

  for (int q = 0; q < 9; q++) {
    int y = h + q / 3 - 1;
    if ((unsigned)y >= 64u) continue;
    int xc = pt * 16 + lane15 + (q % 3) - 1;
    bool xok = (unsigned)xc < 64u;
    int xcc = min(max(xc, 0), 63);
    size_t base = ((size_t)(b * 64 + y) * 64 + xcc) * 256 + cs * 64 + quad * 8;
    const u16* hsrc = xTh + base;
    const u16* lsrc = xTl + base;
#pragma unroll
    for (int c8 = 0; c8 < 2; c8++) {
      bf16x8 xh = *(const bf16x8*)(hsrc + c8 * 32);
      bf16x8 xl = *(const bf16x8*)(lsrc + c8 * 32);
      if (!xok) {
        xh = (bf16x8){0, 0, 0, 0, 0, 0, 0, 0};
        xl = (bf16x8){0, 0, 0, 0, 0, 0, 0, 0};
      }
      int kk = (q * 8 + cs * 2 + c8) * 32;
      bf16x8 ah0 = *(const bf16x8*)(wh0 + kk);
      bf16x8 ah1 = *(const bf16x8*)(wh1 + kk);
      bf16x8 al0 = *(const bf16x8*)(wl0 + kk);
      bf16x8 al1 = *(const bf16x8*)(wl1 + kk);
      acc[0] = __builtin_amdgcn_mfma_f32_16x16x32_bf16(ah0, xh, acc[0], 0, 0, 0);
      acc[0] = __builtin_amdgcn_mfma_f32_16x16x32_bf16(ah0, xl, acc[0], 0, 0, 0);
      acc[0] = __builtin_amdgcn_mfma_f32_16x16x32_bf16(al0, xh, acc[0], 0, 0, 0);
      acc[1] = __builtin_amdgcn_mfma_f32_16x16x32_bf16(ah1, xh, acc[1], 0, 0, 0);
      acc[1] = __builtin_amdgcn_mfma_f32_16x16x32_bf16(ah1, xl, acc[1], 0, 0, 0);
      acc[1] = __builtin_amdgcn_mfma_f32_16x16x32_bf16(al1, xh, acc[1], 0, 0, 0);
    }
  }

  // write partials: part1[cs][b][oc][h*64+px]; C/D col=lane15 (px), row=quad*4+i
  int px = pt * 16 + lane15;
  float* pb = part1 + ((size_t)(cs * BB + b) * 32) * 4096 + h * 64 + px;
#pragma unroll
  for (int tr = 0; tr < 2; tr++)
#pragma unroll
    for (int i = 0; i < 4; i++) {
      int oc = tr * 16 + quad * 4 + i;
      pb[(size_t)oc * 4096] = acc[tr][i];
    }
}

// ---------------- K1r: reduce 4 channel-partials + bias -> py/px/m
__global__ __launch_bounds__(256) void k1r(const float* __restrict__ part1,
                                           const float* __restrict__ off_b,
                                           float* __restrict__ pyg,
                                           float* __restrict__ pxg,
                                           float* __restrict__ mg) {
  int tid = blockIdx.x * 256 + threadIdx.x;
  if (tid >= BB * 27 * HH * WW) return;
  int w = tid & 63;
  int h = (tid >> 6) & 63;
  int oc = (tid >> 12) % 27;
  int b = tid / (27 * 4096);
  int sp = tid & 4095;

  float v = off_b[oc];
#pragma unroll
  for (int cs = 0; cs < 4; cs++)
    v += part1[((size_t)(cs * BB + b) * 32 + oc) * 4096 + sp];

  int k = oc % 9;
  int gi = ((b * 9 + k) * HH + h) * WW + w;
  if (oc < 9) {
    pyg[gi] = v + (float)(oc / 3) - 1.f + (float)h;
  } else if (oc < 18) {
    pxg[gi] = v + (float)((oc - 9) % 3) - 1.f + (float)w;
  } else {
    mg[gi] = 1.f / (1.f + expf(-v));
  }
}

// ---------------- gather: 4 corners x 8 contiguous channels from channel-last xT.
__device__ __forceinline__ void gatherC(const float* __restrict__ base,
                                        int sA0, int sA1, int sB0, int sB1,
                                        f32x4* rx) {
  const float* pA0 = base + (size_t)sA0 * CINC;
  const float* pA1 = base + (size_t)sA1 * CINC;
  const float* pB0 = base + (size_t)sB0 * CINC;
  const float* pB1 = base + (size_t)sB1 * CINC;
  rx[0] = *(const f32x4*)pA0;
  rx[1] = *(const f32x4*)(pA0 + 4);
  rx[2] = *(const f32x4*)pA1;
  rx[3] = *(const f32x4*)(pA1 + 4);
  rx[4] = *(const f32x4*)pB0;
  rx[5] = *(const f32x4*)(pB0 + 4);
  rx[6] = *(const f32x4*)pB1;
  rx[7] = *(const f32x4*)(pB1 + 4);
}

// ---------------- K2m: deformable conv, split-K(4), bf16 MFMA GEMM.
// PROVEN round-3 structure (87.7us): LDS double-buffer, barrier-pinned prefetch
// (the barrier is what stops the compiler from collapsing the pipeline — the
// register-only variants regressed to 131-134us, VGPR collapsed to 68).
__global__ __launch_bounds__(256) void k2m(const float* __restrict__ xT,
                                           const u16* __restrict__ wA,
                                           const float* __restrict__ pyg,
                                           const float* __restrict__ pxg,
                                           const float* __restrict__ mg,
                                           float* __restrict__ part2) {
  int ks = blockIdx.x, h = blockIdx.y, b = blockIdx.z;
  __shared__ __align__(16) u16 scolT[2][64 * 40];  // [px][ck] bf16, +8 pad
  int t = threadIdx.x;
  int px = t & 63;
  int wave = t >> 6;
  int lane15 = t & 15;
  int quad = (t >> 4) & 3;

  // ---- per-(q,px) bilinear descriptors (masked, m-premultiplied) ----
  float dw0[9], dw1[9], dw2[9], dw3[9];
  int doA[9], doB[9];
#pragma unroll
  for (int q = 0; q < 9; q++) {
    int gi = ((b * 9 + q) * HH + h) * WW + px;
    float py = pyg[gi], pxx = pxg[gi], m = mg[gi];
    float y0f = floorf(py), x0f = floorf(pxx);
    float wy = py - y0f, wx = pxx - x0f;
    int y0 = (int)y0f, x0 = (int)x0f;
    bool vy0 = (unsigned)y0 < 64u, vy1 = (unsigned)(y0 + 1) < 64u;
    bool vx0 = (unsigned)x0 < 64u, vx1 = (unsigned)(x0 + 1) < 64u;
    int y0c = min(max(y0, 0), 63), y1c = min(max(y0 + 1, 0), 63);
    int x0c = min(max(x0, 0), 63), x1c = min(max(x0 + 1, 0), 63);
    dw0[q] = (vy0 && vx0) ? (1.f - wy) * (1.f - wx) * m : 0.f;
    dw1[q] = (vy0 && vx1) ? (1.f - wy) * wx * m : 0.f;
    dw2[q] = (vy1 && vx0) ? wy * (1.f - wx) * m : 0.f;
    dw3[q] = (vy1 && vx1) ? wy * wx * m : 0.f;
    doA[q] = (y0c * 64 + x0c) | ((y0c * 64 + x1c) << 16);
    doB[q] = (y1c * 64 + x0c) | ((y1c * 64 + x1c) << 16);
  }

  f32x4 acc[8];
#pragma unroll
  for (int i = 0; i < 8; i++) acc[i] = (f32x4){0.f, 0.f, 0.f, 0.f};

  const float* xTb = xT + (size_t)b * 4096 * CINC;
  const u16* wAr0 = wA + (wave * 32 + lane15) * 2304 + quad * 8;
  const u16* wAr1 = wAr0 + 16 * 2304;

  f32x4 rx[8];
  // prefetch chunk 0 (q=0, channels ks*64 + wave*8)
  gatherC(xTb + ks * 64 + wave * 8, doA[0] & 0xffff, ((unsigned)doA[0]) >> 16,
          doB[0] & 0xffff, ((unsigned)doB[0]) >> 16, rx);

#pragma unroll
  for (int ci = 0; ci < 18; ci++) {
    int q = ci >> 1;
    // combine prefetched corner vectors -> bf16 pack -> one b128 LDS write
    float v[8];
#pragma unroll
    for (int j = 0; j < 4; j++) {
      v[j]     = dw0[q] * rx[0][j] + dw1[q] * rx[2][j] + dw2[q] * rx[4][j] + dw3[q] * rx[6][j];
      v[4 + j] = dw0[q] * rx[1][j] + dw1[q] * rx[3][j] + dw2[q] * rx[5][j] + dw3[q] * rx[7][j];
    }
    uint4 st;
    st.x = (unsigned)f2bf(v[0]) | ((unsigned)f2bf(v[1]) << 16);
    st.y = (unsigned)f2bf(v[2]) | ((unsigned)f2bf(v[3]) << 16);
    st.z = (unsigned)f2bf(v[4]) | ((unsigned)f2bf(v[5]) << 16);
    st.w = (unsigned)f2bf(v[6]) | ((unsigned)f2bf(v[7]) << 16);
    *(uint4*)&scolT[ci & 1][px * 40 + wave * 8] = st;

    // issue next chunk's gathers (land during barrier+MFMA)
    if (ci < 17) {
      int qn = (ci + 1) >> 1;
      int c0n = ks * 64 + ((ci + 1) & 1) * 32 + wave * 8;
      gatherC(xTb + c0n, doA[qn] & 0xffff, ((unsigned)doA[qn]) >> 16,
              doB[qn] & 0xffff, ((unsigned)doB[qn]) >> 16, rx);
    }
    __syncthreads();  // buf[ci&1] visible; prev reads of buf[(ci-1)&1] drained
    // MFMA: 2 cout rows x 4 px tiles
    int kb = q * 256 + ks * 64 + (ci & 1) * 32;
    bf16x8 a0 = *(const bf16x8*)(wAr0 + kb);
    bf16x8 a1 = *(const bf16x8*)(wAr1 + kb);
    const u16* sr = &scolT[ci & 1][lane15 * 40 + quad * 8];
    bf16x8 b0 = *(const bf16x8*)(sr);
    bf16x8 b1 = *(const bf16x8*)(sr + 16 * 40);
    bf16x8 b2 = *(const bf16x8*)(sr + 32 * 40);
    bf16x8 b3 = *(const bf16x8*)(sr + 48 * 40);
    acc[0] = __builtin_amdgcn_mfma_f32_16x16x32_bf16(a0, b0, acc[0], 0, 0, 0);
    acc[1] = __builtin_amdgcn_mfma_f32_16x16x32_bf16(a0, b1, acc[1], 0, 0, 0);
    acc[2] = __builtin_amdgcn_mfma_f32_16x16x32_bf16(a0, b2, acc[2], 0, 0, 0);
    acc[3] = __builtin_amdgcn_mfma_f32_16x16x32_bf16(a0, b3, acc[3], 0, 0, 0);
    acc[4] = __builtin_amdgcn_mfma_f32_16x16x32_bf16(a1, b0, acc[4], 0, 0, 0);
    acc[5] = __builtin_amdgcn_mfma_f32_16x16x32_bf16(a1, b1, acc[5], 0, 0, 0);
    acc[6] = __builtin_amdgcn_mfma_f32_16x16x32_bf16(a1, b2, acc[6], 0, 0, 0);
    acc[7] = __builtin_amdgcn_mfma_f32_16x16x32_bf16(a1, b3, acc[7], 0, 0, 0);
  }

  // write partials: part2[ks][b][o][h][w]; C/D: col=lane&15 (px), row=quad*4+i (o)
  float* pb = part2 + (size_t)ks * BB * COUTC * 4096;
#pragma unroll
  for (int tr = 0; tr < 2; tr++)
#pragma unroll
    for (int pc = 0; pc < 4; pc++) {
      f32x4 a = acc[tr * 4 + pc];
      int ob = wave * 32 + tr * 16 + quad * 4;
#pragma unroll
      for (int i = 0; i < 4; i++)
        pb[((b * COUTC + ob + i) * HH + h) * WW + pc * 16 + lane15] = a[i];
    }
}

// ---------------- K2r: sum 4 partials + bias -> out1
__global__ __launch_bounds__(256) void k2r(const float* __restrict__ part2,
                                           const float* __restrict__ dcn_b,
                                           float* __restrict__ out1) {
  int tid = blockIdx.x * 256 + threadIdx.x;
  if (tid >= BB * COUTC * HH * WW) return;
  int o = (tid >> 12) & 127;
  const int S = BB * COUTC * 4096;
  out1[tid] = part2[tid] + part2[tid + S] + part2[tid + 2 * S] + part2[tid + 3 * S] + dcn_b[o];
}

// ---------------- BN stats: single-pass split reduction (sum + sumsq).
template <int PLANEF4, int NCHUNK>
__global__ __launch_bounds__(256) void bn_part(const float* __restrict__ src,
                                               float* __restrict__ psum,
                                               float* __restrict__ pssq) {
  int c = blockIdx.x, chunk = blockIdx.y, t = threadIdx.x;
  constexpr int PER = (BB * PLANEF4) / NCHUNK;  // float4s per chunk
  float s = 0.f, s2 = 0.f;
#pragma unroll
  for (int i = 0; i < PER / 256; i++) {
    int f = chunk * PER + i * 256 + t;
    int b = f / PLANEF4;  // compile-time divisor -> shifts
    int sp = f - b * PLANEF4;
    const float4 v = *(const float4*)&src[((size_t)(b * COUTC + c) * PLANEF4 + sp) * 4];
    s += v.x + v.y + v.z + v.w;
    s2 += v.x * v.x + v.y * v.y + v.z * v.z + v.w * v.w;
  }
#pragma unroll
  for (int off = 32; off > 0; off >>= 1) {
    s += __shfl_down(s, off);
    s2 += __shfl_down(s2, off);
  }
  __shared__ float rs[4], rq[4];
  int wv = t >> 6;
  if ((t & 63) == 0) { rs[wv] = s; rq[wv] = s2; }
  __syncthreads();
  if (t == 0) {
    psum[c * NCHUNK + chunk] = rs[0] + rs[1] + rs[2] + rs[3];
    pssq[c * NCHUNK + chunk] = rq[0] + rq[1] + rq[2] + rq[3];
  }
}

// finalize: 1 block x 128 threads; per-channel scale/shift from partials
__global__ __launch_bounds__(128) void bn_fin(const float* __restrict__ psum,
                                              const float* __restrict__ pssq,
                                              const float* __restrict__ g,
                                              const float* __restrict__ bt,
                                              float* __restrict__ scale,
                                              float* __restrict__ shift,
                                              int nchunk, float invN) {
  int c = threadIdx.x;
  float S = 0.f, Q = 0.f;
  for (int i = 0; i < nchunk; i++) {
    S += psum[c * nchunk + i];
    Q += pssq[c * nchunk + i];
  }
  float mu = S * invN;
  float var = Q * invN - mu * mu;
  float sc = g[c] * rsqrtf(var + 1e-5f);
  scale[c] = sc;
  shift[c] = bt[c] - mu * sc;
}

// ---------------- K4a: bn1+relu apply, bf16 convert, channel-last transpose.
__global__ __launch_bounds__(256) void k4a(const float* __restrict__ out1,
                                           const float* __restrict__ s1,
                                           const float* __restrict__ sh1,
                                           u16* __restrict__ yT) {
  int m = blockIdx.x, b = blockIdx.y;
  __shared__ __align__(16) u16 T2[64 * 136];
  int t = threadIdx.x;
  for (int e = t; e < 2048; e += 256) {
    int w4 = e & 15, c = e >> 4;
    float4 r = *(const float4*)&out1[((b * COUTC + c) * HH + m) * WW + w4 * 4];
    float sc = s1[c], sh = sh1[c];
    T2[(w4 * 4 + 0) * 136 + c] = f2bf(fmaxf(fmaf(r.x, sc, sh), 0.f));
    T2[(w4 * 4 + 1) * 136 + c] = f2bf(fmaxf(fmaf(r.y, sc, sh), 0.f));
    T2[(w4 * 4 + 2) * 136 + c] = f2bf(fmaxf(fmaf(r.z, sc, sh), 0.f));
    T2[(w4 * 4 + 3) * 136 + c] = f2bf(fmaxf(fmaf(r.w, sc, sh), 0.f));
  }
  __syncthreads();
  for (int e = t; e < 1024; e += 256) {
    int g2 = e * 8;
    int w = g2 >> 7, i = g2 & 127;
    *(bf16x8*)&yT[((size_t)(b * 64 + m) * 64 + w) * 128 + i] =
        *(const bf16x8*)&T2[w * 136 + i];
  }
}

// ---------------- K4m: transposed conv as bf16 MFMA GEMM.
__global__ __launch_bounds__(256) void k4m(const u16* __restrict__ yT,
                                           const u16* __restrict__ Apk,
                                           float* __restrict__ out2) {
  int oh = blockIdx.x, b = blockIdx.y;
  int a = oh >> 1, p = oh & 1;
  __shared__ __align__(16) u16 T[2][66 * 136];
  int t = threadIdx.x;
  int wave = t >> 6, lane15 = t & 15, quad = (t >> 4) & 3;

  // zero border cols: 2 bufs x 2 cols x 128 ch
  for (int e = t; e < 512; e += 256) {
    int ky = e >> 8;
    int rem = e & 255;
    int colp = (rem >> 7) * 65;
    int i = rem & 127;
    T[ky][colp * 136 + i] = 0;
  }
  // stage both tap rows (r = a+p+ky-1); contiguous 16KB copy each
#pragma unroll
  for (int ky = 0; ky < 2; ky++) {
    int r = a + p + ky - 1;
    bool ok = ((unsigned)r < 64u);
    const u16* src = yT + ((size_t)(b * 64 + r) * 64) * 128;
#pragma unroll
    for (int it = 0; it < 4; it++) {
      int g2 = (it * 256 + t) * 8;
      int col = g2 >> 7, i = g2 & 127;
      bf16x8 v = (bf16x8){0, 0, 0, 0, 0, 0, 0, 0};
      if (ok) v = *(const bf16x8*)(src + g2);
      *(bf16x8*)&T[ky][(col + 1) * 136 + i] = v;
    }
  }
  __syncthreads();

  f32x4 acc[2][2][4];  // [q][tr][pc]
#pragma unroll
  for (int q = 0; q < 2; q++)
#pragma unroll
    for (int tr = 0; tr < 2; tr++)
#pragma unroll
      for (int pc = 0; pc < 4; pc++) acc[q][tr][pc] = (f32x4){0.f, 0.f, 0.f, 0.f};

  int row0 = wave * 32 + lane15;
  const u16* A0 = Apk + ((size_t)(p * 2 + 0) * 128) * 512;
  const u16* A1 = Apk + ((size_t)(p * 2 + 1) * 128) * 512;

#pragma unroll
  for (int ky = 0; ky < 2; ky++)
#pragma unroll
    for (int kx = 0; kx < 2; kx++)
#pragma unroll
      for (int c4 = 0; c4 < 4; c4++) {
        int kb = (ky * 2 + kx) * 128 + c4 * 32 + quad * 8;
        bf16x8 a00 = *(const bf16x8*)(A0 + (size_t)row0 * 512 + kb);
        bf16x8 a01 = *(const bf16x8*)(A0 + (size_t)(row0 + 16) * 512 + kb);
        bf16x8 a10 = *(const bf16x8*)(A1 + (size_t)row0 * 512 + kb);
        bf16x8 a11 = *(const bf16x8*)(A1 + (size_t)(row0 + 16) * 512 + kb);
        const u16* tb = &T[ky][(lane15 + kx) * 136 + c4 * 32 + quad * 8];
#pragma unroll
        for (int pc = 0; pc < 4; pc++) {
          bf16x8 b0 = *(const bf16x8*)(tb + (pc * 16) * 136);
          bf16x8 b1 = *(const bf16x8*)(tb + (pc * 16 + 1) * 136);
          acc[0][0][pc] = __builtin_amdgcn_mfma_f32_16x16x32_bf16(a00, b0, acc[0][0][pc], 0, 0, 0);
          acc[0][1][pc] = __builtin_amdgcn_mfma_f32_16x16x32_bf16(a01, b0, acc[0][1][pc], 0, 0, 0);
          acc[1][0][pc] = __builtin_amdgcn_mfma_f32_16x16x32_bf16(a10, b1, acc[1][0][pc], 0, 0, 0);
          acc[1][1][pc] = __builtin_amdgcn_mfma_f32_16x16x32_bf16(a11, b1, acc[1][1][pc], 0, 0, 0);
        }
      }

  // epilogue: C/D col=lane&15 (px), row=quad*4+i (cout). ow = 2*px + q -> float2.
#pragma unroll
  for (int tr = 0; tr < 2; tr++) {
    int o0 = wave * 32 + tr * 16 + quad * 4;
#pragma unroll
    for (int pc = 0; pc < 4; pc++) {
      f32x4 v0 = acc[0][tr][pc];
      f32x4 v1 = acc[1][tr][pc];
      int cw = pc * 32 + 2 * lane15;
#pragma unroll
      for (int i = 0; i < 4; i++) {
        float2 w2;
        w2.x = v0[i];
        w2.y = v1[i];
        *(float2*)&out2[(((size_t)b * COUTC + o0 + i) * OHH + oh) * OWW + cw] = w2;
      }
    }
  }
}

// ---------------- K6: bn2+relu apply (f32 out)
__global__ __launch_bounds__(256) void k6s(const float* __restrict__ out2,
                                           const float* __restrict__ scale2,
                                           const float* __restrict__ shift2,
                                           float* __restrict__ outp) {
  int tid = blockIdx.x * 256 + threadIdx.x;
  if (tid >= BB * COUTC * OHH * OWW) return;
  int c = (tid >> 14) & 127;
  outp[tid] = fmaxf(fmaf(out2[tid], scale2[c], shift2[c]), 0.f);
}

// ---------------- launch
extern "C" void kernel_launch(void* const* d_in, const int* in_sizes, int n_in,
                              void* d_out, int out_size, void* d_ws, size_t ws_size,
                              hipStream_t stream) {
  const float* x     = (const float*)d_in[0];
  const float* off_w = (const float*)d_in[1];
  const float* off_b = (const float*)d_in[2];
  const float* dcn_w = (const float*)d_in[3];
  const float* dcn_b = (const float*)d_in[4];
  const float* bn1_g = (const float*)d_in[5];
  const float* bn1_b = (const float*)d_in[6];
  const float* up_w  = (const float*)d_in[7];
  const float* bn2_g = (const float*)d_in[8];
  const float* bn2_b = (const float*)d_in[9];

  float* ws = (float*)d_ws;
  float* pyg  = ws;                              // 147456
  float* pxg  = pyg + BB * 9 * HH * WW;          // 147456
  float* mg   = pxg + BB * 9 * HH * WW;          // 147456
  float* out1 = mg + BB * 9 * HH * WW;           // 2097152
  float* scale1 = out1 + BB * COUTC * HH * WW;   // 128
  float* shift1 = scale1 + 128;                  // 128
  float* out2 = shift1 + 128;                    // 8388608
  float* scale2 = out2 + BB * COUTC * OHH * OWW; // 128
  float* shift2 = scale2 + 128;                  // 128
  float* w_t = shift2 + 128;                     // 294912 floats reserved
  float* wt4 = w_t + COUTC * CINC * 9;           // 262144 floats (Apk uses as u16)
  float* part2 = wt4 + 4 * COUTC * COUTC * 4;    // 4 * 2097152 floats
  u16* wA = (u16*)w_t;                           // 128*2304 bf16 (first half of w_t region)
  u16* wOk = (u16*)(w_t + 147456);               // 2*32*2304 bf16 hi/lo (second half)
  u16* Apk = (u16*)wt4;                          // 4*128*512 bf16 = 512KB
  // xT (f32 channel-last) overlaid on out2 region: lifetime k2t..k2m.
  float* xT = out2;
  // hi/lo bf16 planes of x: overlaid on part2 region (dead once k2m writes part2).
  u16* xTh = (u16*)part2;                        // 4.2M u16 = first 2.1M floats
  u16* xTl = xTh + (size_t)BB * 4096 * CINC;     // next 2.1M floats
  // offset-conv partials: after the planes in part2 region (lifetime k1m..k1r)
  float* part1 = part2 + 2 * 2097152;            // 4*4*32*4096 = 2.1M floats
  // bn stats partials overlaid on part2 start (lifetime after k2r)
  float* psum = part2;            // up to 128*16
  float* pssq = part2 + 128 * 16; // up to 128*16
  // yT (bf16 4MB) overlaid past the stats partials in the part2 region
  u16* yT = (u16*)(part2 + 8192);

  const int N4 = BB * COUTC * OHH * OWW;  // 8388608
  const int N2 = BB * COUTC * HH * WW;    // 2097152
  const int N1 = BB * 27 * HH * WW;       // 442368

  k0t<<<(COUTC * CINC * 9 + 255) / 256, 256, 0, stream>>>(dcn_w, wA);
  k0o<<<(32 * 2304 + 255) / 256, 256, 0, stream>>>(off_w, wOk);
  k4w<<<(4 * COUTC * 512 + 255) / 256, 256, 0, stream>>>(up_w, Apk);
  // channel-last transpose of x (f32 into out2 region + bf16 hi/lo planes)
  k2t<<<dim3(64, 4, 4), 256, 0, stream>>>(x, xT, xTh, xTl);
  // offset conv via MFMA, split-C(4) partials, then reduce+bias+transform
  k1m<<<dim3(64, BB, 4), 256, 0, stream>>>(xTh, xTl, wOk, part1);
  k1r<<<(N1 + 255) / 256, 256, 0, stream>>>(part1, off_b, pyg, pxg, mg);
  // deformable conv via LDS-pipelined MFMA (proven 87.7us structure)
  k2m<<<dim3(4, 64, 4), 256, 0, stream>>>(xT, wA, pyg, pxg, mg, part2);
  k2r<<<(N2 + 255) / 256, 256, 0, stream>>>(part2, dcn_b, out1);
  // bn1 stats
  bn_part<1024, 8><<<dim3(COUTC, 8), 256, 0, stream>>>(out1, psum, pssq);
  bn_fin<<<1, 128, 0, stream>>>(psum, pssq, bn1_g, bn1_b, scale1, shift1, 8,
                                1.f / 16384.f);
  // bn1 apply + transpose to bf16 channel-last
  k4a<<<dim3(64, 4), 256, 0, stream>>>(out1, scale1, shift1, yT);
  // transposed conv via MFMA
  k4m<<<dim3(128, 4), 256, 0, stream>>>(yT, Apk, out2);
  // bn2 stats
  bn_part<4096, 16><<<dim3(COUTC, 16), 256, 0, stream>>>(out2, psum, pssq);
  bn_fin<<<1, 128, 0, stream>>>(psum, pssq, bn2_g, bn2_b, scale2, shift2, 16,
                                1.f / 65536.f);
  k6s<<<(N4 + 255) / 256, 256, 0, stream>>>(out2, scale2, shift2, (float*)d_out);
}

// Round 8
// 296.933 us; speedup vs baseline: 1.1513x; 1.0166x over previous
//
#include <hip/hip_runtime.h>
#include <math.h>

// Problem constants
#define BB 4
#define CINC 256
#define COUTC 128
#define HH 64
#define WW 64
#define OHH 128
#define OWW 128

typedef unsigned short u16;
typedef __attribute__((ext_vector_type(8))) short bf16x8;
typedef __attribute__((ext_vector_type(4))) float f32x4;

__device__ __forceinline__ u16 f2bf(float f) {
  unsigned int u = __float_as_uint(f);
  unsigned int r = u + 0x7FFFu + ((u >> 16) & 1u);  // RNE
  return (u16)(r >> 16);
}

__device__ __forceinline__ unsigned pk(float a, float b) {
  return (unsigned)f2bf(a) | ((unsigned)f2bf(b) << 16);
}

// ---------------- K0t: dcn_w [o][c*9+q] -> bf16 wA[o][q*256+c]
__global__ __launch_bounds__(256) void k0t(const float* __restrict__ dcn_w, u16* __restrict__ wA) {
  int tid = blockIdx.x * 256 + threadIdx.x;
  if (tid >= COUTC * CINC * 9) return;
  int o = tid / 2304;
  int ckr = tid - o * 2304;
  int q = ckr >> 8;
  int c = ckr & 255;
  wA[tid] = f2bf(dcn_w[o * 2304 + c * 9 + q]);
}

// ---------------- K0o: off_w -> hi/lo bf16 split, padded to 32 rows.
__global__ __launch_bounds__(256) void k0o(const float* __restrict__ off_w, u16* __restrict__ wOk) {
  int tid = blockIdx.x * 256 + threadIdx.x;
  if (tid >= 32 * 2304) return;
  int row = tid / 2304;
  int kr = tid - row * 2304;
  int q = kr >> 8, c = kr & 255;
  float w = (row < 27) ? off_w[(row * CINC + c) * 9 + q] : 0.f;
  u16 hi = f2bf(w);
  float hf = __uint_as_float((unsigned)hi << 16);
  u16 lo = f2bf(w - hf);
  wOk[tid] = hi;
  wOk[73728 + tid] = lo;
}

// ---------------- K4w: pack up_w into 4 parity-class bf16 A-matrices.
__global__ __launch_bounds__(256) void k4w(const float* __restrict__ up_w, u16* __restrict__ Apk) {
  int tid = blockIdx.x * 256 + threadIdx.x;
  if (tid >= 4 * COUTC * 512) return;
  int kp = tid & 511;
  int o = (tid >> 9) & 127;
  int pq = tid >> 16;
  int p = pq >> 1, q = pq & 1;
  int ky = kp >> 8, kx = (kp >> 7) & 1, i = kp & 127;
  float v = up_w[((i * COUTC + o) * 4 + (3 - (p + 2 * ky))) * 4 + (3 - (q + 2 * kx))];
  Apk[tid] = f2bf(v);
}

// ---------------- K2t: transpose x -> xT f32 channel-last + hi/lo bf16 planes.
__global__ __launch_bounds__(256) void k2t(const float* __restrict__ x,
                                           float* __restrict__ xT,
                                           u16* __restrict__ xTh,
                                           u16* __restrict__ xTl) {
  int y = blockIdx.x, cq = blockIdx.y, b = blockIdx.z;
  __shared__ float tile[64][65];
  int t = threadIdx.x;
  int tx = t & 63;
  int tg = t >> 6;
#pragma unroll
  for (int i = 0; i < 16; i++) {
    int c = tg * 16 + i;
    tile[c][tx] = x[((size_t)(b * CINC + cq * 64 + c) * HH + y) * WW + tx];
  }
  __syncthreads();
#pragma unroll
  for (int i = 0; i < 16; i++) {
    int xc = tg * 16 + i;
    size_t idx = ((size_t)(b * HH + y) * WW + xc) * CINC + cq * 64 + tx;
    float v = tile[tx][xc];
    xT[idx] = v;
    u16 hi = f2bf(v);
    float hf = __uint_as_float((unsigned)hi << 16);
    xTh[idx] = hi;
    xTl[idx] = f2bf(v - hf);
  }
}

// ---------------- K1m: offset conv as MFMA GEMM, split-C(4) partials.
__global__ __launch_bounds__(256) void k1m(const u16* __restrict__ xTh,
                                           const u16* __restrict__ xTl,
                                           const u16* __restrict__ wOk,
                                           float* __restrict__ part1) {
  int h = blockIdx.x, b = blockIdx.y, cs = blockIdx.z;
  int t = threadIdx.x;
  int pt = t >> 6;
  int lane15 = t & 15;
  int quad = (t >> 4) & 3;

  const u16* wh0 = wOk + (size_t)lane15 * 2304 + quad * 8;
  const u16* wh1 = wh0 + 16 * 2304;
  const u16* wl0 = wh0 + 73728;
  const u16* wl1 = wh1 + 73728;

  f32x4 acc[2];
  acc[0] = (f32x4){0.f, 0.f, 0.f, 0.f};
  acc[1] = (f32x4){0.f, 0.f, 0.f, 0.f};

  for (int q = 0; q < 9; q++) {
    int y = h + q / 3 - 1;
    if ((unsigned)y >= 64u) continue;
    int xc = pt * 16 + lane15 + (q % 3) - 1;
    bool xok = (unsigned)xc < 64u;
    int xcc = min(max(xc, 0), 63);
    size_t base = ((size_t)(b * 64 + y) * 64 + xcc) * 256 + cs * 64 + quad * 8;
    const u16* hsrc = xTh + base;
    const u16* lsrc = xTl + base;
#pragma unroll
    for (int c8 = 0; c8 < 2; c8++) {
      bf16x8 xh = *(const bf16x8*)(hsrc + c8 * 32);
      bf16x8 xl = *(const bf16x8*)(lsrc + c8 * 32);
      if (!xok) {
        xh = (bf16x8){0, 0, 0, 0, 0, 0, 0, 0};
        xl = (bf16x8){0, 0, 0, 0, 0, 0, 0, 0};
      }
      int kk = (q * 8 + cs * 2 + c8) * 32;
      bf16x8 ah0 = *(const bf16x8*)(wh0 + kk);
      bf16x8 ah1 = *(const bf16x8*)(wh1 + kk);
      bf16x8 al0 = *(const bf16x8*)(wl0 + kk);
      bf16x8 al1 = *(const bf16x8*)(wl1 + kk);
      acc[0] = __builtin_amdgcn_mfma_f32_16x16x32_bf16(ah0, xh, acc[0], 0, 0, 0);
      acc[0] = __builtin_amdgcn_mfma_f32_16x16x32_bf16(ah0, xl, acc[0], 0, 0, 0);
      acc[0] = __builtin_amdgcn_mfma_f32_16x16x32_bf16(al0, xh, acc[0], 0, 0, 0);
      acc[1] = __builtin_amdgcn_mfma_f32_16x16x32_bf16(ah1, xh, acc[1], 0, 0, 0);
      acc[1] = __builtin_amdgcn_mfma_f32_16x16x32_bf16(ah1, xl, acc[1], 0, 0, 0);
      acc[1] = __builtin_amdgcn_mfma_f32_16x16x32_bf16(al1, xh, acc[1], 0, 0, 0);
    }
  }

  int px = pt * 16 + lane15;
  float* pb = part1 + ((size_t)(cs * BB + b) * 32) * 4096 + h * 64 + px;
#pragma unroll
  for (int tr = 0; tr < 2; tr++)
#pragma unroll
    for (int i = 0; i < 4; i++) {
      int oc = tr * 16 + quad * 4 + i;
      pb[(size_t)oc * 4096] = acc[tr][i];
    }
}

// ---------------- K1r: reduce 4 channel-partials + bias -> py/px/m
__global__ __launch_bounds__(256) void k1r(const float* __restrict__ part1,
                                           const float* __restrict__ off_b,
                                           float* __restrict__ pyg,
                                           float* __restrict__ pxg,
                                           float* __restrict__ mg) {
  int tid = blockIdx.x * 256 + threadIdx.x;
  if (tid >= BB * 27 * HH * WW) return;
  int w = tid & 63;
  int h = (tid >> 6) & 63;
  int oc = (tid >> 12) % 27;
  int b = tid / (27 * 4096);
  int sp = tid & 4095;

  float v = off_b[oc];
#pragma unroll
  for (int cs = 0; cs < 4; cs++)
    v += part1[((size_t)(cs * BB + b) * 32 + oc) * 4096 + sp];

  int k = oc % 9;
  int gi = ((b * 9 + k) * HH + h) * WW + w;
  if (oc < 9) {
    pyg[gi] = v + (float)(oc / 3) - 1.f + (float)h;
  } else if (oc < 18) {
    pxg[gi] = v + (float)((oc - 9) % 3) - 1.f + (float)w;
  } else {
    mg[gi] = 1.f / (1.f + expf(-v));
  }
}

// ---------------- K2m: deformable conv, split-K(4), bf16 MFMA GEMM.
// Round-3 skeleton (LDS dbuf + barrier-pinned prefetch) with FULL-LINE gathers:
// thread (px=lane, wave) loads channel slice wave*16..+16 per corner = one whole
// aligned 64B line (100% line use; old 8-ch/thread used 32B of each 64B line ->
// ~1.2GB of L2/L3 line traffic, the measured 87.6us limiter). One tap stages all
// 64 block-channels at once: 9 staging rounds + 9 barriers (was 18), gather
// instrs halved. LDS tile [64px][72] u16 (stride 72 -> optimal 8-cy bank pattern
// for both b128 writes and frag reads). Interp stays f32 -> bit-identical output.
__global__ __launch_bounds__(256) void k2m(const float* __restrict__ xT,
                                           const u16* __restrict__ wA,
                                           const float* __restrict__ pyg,
                                           const float* __restrict__ pxg,
                                           const float* __restrict__ mg,
                                           float* __restrict__ part2) {
  int ks = blockIdx.x, h = blockIdx.y, b = blockIdx.z;
  __shared__ __align__(16) u16 scolT[2][64 * 72];  // [px][ch 0..63 +8 pad] bf16
  int t = threadIdx.x;
  int px = t & 63;
  int wave = t >> 6;
  int lane15 = t & 15;
  int quad = (t >> 4) & 3;

  // ---- per-(q,px) bilinear descriptors (masked, m-premultiplied) ----
  float dw0[9], dw1[9], dw2[9], dw3[9];
  int doA[9], doB[9];
#pragma unroll
  for (int q = 0; q < 9; q++) {
    int gi = ((b * 9 + q) * HH + h) * WW + px;
    float py = pyg[gi], pxx = pxg[gi], m = mg[gi];
    float y0f = floorf(py), x0f = floorf(pxx);
    float wy = py - y0f, wx = pxx - x0f;
    int y0 = (int)y0f, x0 = (int)x0f;
    bool vy0 = (unsigned)y0 < 64u, vy1 = (unsigned)(y0 + 1) < 64u;
    bool vx0 = (unsigned)x0 < 64u, vx1 = (unsigned)(x0 + 1) < 64u;
    int y0c = min(max(y0, 0), 63), y1c = min(max(y0 + 1, 0), 63);
    int x0c = min(max(x0, 0), 63), x1c = min(max(x0 + 1, 0), 63);
    dw0[q] = (vy0 && vx0) ? (1.f - wy) * (1.f - wx) * m : 0.f;
    dw1[q] = (vy0 && vx1) ? (1.f - wy) * wx * m : 0.f;
    dw2[q] = (vy1 && vx0) ? wy * (1.f - wx) * m : 0.f;
    dw3[q] = (vy1 && vx1) ? wy * wx * m : 0.f;
    doA[q] = (y0c * 64 + x0c) | ((y0c * 64 + x1c) << 16);
    doB[q] = (y1c * 64 + x0c) | ((y1c * 64 + x1c) << 16);
  }

  f32x4 acc[8];
#pragma unroll
  for (int i = 0; i < 8; i++) acc[i] = (f32x4){0.f, 0.f, 0.f, 0.f};

  // thread's gather base: its 16-ch (one line) slice
  const float* xTb = xT + (size_t)b * 4096 * CINC + ks * 64 + wave * 16;
  const u16* wAr0 = wA + (wave * 32 + lane15) * 2304 + quad * 8;
  const u16* wAr1 = wAr0 + 16 * 2304;

  f32x4 rx[16];  // 4 corners x 16 ch (4 f32x4 each, all from one line per corner)
#define GATHER_TAP(qq, r)                                                    \
  {                                                                          \
    int sA0 = doA[qq] & 0xffff, sA1 = ((unsigned)doA[qq]) >> 16;             \
    int sB0 = doB[qq] & 0xffff, sB1 = ((unsigned)doB[qq]) >> 16;             \
    const float* p0 = xTb + (size_t)sA0 * CINC;                              \
    const float* p1 = xTb + (size_t)sA1 * CINC;                              \
    const float* p2 = xTb + (size_t)sB0 * CINC;                              \
    const float* p3 = xTb + (size_t)sB1 * CINC;                              \
    _Pragma("unroll") for (int j = 0; j < 4; j++) {                          \
      r[j] = *(const f32x4*)(p0 + 4 * j);                                    \
      r[4 + j] = *(const f32x4*)(p1 + 4 * j);                                \
      r[8 + j] = *(const f32x4*)(p2 + 4 * j);                                \
      r[12 + j] = *(const f32x4*)(p3 + 4 * j);                               \
    }                                                                        \
  }

  GATHER_TAP(0, rx);

#pragma unroll
  for (int q = 0; q < 9; q++) {
    // combine prefetched corners -> bf16 pack -> two b128 LDS writes (16 ch)
    f32x4 o0 = dw0[q] * rx[0] + dw1[q] * rx[4] + dw2[q] * rx[8] + dw3[q] * rx[12];
    f32x4 o1 = dw0[q] * rx[1] + dw1[q] * rx[5] + dw2[q] * rx[9] + dw3[q] * rx[13];
    f32x4 o2 = dw0[q] * rx[2] + dw1[q] * rx[6] + dw2[q] * rx[10] + dw3[q] * rx[14];
    f32x4 o3 = dw0[q] * rx[3] + dw1[q] * rx[7] + dw2[q] * rx[11] + dw3[q] * rx[15];
    u16* sb = &scolT[q & 1][px * 72 + wave * 16];
    uint4 s0, s1;
    s0.x = pk(o0[0], o0[1]); s0.y = pk(o0[2], o0[3]);
    s0.z = pk(o1[0], o1[1]); s0.w = pk(o1[2], o1[3]);
    s1.x = pk(o2[0], o2[1]); s1.y = pk(o2[2], o2[3]);
    s1.z = pk(o3[0], o3[1]); s1.w = pk(o3[2], o3[3]);
    *(uint4*)sb = s0;
    *(uint4*)(sb + 8) = s1;

    // issue next tap's gathers (land during barrier+MFMA)
    if (q < 8) GATHER_TAP(q + 1, rx);

    __syncthreads();  // buf[q&1] visible; prev reads of buf[(q-1)&1] drained
    // MFMA: both 32-ch chunks of this tap; 2 cout rows x 4 px tiles each
#pragma unroll
    for (int c32 = 0; c32 < 2; c32++) {
      int kb = q * 256 + ks * 64 + c32 * 32;
      bf16x8 a0 = *(const bf16x8*)(wAr0 + kb);
      bf16x8 a1 = *(const bf16x8*)(wAr1 + kb);
      const u16* sr = &scolT[q & 1][lane15 * 72 + c32 * 32 + quad * 8];
      bf16x8 b0 = *(const bf16x8*)(sr);
      bf16x8 b1 = *(const bf16x8*)(sr + 16 * 72);
      bf16x8 b2 = *(const bf16x8*)(sr + 32 * 72);
      bf16x8 b3 = *(const bf16x8*)(sr + 48 * 72);
      acc[0] = __builtin_amdgcn_mfma_f32_16x16x32_bf16(a0, b0, acc[0], 0, 0, 0);
      acc[1] = __builtin_amdgcn_mfma_f32_16x16x32_bf16(a0, b1, acc[1], 0, 0, 0);
      acc[2] = __builtin_amdgcn_mfma_f32_16x16x32_bf16(a0, b2, acc[2], 0, 0, 0);
      acc[3] = __builtin_amdgcn_mfma_f32_16x16x32_bf16(a0, b3, acc[3], 0, 0, 0);
      acc[4] = __builtin_amdgcn_mfma_f32_16x16x32_bf16(a1, b0, acc[4], 0, 0, 0);
      acc[5] = __builtin_amdgcn_mfma_f32_16x16x32_bf16(a1, b1, acc[5], 0, 0, 0);
      acc[6] = __builtin_amdgcn_mfma_f32_16x16x32_bf16(a1, b2, acc[6], 0, 0, 0);
      acc[7] = __builtin_amdgcn_mfma_f32_16x16x32_bf16(a1, b3, acc[7], 0, 0, 0);
    }
  }
#undef GATHER_TAP

  // write partials: part2[ks][b][o][h][w]; C/D: col=lane&15 (px), row=quad*4+i (o)
  float* pb = part2 + (size_t)ks * BB * COUTC * 4096;
#pragma unroll
  for (int tr = 0; tr < 2; tr++)
#pragma unroll
    for (int pc = 0; pc < 4; pc++) {
      f32x4 a = acc[tr * 4 + pc];
      int ob = wave * 32 + tr * 16 + quad * 4;
#pragma unroll
      for (int i = 0; i < 4; i++)
        pb[((b * COUTC + ob + i) * HH + h) * WW + pc * 16 + lane15] = a[i];
    }
}

// ---------------- K2r: sum 4 partials + bias -> out1
__global__ __launch_bounds__(256) void k2r(const float* __restrict__ part2,
                                           const float* __restrict__ dcn_b,
                                           float* __restrict__ out1) {
  int tid = blockIdx.x * 256 + threadIdx.x;
  if (tid >= BB * COUTC * HH * WW) return;
  int o = (tid >> 12) & 127;
  const int S = BB * COUTC * 4096;
  out1[tid] = part2[tid] + part2[tid + S] + part2[tid + 2 * S] + part2[tid + 3 * S] + dcn_b[o];
}

// ---------------- BN stats: single-pass split reduction (sum + sumsq).
template <int PLANEF4, int NCHUNK>
__global__ __launch_bounds__(256) void bn_part(const float* __restrict__ src,
                                               float* __restrict__ psum,
                                               float* __restrict__ pssq) {
  int c = blockIdx.x, chunk = blockIdx.y, t = threadIdx.x;
  constexpr int PER = (BB * PLANEF4) / NCHUNK;  // float4s per chunk
  float s = 0.f, s2 = 0.f;
#pragma unroll
  for (int i = 0; i < PER / 256; i++) {
    int f = chunk * PER + i * 256 + t;
    int b = f / PLANEF4;  // compile-time divisor -> shifts
    int sp = f - b * PLANEF4;
    const float4 v = *(const float4*)&src[((size_t)(b * COUTC + c) * PLANEF4 + sp) * 4];
    s += v.x + v.y + v.z + v.w;
    s2 += v.x * v.x + v.y * v.y + v.z * v.z + v.w * v.w;
  }
#pragma unroll
  for (int off = 32; off > 0; off >>= 1) {
    s += __shfl_down(s, off);
    s2 += __shfl_down(s2, off);
  }
  __shared__ float rs[4], rq[4];
  int wv = t >> 6;
  if ((t & 63) == 0) { rs[wv] = s; rq[wv] = s2; }
  __syncthreads();
  if (t == 0) {
    psum[c * NCHUNK + chunk] = rs[0] + rs[1] + rs[2] + rs[3];
    pssq[c * NCHUNK + chunk] = rq[0] + rq[1] + rq[2] + rq[3];
  }
}

// finalize: 1 block x 128 threads; per-channel scale/shift from partials
__global__ __launch_bounds__(128) void bn_fin(const float* __restrict__ psum,
                                              const float* __restrict__ pssq,
                                              const float* __restrict__ g,
                                              const float* __restrict__ bt,
                                              float* __restrict__ scale,
                                              float* __restrict__ shift,
                                              int nchunk, float invN) {
  int c = threadIdx.x;
  float S = 0.f, Q = 0.f;
  for (int i = 0; i < nchunk; i++) {
    S += psum[c * nchunk + i];
    Q += pssq[c * nchunk + i];
  }
  float mu = S * invN;
  float var = Q * invN - mu * mu;
  float sc = g[c] * rsqrtf(var + 1e-5f);
  scale[c] = sc;
  shift[c] = bt[c] - mu * sc;
}

// ---------------- K4a: bn1+relu apply, bf16 convert, channel-last transpose.
__global__ __launch_bounds__(256) void k4a(const float* __restrict__ out1,
                                           const float* __restrict__ s1,
                                           const float* __restrict__ sh1,
                                           u16* __restrict__ yT) {
  int m = blockIdx.x, b = blockIdx.y;
  __shared__ __align__(16) u16 T2[64 * 136];
  int t = threadIdx.x;
  for (int e = t; e < 2048; e += 256) {
    int w4 = e & 15, c = e >> 4;
    float4 r = *(const float4*)&out1[((b * COUTC + c) * HH + m) * WW + w4 * 4];
    float sc = s1[c], sh = sh1[c];
    T2[(w4 * 4 + 0) * 136 + c] = f2bf(fmaxf(fmaf(r.x, sc, sh), 0.f));
    T2[(w4 * 4 + 1) * 136 + c] = f2bf(fmaxf(fmaf(r.y, sc, sh), 0.f));
    T2[(w4 * 4 + 2) * 136 + c] = f2bf(fmaxf(fmaf(r.z, sc, sh), 0.f));
    T2[(w4 * 4 + 3) * 136 + c] = f2bf(fmaxf(fmaf(r.w, sc, sh), 0.f));
  }
  __syncthreads();
  for (int e = t; e < 1024; e += 256) {
    int g2 = e * 8;
    int w = g2 >> 7, i = g2 & 127;
    *(bf16x8*)&yT[((size_t)(b * 64 + m) * 64 + w) * 128 + i] =
        *(const bf16x8*)&T2[w * 136 + i];
  }
}

// ---------------- K4m: transposed conv as bf16 MFMA GEMM.
__global__ __launch_bounds__(256) void k4m(const u16* __restrict__ yT,
                                           const u16* __restrict__ Apk,
                                           float* __restrict__ out2) {
  int oh = blockIdx.x, b = blockIdx.y;
  int a = oh >> 1, p = oh & 1;
  __shared__ __align__(16) u16 T[2][66 * 136];
  int t = threadIdx.x;
  int wave = t >> 6, lane15 = t & 15, quad = (t >> 4) & 3;

  // zero border cols: 2 bufs x 2 cols x 128 ch
  for (int e = t; e < 512; e += 256) {
    int ky = e >> 8;
    int rem = e & 255;
    int colp = (rem >> 7) * 65;
    int i = rem & 127;
    T[ky][colp * 136 + i] = 0;
  }
  // stage both tap rows (r = a+p+ky-1); contiguous 16KB copy each
#pragma unroll
  for (int ky = 0; ky < 2; ky++) {
    int r = a + p + ky - 1;
    bool ok = ((unsigned)r < 64u);
    const u16* src = yT + ((size_t)(b * 64 + r) * 64) * 128;
#pragma unroll
    for (int it = 0; it < 4; it++) {
      int g2 = (it * 256 + t) * 8;
      int col = g2 >> 7, i = g2 & 127;
      bf16x8 v = (bf16x8){0, 0, 0, 0, 0, 0, 0, 0};
      if (ok) v = *(const bf16x8*)(src + g2);
      *(bf16x8*)&T[ky][(col + 1) * 136 + i] = v;
    }
  }
  __syncthreads();

  f32x4 acc[2][2][4];  // [q][tr][pc]
#pragma unroll
  for (int q = 0; q < 2; q++)
#pragma unroll
    for (int tr = 0; tr < 2; tr++)
#pragma unroll
      for (int pc = 0; pc < 4; pc++) acc[q][tr][pc] = (f32x4){0.f, 0.f, 0.f, 0.f};

  int row0 = wave * 32 + lane15;
  const u16* A0 = Apk + ((size_t)(p * 2 + 0) * 128) * 512;
  const u16* A1 = Apk + ((size_t)(p * 2 + 1) * 128) * 512;

#pragma unroll
  for (int ky = 0; ky < 2; ky++)
#pragma unroll
    for (int kx = 0; kx < 2; kx++)
#pragma unroll
      for (int c4 = 0; c4 < 4; c4++) {
        int kb = (ky * 2 + kx) * 128 + c4 * 32 + quad * 8;
        bf16x8 a00 = *(const bf16x8*)(A0 + (size_t)row0 * 512 + kb);
        bf16x8 a01 = *(const bf16x8*)(A0 + (size_t)(row0 + 16) * 512 + kb);
        bf16x8 a10 = *(const bf16x8*)(A1 + (size_t)row0 * 512 + kb);
        bf16x8 a11 = *(const bf16x8*)(A1 + (size_t)(row0 + 16) * 512 + kb);
        const u16* tb = &T[ky][(lane15 + kx) * 136 + c4 * 32 + quad * 8];
#pragma unroll
        for (int pc = 0; pc < 4; pc++) {
          bf16x8 b0 = *(const bf16x8*)(tb + (pc * 16) * 136);
          bf16x8 b1 = *(const bf16x8*)(tb + (pc * 16 + 1) * 136);
          acc[0][0][pc] = __builtin_amdgcn_mfma_f32_16x16x32_bf16(a00, b0, acc[0][0][pc], 0, 0, 0);
          acc[0][1][pc] = __builtin_amdgcn_mfma_f32_16x16x32_bf16(a01, b0, acc[0][1][pc], 0, 0, 0);
          acc[1][0][pc] = __builtin_amdgcn_mfma_f32_16x16x32_bf16(a10, b1, acc[1][0][pc], 0, 0, 0);
          acc[1][1][pc] = __builtin_amdgcn_mfma_f32_16x16x32_bf16(a11, b1, acc[1][1][pc], 0, 0, 0);
        }
      }

  // epilogue: C/D col=lane&15 (px), row=quad*4+i (cout). ow = 2*px + q -> float2.
#pragma unroll
  for (int tr = 0; tr < 2; tr++) {
    int o0 = wave * 32 + tr * 16 + quad * 4;
#pragma unroll
    for (int pc = 0; pc < 4; pc++) {
      f32x4 v0 = acc[0][tr][pc];
      f32x4 v1 = acc[1][tr][pc];
      int cw = pc * 32 + 2 * lane15;
#pragma unroll
      for (int i = 0; i < 4; i++) {
        float2 w2;
        w2.x = v0[i];
        w2.y = v1[i];
        *(float2*)&out2[(((size_t)b * COUTC + o0 + i) * OHH + oh) * OWW + cw] = w2;
      }
    }
  }
}

// ---------------- K6: bn2+relu apply (f32 out)
__global__ __launch_bounds__(256) void k6s(const float* __restrict__ out2,
                                           const float* __restrict__ scale2,
                                           const float* __restrict__ shift2,
                                           float* __restrict__ outp) {
  int tid = blockIdx.x * 256 + threadIdx.x;
  if (tid >= BB * COUTC * OHH * OWW) return;
  int c = (tid >> 14) & 127;
  outp[tid] = fmaxf(fmaf(out2[tid], scale2[c], shift2[c]), 0.f);
}

// ---------------- launch
extern "C" void kernel_launch(void* const* d_in, const int* in_sizes, int n_in,
                              void* d_out, int out_size, void* d_ws, size_t ws_size,
                              hipStream_t stream) {
  const float* x     = (const float*)d_in[0];
  const float* off_w = (const float*)d_in[1];
  const float* off_b = (const float*)d_in[2];
  const float* dcn_w = (const float*)d_in[3];
  const float* dcn_b = (const float*)d_in[4];
  const float* bn1_g = (const float*)d_in[5];
  const float* bn1_b = (const float*)d_in[6];
  const float* up_w  = (const float*)d_in[7];
  const float* bn2_g = (const float*)d_in[8];
  const float* bn2_b = (const float*)d_in[9];

  float* ws = (float*)d_ws;
  float* pyg  = ws;                              // 147456
  float* pxg  = pyg + BB * 9 * HH * WW;          // 147456
  float* mg   = pxg + BB * 9 * HH * WW;          // 147456
  float* out1 = mg + BB * 9 * HH * WW;           // 2097152
  float* scale1 = out1 + BB * COUTC * HH * WW;   // 128
  float* shift1 = scale1 + 128;                  // 128
  float* out2 = shift1 + 128;                    // 8388608
  float* scale2 = out2 + BB * COUTC * OHH * OWW; // 128
  float* shift2 = scale2 + 128;                  // 128
  float* w_t = shift2 + 128;                     // 294912 floats reserved
  float* wt4 = w_t + COUTC * CINC * 9;           // 262144 floats (Apk uses as u16)
  float* part2 = wt4 + 4 * COUTC * COUTC * 4;    // 4 * 2097152 floats
  u16* wA = (u16*)w_t;                           // 128*2304 bf16 (first half of w_t region)
  u16* wOk = (u16*)(w_t + 147456);               // 2*32*2304 bf16 hi/lo (second half)
  u16* Apk = (u16*)wt4;                          // 4*128*512 bf16 = 512KB
  // xT (f32 channel-last) overlaid on out2 region: lifetime k2t..k2m.
  float* xT = out2;
  // hi/lo bf16 planes of x: overlaid on part2 region (dead once k2m writes part2).
  u16* xTh = (u16*)part2;                        // 4.2M u16 = first 2.1M floats
  u16* xTl = xTh + (size_t)BB * 4096 * CINC;     // next 2.1M floats
  // offset-conv partials: after the planes in part2 region (lifetime k1m..k1r)
  float* part1 = part2 + 2 * 2097152;            // 4*4*32*4096 = 2.1M floats
  // bn stats partials overlaid on part2 start (lifetime after k2r)
  float* psum = part2;            // up to 128*16
  float* pssq = part2 + 128 * 16; // up to 128*16
  // yT (bf16 4MB) overlaid past the stats partials in the part2 region
  u16* yT = (u16*)(part2 + 8192);

  const int N4 = BB * COUTC * OHH * OWW;  // 8388608
  const int N2 = BB * COUTC * HH * WW;    // 2097152
  const int N1 = BB * 27 * HH * WW;       // 442368

  k0t<<<(COUTC * CINC * 9 + 255) / 256, 256, 0, stream>>>(dcn_w, wA);
  k0o<<<(32 * 2304 + 255) / 256, 256, 0, stream>>>(off_w, wOk);
  k4w<<<(4 * COUTC * 512 + 255) / 256, 256, 0, stream>>>(up_w, Apk);
  // channel-last transpose of x (f32 into out2 region + bf16 hi/lo planes)
  k2t<<<dim3(64, 4, 4), 256, 0, stream>>>(x, xT, xTh, xTl);
  // offset conv via MFMA, split-C(4) partials, then reduce+bias+transform
  k1m<<<dim3(64, BB, 4), 256, 0, stream>>>(xTh, xTl, wOk, part1);
  k1r<<<(N1 + 255) / 256, 256, 0, stream>>>(part1, off_b, pyg, pxg, mg);
  // deformable conv via LDS-pipelined MFMA with full-line gathers
  k2m<<<dim3(4, 64, 4), 256, 0, stream>>>(xT, wA, pyg, pxg, mg, part2);
  k2r<<<(N2 + 255) / 256, 256, 0, stream>>>(part2, dcn_b, out1);
  // bn1 stats
  bn_part<1024, 8><<<dim3(COUTC, 8), 256, 0, stream>>>(out1, psum, pssq);
  bn_fin<<<1, 128, 0, stream>>>(psum, pssq, bn1_g, bn1_b, scale1, shift1, 8,
                                1.f / 16384.f);
  // bn1 apply + transpose to bf16 channel-last
  k4a<<<dim3(64, 4), 256, 0, stream>>>(out1, scale1, shift1, yT);
  // transposed conv via MFMA
  k4m<<<dim3(128, 4), 256, 0, stream>>>(yT, Apk, out2);
  // bn2 stats
  bn_part<4096, 16><<<dim3(COUTC, 16), 256, 0, stream>>>(out2, psum, pssq);
  bn_fin<<<1, 128, 0, stream>>>(psum, pssq, bn2_g, bn2_b, scale2, shift2, 16,
                                1.f / 65536.f);
  k6s<<<(N4 + 255) / 256, 256, 0, stream>>>(out2, scale2, shift2, (float*)d_out);
}

// Round 9
// 270.388 us; speedup vs baseline: 1.2644x; 1.0982x over previous
//
#include <hip/hip_runtime.h>
#include <math.h>

// Problem constants
#define BB 4
#define CINC 256
#define COUTC 128
#define HH 64
#define WW 64
#define OHH 128
#define OWW 128

typedef unsigned short u16;
typedef __attribute__((ext_vector_type(8))) short bf16x8;
typedef __attribute__((ext_vector_type(4))) float f32x4;

__device__ __forceinline__ u16 f2bf(float f) {
  unsigned int u = __float_as_uint(f);
  unsigned int r = u + 0x7FFFu + ((u >> 16) & 1u);  // RNE
  return (u16)(r >> 16);
}

__device__ __forceinline__ unsigned pk(float a, float b) {
  return (unsigned)f2bf(a) | ((unsigned)f2bf(b) << 16);
}

__device__ __forceinline__ float bf2f(short h) {
  return __uint_as_float(((unsigned)(unsigned short)h) << 16);
}

// ---------------- K0t: dcn_w [o][c*9+q] -> bf16 wA[o][q*256+c]
__global__ __launch_bounds__(256) void k0t(const float* __restrict__ dcn_w, u16* __restrict__ wA) {
  int tid = blockIdx.x * 256 + threadIdx.x;
  if (tid >= COUTC * CINC * 9) return;
  int o = tid / 2304;
  int ckr = tid - o * 2304;
  int q = ckr >> 8;
  int c = ckr & 255;
  wA[tid] = f2bf(dcn_w[o * 2304 + c * 9 + q]);
}

// ---------------- K0o: off_w -> hi/lo bf16 split, padded to 32 rows.
__global__ __launch_bounds__(256) void k0o(const float* __restrict__ off_w, u16* __restrict__ wOk) {
  int tid = blockIdx.x * 256 + threadIdx.x;
  if (tid >= 32 * 2304) return;
  int row = tid / 2304;
  int kr = tid - row * 2304;
  int q = kr >> 8, c = kr & 255;
  float w = (row < 27) ? off_w[(row * CINC + c) * 9 + q] : 0.f;
  u16 hi = f2bf(w);
  float hf = __uint_as_float((unsigned)hi << 16);
  u16 lo = f2bf(w - hf);
  wOk[tid] = hi;
  wOk[73728 + tid] = lo;
}

// ---------------- K4w: pack up_w into 4 parity-class bf16 A-matrices.
__global__ __launch_bounds__(256) void k4w(const float* __restrict__ up_w, u16* __restrict__ Apk) {
  int tid = blockIdx.x * 256 + threadIdx.x;
  if (tid >= 4 * COUTC * 512) return;
  int kp = tid & 511;
  int o = (tid >> 9) & 127;
  int pq = tid >> 16;
  int p = pq >> 1, q = pq & 1;
  int ky = kp >> 8, kx = (kp >> 7) & 1, i = kp & 127;
  float v = up_w[((i * COUTC + o) * 4 + (3 - (p + 2 * ky))) * 4 + (3 - (q + 2 * kx))];
  Apk[tid] = f2bf(v);
}

// ---------------- K2t: transpose x -> channel-last hi/lo bf16 planes only.
// (f32 xT dropped: k2m now gathers bf16 — halves its TA line traffic.)
__global__ __launch_bounds__(256) void k2t(const float* __restrict__ x,
                                           u16* __restrict__ xTh,
                                           u16* __restrict__ xTl) {
  int y = blockIdx.x, cq = blockIdx.y, b = blockIdx.z;
  __shared__ float tile[64][65];
  int t = threadIdx.x;
  int tx = t & 63;
  int tg = t >> 6;
#pragma unroll
  for (int i = 0; i < 16; i++) {
    int c = tg * 16 + i;
    tile[c][tx] = x[((size_t)(b * CINC + cq * 64 + c) * HH + y) * WW + tx];
  }
  __syncthreads();
#pragma unroll
  for (int i = 0; i < 16; i++) {
    int xc = tg * 16 + i;
    size_t idx = ((size_t)(b * HH + y) * WW + xc) * CINC + cq * 64 + tx;
    float v = tile[tx][xc];
    u16 hi = f2bf(v);
    float hf = __uint_as_float((unsigned)hi << 16);
    xTh[idx] = hi;
    xTl[idx] = f2bf(v - hf);
  }
}

// ---------------- K1m: offset conv as MFMA GEMM, split-C(4) partials.
__global__ __launch_bounds__(256) void k1m(const u16* __restrict__ xTh,
                                           const u16* __restrict__ xTl,
                                           const u16* __restrict__ wOk,
                                           float* __restrict__ part1) {
  int h = blockIdx.x, b = blockIdx.y, cs = blockIdx.z;
  int t = threadIdx.x;
  int pt = t >> 6;
  int lane15 = t & 15;
  int quad = (t >> 4) & 3;

  const u16* wh0 = wOk + (size_t)lane15 * 2304 + quad * 8;
  const u16* wh1 = wh0 + 16 * 2304;
  const u16* wl0 = wh0 + 73728;
  const u16* wl1 = wh1 + 73728;

  f32x4 acc[2];
  acc[0] = (f32x4){0.f, 0.f, 0.f, 0.f};
  acc[1] = (f32x4){0.f, 0.f, 0.f, 0.f};

  for (int q = 0; q < 9; q++) {
    int y = h + q / 3 - 1;
    if ((unsigned)y >= 64u) continue;
    int xc = pt * 16 + lane15 + (q % 3) - 1;
    bool xok = (unsigned)xc < 64u;
    int xcc = min(max(xc, 0), 63);
    size_t base = ((size_t)(b * 64 + y) * 64 + xcc) * 256 + cs * 64 + quad * 8;
    const u16* hsrc = xTh + base;
    const u16* lsrc = xTl + base;
#pragma unroll
    for (int c8 = 0; c8 < 2; c8++) {
      bf16x8 xh = *(const bf16x8*)(hsrc + c8 * 32);
      bf16x8 xl = *(const bf16x8*)(lsrc + c8 * 32);
      if (!xok) {
        xh = (bf16x8){0, 0, 0, 0, 0, 0, 0, 0};
        xl = (bf16x8){0, 0, 0, 0, 0, 0, 0, 0};
      }
      int kk = (q * 8 + cs * 2 + c8) * 32;
      bf16x8 ah0 = *(const bf16x8*)(wh0 + kk);
      bf16x8 ah1 = *(const bf16x8*)(wh1 + kk);
      bf16x8 al0 = *(const bf16x8*)(wl0 + kk);
      bf16x8 al1 = *(const bf16x8*)(wl1 + kk);
      acc[0] = __builtin_amdgcn_mfma_f32_16x16x32_bf16(ah0, xh, acc[0], 0, 0, 0);
      acc[0] = __builtin_amdgcn_mfma_f32_16x16x32_bf16(ah0, xl, acc[0], 0, 0, 0);
      acc[0] = __builtin_amdgcn_mfma_f32_16x16x32_bf16(al0, xh, acc[0], 0, 0, 0);
      acc[1] = __builtin_amdgcn_mfma_f32_16x16x32_bf16(ah1, xh, acc[1], 0, 0, 0);
      acc[1] = __builtin_amdgcn_mfma_f32_16x16x32_bf16(ah1, xl, acc[1], 0, 0, 0);
      acc[1] = __builtin_amdgcn_mfma_f32_16x16x32_bf16(al1, xh, acc[1], 0, 0, 0);
    }
  }

  int px = pt * 16 + lane15;
  float* pb = part1 + ((size_t)(cs * BB + b) * 32) * 4096 + h * 64 + px;
#pragma unroll
  for (int tr = 0; tr < 2; tr++)
#pragma unroll
    for (int i = 0; i < 4; i++) {
      int oc = tr * 16 + quad * 4 + i;
      pb[(size_t)oc * 4096] = acc[tr][i];
    }
}

// ---------------- K1r: reduce 4 channel-partials + bias -> py/px/m
__global__ __launch_bounds__(256) void k1r(const float* __restrict__ part1,
                                           const float* __restrict__ off_b,
                                           float* __restrict__ pyg,
                                           float* __restrict__ pxg,
                                           float* __restrict__ mg) {
  int tid = blockIdx.x * 256 + threadIdx.x;
  if (tid >= BB * 27 * HH * WW) return;
  int w = tid & 63;
  int h = (tid >> 6) & 63;
  int oc = (tid >> 12) % 27;
  int b = tid / (27 * 4096);
  int sp = tid & 4095;

  float v = off_b[oc];
#pragma unroll
  for (int cs = 0; cs < 4; cs++)
    v += part1[((size_t)(cs * BB + b) * 32 + oc) * 4096 + sp];

  int k = oc % 9;
  int gi = ((b * 9 + k) * HH + h) * WW + w;
  if (oc < 9) {
    pyg[gi] = v + (float)(oc / 3) - 1.f + (float)h;
  } else if (oc < 18) {
    pxg[gi] = v + (float)((oc - 9) % 3) - 1.f + (float)w;
  } else {
    mg[gi] = 1.f / (1.f + expf(-v));
  }
}

// ---------------- K2m: deformable conv, split-K(4), bf16 MFMA GEMM.
// Round-3 skeleton (LDS dbuf + barrier-pinned prefetch) with BF16 gathers from
// the xTh plane: TA/L1 address throughput is the measured limiter (144 divergent
// loads/thread invariant across r4/r8 at 87us) — bf16 halves bytes/lane ->
// 72 loads/thread (2x dwordx4 per 16-ch corner). Interp in f32 (bf16->f32 is a
// shift). x is pre-rounded to bf16 (adds <=1 ulp to sampled values).
__global__ __launch_bounds__(256) void k2m(const u16* __restrict__ xTh,
                                           const u16* __restrict__ wA,
                                           const float* __restrict__ pyg,
                                           const float* __restrict__ pxg,
                                           const float* __restrict__ mg,
                                           float* __restrict__ part2) {
  int ks = blockIdx.x, h = blockIdx.y, b = blockIdx.z;
  __shared__ __align__(16) u16 scolT[2][64 * 72];  // [px][ch 0..63 +8 pad] bf16
  int t = threadIdx.x;
  int px = t & 63;
  int wave = t >> 6;
  int lane15 = t & 15;
  int quad = (t >> 4) & 3;

  // ---- per-(q,px) bilinear descriptors (masked, m-premultiplied) ----
  float dw0[9], dw1[9], dw2[9], dw3[9];
  int doA[9], doB[9];
#pragma unroll
  for (int q = 0; q < 9; q++) {
    int gi = ((b * 9 + q) * HH + h) * WW + px;
    float py = pyg[gi], pxx = pxg[gi], m = mg[gi];
    float y0f = floorf(py), x0f = floorf(pxx);
    float wy = py - y0f, wx = pxx - x0f;
    int y0 = (int)y0f, x0 = (int)x0f;
    bool vy0 = (unsigned)y0 < 64u, vy1 = (unsigned)(y0 + 1) < 64u;
    bool vx0 = (unsigned)x0 < 64u, vx1 = (unsigned)(x0 + 1) < 64u;
    int y0c = min(max(y0, 0), 63), y1c = min(max(y0 + 1, 0), 63);
    int x0c = min(max(x0, 0), 63), x1c = min(max(x0 + 1, 0), 63);
    dw0[q] = (vy0 && vx0) ? (1.f - wy) * (1.f - wx) * m : 0.f;
    dw1[q] = (vy0 && vx1) ? (1.f - wy) * wx * m : 0.f;
    dw2[q] = (vy1 && vx0) ? wy * (1.f - wx) * m : 0.f;
    dw3[q] = (vy1 && vx1) ? wy * wx * m : 0.f;
    doA[q] = (y0c * 64 + x0c) | ((y0c * 64 + x1c) << 16);
    doB[q] = (y1c * 64 + x0c) | ((y1c * 64 + x1c) << 16);
  }

  f32x4 acc[8];
#pragma unroll
  for (int i = 0; i < 8; i++) acc[i] = (f32x4){0.f, 0.f, 0.f, 0.f};

  // thread's gather base: its 16-ch bf16 slice (32B per corner = 2 loads)
  const u16* xTb = xTh + (size_t)b * 4096 * CINC + ks * 64 + wave * 16;
  const u16* wAr0 = wA + (wave * 32 + lane15) * 2304 + quad * 8;
  const u16* wAr1 = wAr0 + 16 * 2304;

  bf16x8 rx[8];  // 4 corners x 16 ch (2 bf16x8 each)
#define GATHER_TAP(qq)                                                       \
  {                                                                          \
    int sA0 = doA[qq] & 0xffff, sA1 = ((unsigned)doA[qq]) >> 16;             \
    int sB0 = doB[qq] & 0xffff, sB1 = ((unsigned)doB[qq]) >> 16;             \
    const u16* p0 = xTb + (size_t)sA0 * CINC;                                \
    const u16* p1 = xTb + (size_t)sA1 * CINC;                                \
    const u16* p2 = xTb + (size_t)sB0 * CINC;                                \
    const u16* p3 = xTb + (size_t)sB1 * CINC;                                \
    rx[0] = *(const bf16x8*)p0;                                              \
    rx[1] = *(const bf16x8*)(p0 + 8);                                        \
    rx[2] = *(const bf16x8*)p1;                                              \
    rx[3] = *(const bf16x8*)(p1 + 8);                                        \
    rx[4] = *(const bf16x8*)p2;                                              \
    rx[5] = *(const bf16x8*)(p2 + 8);                                        \
    rx[6] = *(const bf16x8*)p3;                                              \
    rx[7] = *(const bf16x8*)(p3 + 8);                                        \
  }

  GATHER_TAP(0);

#pragma unroll
  for (int q = 0; q < 9; q++) {
    // combine prefetched corners (f32 interp) -> bf16 pack -> two b128 writes
    float v[16];
#pragma unroll
    for (int j = 0; j < 8; j++) {
      v[j] = dw0[q] * bf2f(rx[0][j]) + dw1[q] * bf2f(rx[2][j]) +
             dw2[q] * bf2f(rx[4][j]) + dw3[q] * bf2f(rx[6][j]);
      v[8 + j] = dw0[q] * bf2f(rx[1][j]) + dw1[q] * bf2f(rx[3][j]) +
                 dw2[q] * bf2f(rx[5][j]) + dw3[q] * bf2f(rx[7][j]);
    }
    u16* sb = &scolT[q & 1][px * 72 + wave * 16];
    uint4 s0, s1;
    s0.x = pk(v[0], v[1]);  s0.y = pk(v[2], v[3]);
    s0.z = pk(v[4], v[5]);  s0.w = pk(v[6], v[7]);
    s1.x = pk(v[8], v[9]);  s1.y = pk(v[10], v[11]);
    s1.z = pk(v[12], v[13]); s1.w = pk(v[14], v[15]);
    *(uint4*)sb = s0;
    *(uint4*)(sb + 8) = s1;

    // issue next tap's gathers (land during barrier+MFMA)
    if (q < 8) GATHER_TAP(q + 1);

    __syncthreads();  // buf[q&1] visible; prev reads of buf[(q-1)&1] drained
    // MFMA: both 32-ch chunks of this tap; 2 cout rows x 4 px tiles each
#pragma unroll
    for (int c32 = 0; c32 < 2; c32++) {
      int kb = q * 256 + ks * 64 + c32 * 32;
      bf16x8 a0 = *(const bf16x8*)(wAr0 + kb);
      bf16x8 a1 = *(const bf16x8*)(wAr1 + kb);
      const u16* sr = &scolT[q & 1][lane15 * 72 + c32 * 32 + quad * 8];
      bf16x8 b0 = *(const bf16x8*)(sr);
      bf16x8 b1 = *(const bf16x8*)(sr + 16 * 72);
      bf16x8 b2 = *(const bf16x8*)(sr + 32 * 72);
      bf16x8 b3 = *(const bf16x8*)(sr + 48 * 72);
      acc[0] = __builtin_amdgcn_mfma_f32_16x16x32_bf16(a0, b0, acc[0], 0, 0, 0);
      acc[1] = __builtin_amdgcn_mfma_f32_16x16x32_bf16(a0, b1, acc[1], 0, 0, 0);
      acc[2] = __builtin_amdgcn_mfma_f32_16x16x32_bf16(a0, b2, acc[2], 0, 0, 0);
      acc[3] = __builtin_amdgcn_mfma_f32_16x16x32_bf16(a0, b3, acc[3], 0, 0, 0);
      acc[4] = __builtin_amdgcn_mfma_f32_16x16x32_bf16(a1, b0, acc[4], 0, 0, 0);
      acc[5] = __builtin_amdgcn_mfma_f32_16x16x32_bf16(a1, b1, acc[5], 0, 0, 0);
      acc[6] = __builtin_amdgcn_mfma_f32_16x16x32_bf16(a1, b2, acc[6], 0, 0, 0);
      acc[7] = __builtin_amdgcn_mfma_f32_16x16x32_bf16(a1, b3, acc[7], 0, 0, 0);
    }
  }
#undef GATHER_TAP

  // write partials: part2[ks][b][o][h][w]; C/D: col=lane&15 (px), row=quad*4+i (o)
  float* pb = part2 + (size_t)ks * BB * COUTC * 4096;
#pragma unroll
  for (int tr = 0; tr < 2; tr++)
#pragma unroll
    for (int pc = 0; pc < 4; pc++) {
      f32x4 a = acc[tr * 4 + pc];
      int ob = wave * 32 + tr * 16 + quad * 4;
#pragma unroll
      for (int i = 0; i < 4; i++)
        pb[((b * COUTC + ob + i) * HH + h) * WW + pc * 16 + lane15] = a[i];
    }
}

// ---------------- K2r: sum 4 partials + bias -> out1
__global__ __launch_bounds__(256) void k2r(const float* __restrict__ part2,
                                           const float* __restrict__ dcn_b,
                                           float* __restrict__ out1) {
  int tid = blockIdx.x * 256 + threadIdx.x;
  if (tid >= BB * COUTC * HH * WW) return;
  int o = (tid >> 12) & 127;
  const int S = BB * COUTC * 4096;
  out1[tid] = part2[tid] + part2[tid + S] + part2[tid + 2 * S] + part2[tid + 3 * S] + dcn_b[o];
}

// ---------------- BN stats: single-pass split reduction (sum + sumsq).
template <int PLANEF4, int NCHUNK>
__global__ __launch_bounds__(256) void bn_part(const float* __restrict__ src,
                                               float* __restrict__ psum,
                                               float* __restrict__ pssq) {
  int c = blockIdx.x, chunk = blockIdx.y, t = threadIdx.x;
  constexpr int PER = (BB * PLANEF4) / NCHUNK;  // float4s per chunk
  float s = 0.f, s2 = 0.f;
#pragma unroll
  for (int i = 0; i < PER / 256; i++) {
    int f = chunk * PER + i * 256 + t;
    int b = f / PLANEF4;  // compile-time divisor -> shifts
    int sp = f - b * PLANEF4;
    const float4 v = *(const float4*)&src[((size_t)(b * COUTC + c) * PLANEF4 + sp) * 4];
    s += v.x + v.y + v.z + v.w;
    s2 += v.x * v.x + v.y * v.y + v.z * v.z + v.w * v.w;
  }
#pragma unroll
  for (int off = 32; off > 0; off >>= 1) {
    s += __shfl_down(s, off);
    s2 += __shfl_down(s2, off);
  }
  __shared__ float rs[4], rq[4];
  int wv = t >> 6;
  if ((t & 63) == 0) { rs[wv] = s; rq[wv] = s2; }
  __syncthreads();
  if (t == 0) {
    psum[c * NCHUNK + chunk] = rs[0] + rs[1] + rs[2] + rs[3];
    pssq[c * NCHUNK + chunk] = rq[0] + rq[1] + rq[2] + rq[3];
  }
}

// finalize: 1 block x 128 threads; per-channel scale/shift from partials
__global__ __launch_bounds__(128) void bn_fin(const float* __restrict__ psum,
                                              const float* __restrict__ pssq,
                                              const float* __restrict__ g,
                                              const float* __restrict__ bt,
                                              float* __restrict__ scale,
                                              float* __restrict__ shift,
                                              int nchunk, float invN) {
  int c = threadIdx.x;
  float S = 0.f, Q = 0.f;
  for (int i = 0; i < nchunk; i++) {
    S += psum[c * nchunk + i];
    Q += pssq[c * nchunk + i];
  }
  float mu = S * invN;
  float var = Q * invN - mu * mu;
  float sc = g[c] * rsqrtf(var + 1e-5f);
  scale[c] = sc;
  shift[c] = bt[c] - mu * sc;
}

// ---------------- K4a: bn1+relu apply, bf16 convert, channel-last transpose.
__global__ __launch_bounds__(256) void k4a(const float* __restrict__ out1,
                                           const float* __restrict__ s1,
                                           const float* __restrict__ sh1,
                                           u16* __restrict__ yT) {
  int m = blockIdx.x, b = blockIdx.y;
  __shared__ __align__(16) u16 T2[64 * 136];
  int t = threadIdx.x;
  for (int e = t; e < 2048; e += 256) {
    int w4 = e & 15, c = e >> 4;
    float4 r = *(const float4*)&out1[((b * COUTC + c) * HH + m) * WW + w4 * 4];
    float sc = s1[c], sh = sh1[c];
    T2[(w4 * 4 + 0) * 136 + c] = f2bf(fmaxf(fmaf(r.x, sc, sh), 0.f));
    T2[(w4 * 4 + 1) * 136 + c] = f2bf(fmaxf(fmaf(r.y, sc, sh), 0.f));
    T2[(w4 * 4 + 2) * 136 + c] = f2bf(fmaxf(fmaf(r.z, sc, sh), 0.f));
    T2[(w4 * 4 + 3) * 136 + c] = f2bf(fmaxf(fmaf(r.w, sc, sh), 0.f));
  }
  __syncthreads();
  for (int e = t; e < 1024; e += 256) {
    int g2 = e * 8;
    int w = g2 >> 7, i = g2 & 127;
    *(bf16x8*)&yT[((size_t)(b * 64 + m) * 64 + w) * 128 + i] =
        *(const bf16x8*)&T2[w * 136 + i];
  }
}

// ---------------- K4m: transposed conv as bf16 MFMA GEMM.
__global__ __launch_bounds__(256) void k4m(const u16* __restrict__ yT,
                                           const u16* __restrict__ Apk,
                                           float* __restrict__ out2) {
  int oh = blockIdx.x, b = blockIdx.y;
  int a = oh >> 1, p = oh & 1;
  __shared__ __align__(16) u16 T[2][66 * 136];
  int t = threadIdx.x;
  int wave = t >> 6, lane15 = t & 15, quad = (t >> 4) & 3;

  // zero border cols: 2 bufs x 2 cols x 128 ch
  for (int e = t; e < 512; e += 256) {
    int ky = e >> 8;
    int rem = e & 255;
    int colp = (rem >> 7) * 65;
    int i = rem & 127;
    T[ky][colp * 136 + i] = 0;
  }
  // stage both tap rows (r = a+p+ky-1); contiguous 16KB copy each
#pragma unroll
  for (int ky = 0; ky < 2; ky++) {
    int r = a + p + ky - 1;
    bool ok = ((unsigned)r < 64u);
    const u16* src = yT + ((size_t)(b * 64 + r) * 64) * 128;
#pragma unroll
    for (int it = 0; it < 4; it++) {
      int g2 = (it * 256 + t) * 8;
      int col = g2 >> 7, i = g2 & 127;
      bf16x8 v = (bf16x8){0, 0, 0, 0, 0, 0, 0, 0};
      if (ok) v = *(const bf16x8*)(src + g2);
      *(bf16x8*)&T[ky][(col + 1) * 136 + i] = v;
    }
  }
  __syncthreads();

  f32x4 acc[2][2][4];  // [q][tr][pc]
#pragma unroll
  for (int q = 0; q < 2; q++)
#pragma unroll
    for (int tr = 0; tr < 2; tr++)
#pragma unroll
      for (int pc = 0; pc < 4; pc++) acc[q][tr][pc] = (f32x4){0.f, 0.f, 0.f, 0.f};

  int row0 = wave * 32 + lane15;
  const u16* A0 = Apk + ((size_t)(p * 2 + 0) * 128) * 512;
  const u16* A1 = Apk + ((size_t)(p * 2 + 1) * 128) * 512;

#pragma unroll
  for (int ky = 0; ky < 2; ky++)
#pragma unroll
    for (int kx = 0; kx < 2; kx++)
#pragma unroll
      for (int c4 = 0; c4 < 4; c4++) {
        int kb = (ky * 2 + kx) * 128 + c4 * 32 + quad * 8;
        bf16x8 a00 = *(const bf16x8*)(A0 + (size_t)row0 * 512 + kb);
        bf16x8 a01 = *(const bf16x8*)(A0 + (size_t)(row0 + 16) * 512 + kb);
        bf16x8 a10 = *(const bf16x8*)(A1 + (size_t)row0 * 512 + kb);
        bf16x8 a11 = *(const bf16x8*)(A1 + (size_t)(row0 + 16) * 512 + kb);
        const u16* tb = &T[ky][(lane15 + kx) * 136 + c4 * 32 + quad * 8];
#pragma unroll
        for (int pc = 0; pc < 4; pc++) {
          bf16x8 b0 = *(const bf16x8*)(tb + (pc * 16) * 136);
          bf16x8 b1 = *(const bf16x8*)(tb + (pc * 16 + 1) * 136);
          acc[0][0][pc] = __builtin_amdgcn_mfma_f32_16x16x32_bf16(a00, b0, acc[0][0][pc], 0, 0, 0);
          acc[0][1][pc] = __builtin_amdgcn_mfma_f32_16x16x32_bf16(a01, b0, acc[0][1][pc], 0, 0, 0);
          acc[1][0][pc] = __builtin_amdgcn_mfma_f32_16x16x32_bf16(a10, b1, acc[1][0][pc], 0, 0, 0);
          acc[1][1][pc] = __builtin_amdgcn_mfma_f32_16x16x32_bf16(a11, b1, acc[1][1][pc], 0, 0, 0);
        }
      }

  // epilogue: C/D col=lane&15 (px), row=quad*4+i (cout). ow = 2*px + q -> float2.
#pragma unroll
  for (int tr = 0; tr < 2; tr++) {
    int o0 = wave * 32 + tr * 16 + quad * 4;
#pragma unroll
    for (int pc = 0; pc < 4; pc++) {
      f32x4 v0 = acc[0][tr][pc];
      f32x4 v1 = acc[1][tr][pc];
      int cw = pc * 32 + 2 * lane15;
#pragma unroll
      for (int i = 0; i < 4; i++) {
        float2 w2;
        w2.x = v0[i];
        w2.y = v1[i];
        *(float2*)&out2[(((size_t)b * COUTC + o0 + i) * OHH + oh) * OWW + cw] = w2;
      }
    }
  }
}

// ---------------- K6: bn2+relu apply (f32 out)
__global__ __launch_bounds__(256) void k6s(const float* __restrict__ out2,
                                           const float* __restrict__ scale2,
                                           const float* __restrict__ shift2,
                                           float* __restrict__ outp) {
  int tid = blockIdx.x * 256 + threadIdx.x;
  if (tid >= BB * COUTC * OHH * OWW) return;
  int c = (tid >> 14) & 127;
  outp[tid] = fmaxf(fmaf(out2[tid], scale2[c], shift2[c]), 0.f);
}

// ---------------- launch
extern "C" void kernel_launch(void* const* d_in, const int* in_sizes, int n_in,
                              void* d_out, int out_size, void* d_ws, size_t ws_size,
                              hipStream_t stream) {
  const float* x     = (const float*)d_in[0];
  const float* off_w = (const float*)d_in[1];
  const float* off_b = (const float*)d_in[2];
  const float* dcn_w = (const float*)d_in[3];
  const float* dcn_b = (const float*)d_in[4];
  const float* bn1_g = (const float*)d_in[5];
  const float* bn1_b = (const float*)d_in[6];
  const float* up_w  = (const float*)d_in[7];
  const float* bn2_g = (const float*)d_in[8];
  const float* bn2_b = (const float*)d_in[9];

  float* ws = (float*)d_ws;
  float* pyg  = ws;                              // 147456
  float* pxg  = pyg + BB * 9 * HH * WW;          // 147456
  float* mg   = pxg + BB * 9 * HH * WW;          // 147456
  float* out1 = mg + BB * 9 * HH * WW;           // 2097152
  float* scale1 = out1 + BB * COUTC * HH * WW;   // 128
  float* shift1 = scale1 + 128;                  // 128
  float* out2 = shift1 + 128;                    // 8388608
  float* scale2 = out2 + BB * COUTC * OHH * OWW; // 128
  float* shift2 = scale2 + 128;                  // 128
  float* w_t = shift2 + 128;                     // 294912 floats reserved
  float* wt4 = w_t + COUTC * CINC * 9;           // 262144 floats (Apk uses as u16)
  float* part2 = wt4 + 4 * COUTC * COUTC * 4;    // 4 * 2097152 floats
  u16* wA = (u16*)w_t;                           // 128*2304 bf16 (first half of w_t region)
  u16* wOk = (u16*)(w_t + 147456);               // 2*32*2304 bf16 hi/lo (second half)
  u16* Apk = (u16*)wt4;                          // 4*128*512 bf16 = 512KB
  // hi/lo bf16 planes of x in the out2 region (lifetime k2t..k2m; k2m reads xTh
  // while WRITING part2, so they must not live in the part2 region).
  u16* xTh = (u16*)out2;                         // 4.2M u16 = 2.1M floats
  u16* xTl = (u16*)(out2 + 2097152);             // 4.2M u16
  // offset-conv partials at part2 base (lifetime k1m..k1r, dead before k2m)
  float* part1 = part2;
  // bn stats partials overlaid on part2 start (lifetime after k2r)
  float* psum = part2;            // up to 128*16
  float* pssq = part2 + 128 * 16; // up to 128*16
  // yT (bf16 4MB) overlaid past the stats partials in the part2 region
  u16* yT = (u16*)(part2 + 8192);

  const int N4 = BB * COUTC * OHH * OWW;  // 8388608
  const int N2 = BB * COUTC * HH * WW;    // 2097152
  const int N1 = BB * 27 * HH * WW;       // 442368

  k0t<<<(COUTC * CINC * 9 + 255) / 256, 256, 0, stream>>>(dcn_w, wA);
  k0o<<<(32 * 2304 + 255) / 256, 256, 0, stream>>>(off_w, wOk);
  k4w<<<(4 * COUTC * 512 + 255) / 256, 256, 0, stream>>>(up_w, Apk);
  // channel-last transpose of x -> bf16 hi/lo planes (in out2 region)
  k2t<<<dim3(64, 4, 4), 256, 0, stream>>>(x, xTh, xTl);
  // offset conv via MFMA, split-C(4) partials, then reduce+bias+transform
  k1m<<<dim3(64, BB, 4), 256, 0, stream>>>(xTh, xTl, wOk, part1);
  k1r<<<(N1 + 255) / 256, 256, 0, stream>>>(part1, off_b, pyg, pxg, mg);
  // deformable conv via LDS-pipelined MFMA with bf16 gathers
  k2m<<<dim3(4, 64, 4), 256, 0, stream>>>(xTh, wA, pyg, pxg, mg, part2);
  k2r<<<(N2 + 255) / 256, 256, 0, stream>>>(part2, dcn_b, out1);
  // bn1 stats
  bn_part<1024, 8><<<dim3(COUTC, 8), 256, 0, stream>>>(out1, psum, pssq);
  bn_fin<<<1, 128, 0, stream>>>(psum, pssq, bn1_g, bn1_b, scale1, shift1, 8,
                                1.f / 16384.f);
  // bn1 apply + transpose to bf16 channel-last
  k4a<<<dim3(64, 4), 256, 0, stream>>>(out1, scale1, shift1, yT);
  // transposed conv via MFMA
  k4m<<<dim3(128, 4), 256, 0, stream>>>(yT, Apk, out2);
  // bn2 stats
  bn_part<4096, 16><<<dim3(COUTC, 16), 256, 0, stream>>>(out2, psum, pssq);
  bn_fin<<<1, 128, 0, stream>>>(psum, pssq, bn2_g, bn2_b, scale2, shift2, 16,
                                1.f / 65536.f);
  k6s<<<(N4 + 255) / 256, 256, 0, stream>>>(out2, scale2, shift2, (float*)d_out);
}

// Round 10
// 269.771 us; speedup vs baseline: 1.2672x; 1.0023x over previous
//
#include <hip/hip_runtime.h>
#include <math.h>

// Problem constants
#define BB 4
#define CINC 256
#define COUTC 128
#define HH 64
#define WW 64
#define OHH 128
#define OWW 128

typedef unsigned short u16;
typedef __attribute__((ext_vector_type(8))) short bf16x8;
typedef __attribute__((ext_vector_type(4))) float f32x4;

__device__ __forceinline__ u16 f2bf(float f) {
  unsigned int u = __float_as_uint(f);
  unsigned int r = u + 0x7FFFu + ((u >> 16) & 1u);  // RNE
  return (u16)(r >> 16);
}

__device__ __forceinline__ unsigned pk(float a, float b) {
  return (unsigned)f2bf(a) | ((unsigned)f2bf(b) << 16);
}

__device__ __forceinline__ float bf2f(short h) {
  return __uint_as_float(((unsigned)(unsigned short)h) << 16);
}

// ---------------- K0all: merged weight preprocessing (k0t + k0o + k4w).
// [0, 294912):        dcn_w -> bf16 wA[o][q*256+c]
// [294912, 368640):   off_w -> hi/lo bf16 wOk (padded to 32 rows)
// [368640, 630784):   up_w  -> 4 parity-class bf16 Apk
__global__ __launch_bounds__(256) void k0all(const float* __restrict__ dcn_w,
                                             const float* __restrict__ off_w,
                                             const float* __restrict__ up_w,
                                             u16* __restrict__ wA,
                                             u16* __restrict__ wOk,
                                             u16* __restrict__ Apk) {
  int tid = blockIdx.x * 256 + threadIdx.x;
  if (tid < 294912) {
    int o = tid / 2304;
    int ckr = tid - o * 2304;
    int q = ckr >> 8;
    int c = ckr & 255;
    wA[tid] = f2bf(dcn_w[o * 2304 + c * 9 + q]);
  } else if (tid < 368640) {
    int t2 = tid - 294912;
    int row = t2 / 2304;
    int kr = t2 - row * 2304;
    int q = kr >> 8, c = kr & 255;
    float w = (row < 27) ? off_w[(row * CINC + c) * 9 + q] : 0.f;
    u16 hi = f2bf(w);
    float hf = __uint_as_float((unsigned)hi << 16);
    wOk[t2] = hi;
    wOk[73728 + t2] = f2bf(w - hf);
  } else if (tid < 630784) {
    int t2 = tid - 368640;
    int kp = t2 & 511;
    int o = (t2 >> 9) & 127;
    int pq = t2 >> 16;
    int p = pq >> 1, q = pq & 1;
    int ky = kp >> 8, kx = (kp >> 7) & 1, i = kp & 127;
    float v = up_w[((i * COUTC + o) * 4 + (3 - (p + 2 * ky))) * 4 + (3 - (q + 2 * kx))];
    Apk[t2] = f2bf(v);
  }
}

// ---------------- Kinit: out1 = dcn_b[o] (accumulation base for k2m atomics)
__global__ __launch_bounds__(256) void kinit(const float* __restrict__ dcn_b,
                                             float* __restrict__ out1) {
  int tid = blockIdx.x * 256 + threadIdx.x;
  if (tid >= BB * COUTC * HH * WW) return;
  out1[tid] = dcn_b[(tid >> 12) & 127];
}

// ---------------- K2t: transpose x -> channel-last hi/lo bf16 planes only.
__global__ __launch_bounds__(256) void k2t(const float* __restrict__ x,
                                           u16* __restrict__ xTh,
                                           u16* __restrict__ xTl) {
  int y = blockIdx.x, cq = blockIdx.y, b = blockIdx.z;
  __shared__ float tile[64][65];
  int t = threadIdx.x;
  int tx = t & 63;
  int tg = t >> 6;
#pragma unroll
  for (int i = 0; i < 16; i++) {
    int c = tg * 16 + i;
    tile[c][tx] = x[((size_t)(b * CINC + cq * 64 + c) * HH + y) * WW + tx];
  }
  __syncthreads();
#pragma unroll
  for (int i = 0; i < 16; i++) {
    int xc = tg * 16 + i;
    size_t idx = ((size_t)(b * HH + y) * WW + xc) * CINC + cq * 64 + tx;
    float v = tile[tx][xc];
    u16 hi = f2bf(v);
    float hf = __uint_as_float((unsigned)hi << 16);
    xTh[idx] = hi;
    xTl[idx] = f2bf(v - hf);
  }
}

// ---------------- K1m: offset conv as MFMA GEMM, split-C(4) partials.
__global__ __launch_bounds__(256) void k1m(const u16* __restrict__ xTh,
                                           const u16* __restrict__ xTl,
                                           const u16* __restrict__ wOk,
                                           float* __restrict__ part1) {
  int h = blockIdx.x, b = blockIdx.y, cs = blockIdx.z;
  int t = threadIdx.x;
  int pt = t >> 6;
  int lane15 = t & 15;
  int quad = (t >> 4) & 3;

  const u16* wh0 = wOk + (size_t)lane15 * 2304 + quad * 8;
  const u16* wh1 = wh0 + 16 * 2304;
  const u16* wl0 = wh0 + 73728;
  const u16* wl1 = wh1 + 73728;

  f32x4 acc[2];
  acc[0] = (f32x4){0.f, 0.f, 0.f, 0.f};
  acc[1] = (f32x4){0.f, 0.f, 0.f, 0.f};

  for (int q = 0; q < 9; q++) {
    int y = h + q / 3 - 1;
    if ((unsigned)y >= 64u) continue;
    int xc = pt * 16 + lane15 + (q % 3) - 1;
    bool xok = (unsigned)xc < 64u;
    int xcc = min(max(xc, 0), 63);
    size_t base = ((size_t)(b * 64 + y) * 64 + xcc) * 256 + cs * 64 + quad * 8;
    const u16* hsrc = xTh + base;
    const u16* lsrc = xTl + base;
#pragma unroll
    for (int c8 = 0; c8 < 2; c8++) {
      bf16x8 xh = *(const bf16x8*)(hsrc + c8 * 32);
      bf16x8 xl = *(const bf16x8*)(lsrc + c8 * 32);
      if (!xok) {
        xh = (bf16x8){0, 0, 0, 0, 0, 0, 0, 0};
        xl = (bf16x8){0, 0, 0, 0, 0, 0, 0, 0};
      }
      int kk = (q * 8 + cs * 2 + c8) * 32;
      bf16x8 ah0 = *(const bf16x8*)(wh0 + kk);
      bf16x8 ah1 = *(const bf16x8*)(wh1 + kk);
      bf16x8 al0 = *(const bf16x8*)(wl0 + kk);
      bf16x8 al1 = *(const bf16x8*)(wl1 + kk);
      acc[0] = __builtin_amdgcn_mfma_f32_16x16x32_bf16(ah0, xh, acc[0], 0, 0, 0);
      acc[0] = __builtin_amdgcn_mfma_f32_16x16x32_bf16(ah0, xl, acc[0], 0, 0, 0);
      acc[0] = __builtin_amdgcn_mfma_f32_16x16x32_bf16(al0, xh, acc[0], 0, 0, 0);
      acc[1] = __builtin_amdgcn_mfma_f32_16x16x32_bf16(ah1, xh, acc[1], 0, 0, 0);
      acc[1] = __builtin_amdgcn_mfma_f32_16x16x32_bf16(ah1, xl, acc[1], 0, 0, 0);
      acc[1] = __builtin_amdgcn_mfma_f32_16x16x32_bf16(al1, xh, acc[1], 0, 0, 0);
    }
  }

  int px = pt * 16 + lane15;
  float* pb = part1 + ((size_t)(cs * BB + b) * 32) * 4096 + h * 64 + px;
#pragma unroll
  for (int tr = 0; tr < 2; tr++)
#pragma unroll
    for (int i = 0; i < 4; i++) {
      int oc = tr * 16 + quad * 4 + i;
      pb[(size_t)oc * 4096] = acc[tr][i];
    }
}

// ---------------- K1r: reduce 4 channel-partials + bias -> py/px/m
__global__ __launch_bounds__(256) void k1r(const float* __restrict__ part1,
                                           const float* __restrict__ off_b,
                                           float* __restrict__ pyg,
                                           float* __restrict__ pxg,
                                           float* __restrict__ mg) {
  int tid = blockIdx.x * 256 + threadIdx.x;
  if (tid >= BB * 27 * HH * WW) return;
  int w = tid & 63;
  int h = (tid >> 6) & 63;
  int oc = (tid >> 12) % 27;
  int b = tid / (27 * 4096);
  int sp = tid & 4095;

  float v = off_b[oc];
#pragma unroll
  for (int cs = 0; cs < 4; cs++)
    v += part1[((size_t)(cs * BB + b) * 32 + oc) * 4096 + sp];

  int k = oc % 9;
  int gi = ((b * 9 + k) * HH + h) * WW + w;
  if (oc < 9) {
    pyg[gi] = v + (float)(oc / 3) - 1.f + (float)h;
  } else if (oc < 18) {
    pxg[gi] = v + (float)((oc - 9) % 3) - 1.f + (float)w;
  } else {
    mg[gi] = 1.f / (1.f + expf(-v));
  }
}

// ---------------- K2m: deformable conv, split-K(4), bf16 MFMA GEMM.
// Proven LDS-dbuf + barrier-pinned prefetch skeleton with bf16 gathers (58.4us).
// Epilogue now ACCUMULATES into out1 via f32 atomicAdd (out1 pre-set to bias by
// kinit) — deletes the part2 write + k2r read/write pass entirely.
__global__ __launch_bounds__(256) void k2m(const u16* __restrict__ xTh,
                                           const u16* __restrict__ wA,
                                           const float* __restrict__ pyg,
                                           const float* __restrict__ pxg,
                                           const float* __restrict__ mg,
                                           float* __restrict__ out1) {
  int ks = blockIdx.x, h = blockIdx.y, b = blockIdx.z;
  __shared__ __align__(16) u16 scolT[2][64 * 72];  // [px][ch 0..63 +8 pad] bf16
  int t = threadIdx.x;
  int px = t & 63;
  int wave = t >> 6;
  int lane15 = t & 15;
  int quad = (t >> 4) & 3;

  // ---- per-(q,px) bilinear descriptors (masked, m-premultiplied) ----
  float dw0[9], dw1[9], dw2[9], dw3[9];
  int doA[9], doB[9];
#pragma unroll
  for (int q = 0; q < 9; q++) {
    int gi = ((b * 9 + q) * HH + h) * WW + px;
    float py = pyg[gi], pxx = pxg[gi], m = mg[gi];
    float y0f = floorf(py), x0f = floorf(pxx);
    float wy = py - y0f, wx = pxx - x0f;
    int y0 = (int)y0f, x0 = (int)x0f;
    bool vy0 = (unsigned)y0 < 64u, vy1 = (unsigned)(y0 + 1) < 64u;
    bool vx0 = (unsigned)x0 < 64u, vx1 = (unsigned)(x0 + 1) < 64u;
    int y0c = min(max(y0, 0), 63), y1c = min(max(y0 + 1, 0), 63);
    int x0c = min(max(x0, 0), 63), x1c = min(max(x0 + 1, 0), 63);
    dw0[q] = (vy0 && vx0) ? (1.f - wy) * (1.f - wx) * m : 0.f;
    dw1[q] = (vy0 && vx1) ? (1.f - wy) * wx * m : 0.f;
    dw2[q] = (vy1 && vx0) ? wy * (1.f - wx) * m : 0.f;
    dw3[q] = (vy1 && vx1) ? wy * wx * m : 0.f;
    doA[q] = (y0c * 64 + x0c) | ((y0c * 64 + x1c) << 16);
    doB[q] = (y1c * 64 + x0c) | ((y1c * 64 + x1c) << 16);
  }

  f32x4 acc[8];
#pragma unroll
  for (int i = 0; i < 8; i++) acc[i] = (f32x4){0.f, 0.f, 0.f, 0.f};

  // thread's gather base: its 16-ch bf16 slice (32B per corner = 2 loads)
  const u16* xTb = xTh + (size_t)b * 4096 * CINC + ks * 64 + wave * 16;
  const u16* wAr0 = wA + (wave * 32 + lane15) * 2304 + quad * 8;
  const u16* wAr1 = wAr0 + 16 * 2304;

  bf16x8 rx[8];  // 4 corners x 16 ch (2 bf16x8 each)
#define GATHER_TAP(qq)                                                       \
  {                                                                          \
    int sA0 = doA[qq] & 0xffff, sA1 = ((unsigned)doA[qq]) >> 16;             \
    int sB0 = doB[qq] & 0xffff, sB1 = ((unsigned)doB[qq]) >> 16;             \
    const u16* p0 = xTb + (size_t)sA0 * CINC;                                \
    const u16* p1 = xTb + (size_t)sA1 * CINC;                                \
    const u16* p2 = xTb + (size_t)sB0 * CINC;                                \
    const u16* p3 = xTb + (size_t)sB1 * CINC;                                \
    rx[0] = *(const bf16x8*)p0;                                              \
    rx[1] = *(const bf16x8*)(p0 + 8);                                        \
    rx[2] = *(const bf16x8*)p1;                                              \
    rx[3] = *(const bf16x8*)(p1 + 8);                                        \
    rx[4] = *(const bf16x8*)p2;                                              \
    rx[5] = *(const bf16x8*)(p2 + 8);                                        \
    rx[6] = *(const bf16x8*)p3;                                              \
    rx[7] = *(const bf16x8*)(p3 + 8);                                        \
  }

  GATHER_TAP(0);

#pragma unroll
  for (int q = 0; q < 9; q++) {
    // combine prefetched corners (f32 interp) -> bf16 pack -> two b128 writes
    float v[16];
#pragma unroll
    for (int j = 0; j < 8; j++) {
      v[j] = dw0[q] * bf2f(rx[0][j]) + dw1[q] * bf2f(rx[2][j]) +
             dw2[q] * bf2f(rx[4][j]) + dw3[q] * bf2f(rx[6][j]);
      v[8 + j] = dw0[q] * bf2f(rx[1][j]) + dw1[q] * bf2f(rx[3][j]) +
                 dw2[q] * bf2f(rx[5][j]) + dw3[q] * bf2f(rx[7][j]);
    }
    u16* sb = &scolT[q & 1][px * 72 + wave * 16];
    uint4 s0, s1;
    s0.x = pk(v[0], v[1]);  s0.y = pk(v[2], v[3]);
    s0.z = pk(v[4], v[5]);  s0.w = pk(v[6], v[7]);
    s1.x = pk(v[8], v[9]);  s1.y = pk(v[10], v[11]);
    s1.z = pk(v[12], v[13]); s1.w = pk(v[14], v[15]);
    *(uint4*)sb = s0;
    *(uint4*)(sb + 8) = s1;

    // issue next tap's gathers (land during barrier+MFMA)
    if (q < 8) GATHER_TAP(q + 1);

    __syncthreads();  // buf[q&1] visible; prev reads of buf[(q-1)&1] drained
    // MFMA: both 32-ch chunks of this tap; 2 cout rows x 4 px tiles each
#pragma unroll
    for (int c32 = 0; c32 < 2; c32++) {
      int kb = q * 256 + ks * 64 + c32 * 32;
      bf16x8 a0 = *(const bf16x8*)(wAr0 + kb);
      bf16x8 a1 = *(const bf16x8*)(wAr1 + kb);
      const u16* sr = &scolT[q & 1][lane15 * 72 + c32 * 32 + quad * 8];
      bf16x8 b0 = *(const bf16x8*)(sr);
      bf16x8 b1 = *(const bf16x8*)(sr + 16 * 72);
      bf16x8 b2 = *(const bf16x8*)(sr + 32 * 72);
      bf16x8 b3 = *(const bf16x8*)(sr + 48 * 72);
      acc[0] = __builtin_amdgcn_mfma_f32_16x16x32_bf16(a0, b0, acc[0], 0, 0, 0);
      acc[1] = __builtin_amdgcn_mfma_f32_16x16x32_bf16(a0, b1, acc[1], 0, 0, 0);
      acc[2] = __builtin_amdgcn_mfma_f32_16x16x32_bf16(a0, b2, acc[2], 0, 0, 0);
      acc[3] = __builtin_amdgcn_mfma_f32_16x16x32_bf16(a0, b3, acc[3], 0, 0, 0);
      acc[4] = __builtin_amdgcn_mfma_f32_16x16x32_bf16(a1, b0, acc[4], 0, 0, 0);
      acc[5] = __builtin_amdgcn_mfma_f32_16x16x32_bf16(a1, b1, acc[5], 0, 0, 0);
      acc[6] = __builtin_amdgcn_mfma_f32_16x16x32_bf16(a1, b2, acc[6], 0, 0, 0);
      acc[7] = __builtin_amdgcn_mfma_f32_16x16x32_bf16(a1, b3, acc[7], 0, 0, 0);
    }
  }
#undef GATHER_TAP

  // epilogue: accumulate into out1 (pre-initialized with dcn_b) via atomicAdd.
  // C/D: col=lane&15 (px), row=quad*4+i (o)
#pragma unroll
  for (int tr = 0; tr < 2; tr++)
#pragma unroll
    for (int pc = 0; pc < 4; pc++) {
      f32x4 a = acc[tr * 4 + pc];
      int ob = wave * 32 + tr * 16 + quad * 4;
#pragma unroll
      for (int i = 0; i < 4; i++)
        atomicAdd(&out1[((b * COUTC + ob + i) * HH + h) * WW + pc * 16 + lane15], a[i]);
    }
}

// ---------------- BN stats: single-pass split reduction (sum + sumsq).
template <int PLANEF4, int NCHUNK>
__global__ __launch_bounds__(256) void bn_part(const float* __restrict__ src,
                                               float* __restrict__ psum,
                                               float* __restrict__ pssq) {
  int c = blockIdx.x, chunk = blockIdx.y, t = threadIdx.x;
  constexpr int PER = (BB * PLANEF4) / NCHUNK;  // float4s per chunk
  float s = 0.f, s2 = 0.f;
#pragma unroll
  for (int i = 0; i < PER / 256; i++) {
    int f = chunk * PER + i * 256 + t;
    int b = f / PLANEF4;  // compile-time divisor -> shifts
    int sp = f - b * PLANEF4;
    const float4 v = *(const float4*)&src[((size_t)(b * COUTC + c) * PLANEF4 + sp) * 4];
    s += v.x + v.y + v.z + v.w;
    s2 += v.x * v.x + v.y * v.y + v.z * v.z + v.w * v.w;
  }
#pragma unroll
  for (int off = 32; off > 0; off >>= 1) {
    s += __shfl_down(s, off);
    s2 += __shfl_down(s2, off);
  }
  __shared__ float rs[4], rq[4];
  int wv = t >> 6;
  if ((t & 63) == 0) { rs[wv] = s; rq[wv] = s2; }
  __syncthreads();
  if (t == 0) {
    psum[c * NCHUNK + chunk] = rs[0] + rs[1] + rs[2] + rs[3];
    pssq[c * NCHUNK + chunk] = rq[0] + rq[1] + rq[2] + rq[3];
  }
}

// finalize: block-per-channel (grid 128 x 256 thr) — parallel partial reduce
__global__ __launch_bounds__(256) void bn_fin(const float* __restrict__ psum,
                                              const float* __restrict__ pssq,
                                              const float* __restrict__ g,
                                              const float* __restrict__ bt,
                                              float* __restrict__ scale,
                                              float* __restrict__ shift,
                                              int nchunk, float invN) {
  int c = blockIdx.x, t = threadIdx.x;
  float S = 0.f, Q = 0.f;
  for (int i = t; i < nchunk; i += 256) {
    S += psum[c * nchunk + i];
    Q += pssq[c * nchunk + i];
  }
#pragma unroll
  for (int off = 32; off > 0; off >>= 1) {
    S += __shfl_down(S, off);
    Q += __shfl_down(Q, off);
  }
  __shared__ float rs[4], rq[4];
  int wv = t >> 6;
  if ((t & 63) == 0) { rs[wv] = S; rq[wv] = Q; }
  __syncthreads();
  if (t == 0) {
    S = rs[0] + rs[1] + rs[2] + rs[3];
    Q = rq[0] + rq[1] + rq[2] + rq[3];
    float mu = S * invN;
    float var = Q * invN - mu * mu;
    float sc = g[c] * rsqrtf(var + 1e-5f);
    scale[c] = sc;
    shift[c] = bt[c] - mu * sc;
  }
}

// ---------------- K4a: bn1+relu apply, bf16 convert, channel-last transpose.
__global__ __launch_bounds__(256) void k4a(const float* __restrict__ out1,
                                           const float* __restrict__ s1,
                                           const float* __restrict__ sh1,
                                           u16* __restrict__ yT) {
  int m = blockIdx.x, b = blockIdx.y;
  __shared__ __align__(16) u16 T2[64 * 136];
  int t = threadIdx.x;
  for (int e = t; e < 2048; e += 256) {
    int w4 = e & 15, c = e >> 4;
    float4 r = *(const float4*)&out1[((b * COUTC + c) * HH + m) * WW + w4 * 4];
    float sc = s1[c], sh = sh1[c];
    T2[(w4 * 4 + 0) * 136 + c] = f2bf(fmaxf(fmaf(r.x, sc, sh), 0.f));
    T2[(w4 * 4 + 1) * 136 + c] = f2bf(fmaxf(fmaf(r.y, sc, sh), 0.f));
    T2[(w4 * 4 + 2) * 136 + c] = f2bf(fmaxf(fmaf(r.z, sc, sh), 0.f));
    T2[(w4 * 4 + 3) * 136 + c] = f2bf(fmaxf(fmaf(r.w, sc, sh), 0.f));
  }
  __syncthreads();
  for (int e = t; e < 1024; e += 256) {
    int g2 = e * 8;
    int w = g2 >> 7, i = g2 & 127;
    *(bf16x8*)&yT[((size_t)(b * 64 + m) * 64 + w) * 128 + i] =
        *(const bf16x8*)&T2[w * 136 + i];
  }
}

// ---------------- K4m: transposed conv as bf16 MFMA GEMM + fused bn2 partials.
__global__ __launch_bounds__(256) void k4m(const u16* __restrict__ yT,
                                           const u16* __restrict__ Apk,
                                           float* __restrict__ out2,
                                           float* __restrict__ psum2,
                                           float* __restrict__ pssq2) {
  int oh = blockIdx.x, b = blockIdx.y;
  int a = oh >> 1, p = oh & 1;
  __shared__ __align__(16) u16 T[2][66 * 136];
  int t = threadIdx.x;
  int wave = t >> 6, lane15 = t & 15, quad = (t >> 4) & 3;

  // zero border cols: 2 bufs x 2 cols x 128 ch
  for (int e = t; e < 512; e += 256) {
    int ky = e >> 8;
    int rem = e & 255;
    int colp = (rem >> 7) * 65;
    int i = rem & 127;
    T[ky][colp * 136 + i] = 0;
  }
  // stage both tap rows (r = a+p+ky-1); contiguous 16KB copy each
#pragma unroll
  for (int ky = 0; ky < 2; ky++) {
    int r = a + p + ky - 1;
    bool ok = ((unsigned)r < 64u);
    const u16* src = yT + ((size_t)(b * 64 + r) * 64) * 128;
#pragma unroll
    for (int it = 0; it < 4; it++) {
      int g2 = (it * 256 + t) * 8;
      int col = g2 >> 7, i = g2 & 127;
      bf16x8 v = (bf16x8){0, 0, 0, 0, 0, 0, 0, 0};
      if (ok) v = *(const bf16x8*)(src + g2);
      *(bf16x8*)&T[ky][(col + 1) * 136 + i] = v;
    }
  }
  __syncthreads();

  f32x4 acc[2][2][4];  // [q][tr][pc]
#pragma unroll
  for (int q = 0; q < 2; q++)
#pragma unroll
    for (int tr = 0; tr < 2; tr++)
#pragma unroll
      for (int pc = 0; pc < 4; pc++) acc[q][tr][pc] = (f32x4){0.f, 0.f, 0.f, 0.f};

  int row0 = wave * 32 + lane15;
  const u16* A0 = Apk + ((size_t)(p * 2 + 0) * 128) * 512;
  const u16* A1 = Apk + ((size_t)(p * 2 + 1) * 128) * 512;

#pragma unroll
  for (int ky = 0; ky < 2; ky++)
#pragma unroll
    for (int kx = 0; kx < 2; kx++)
#pragma unroll
      for (int c4 = 0; c4 < 4; c4++) {
        int kb = (ky * 2 + kx) * 128 + c4 * 32 + quad * 8;
        bf16x8 a00 = *(const bf16x8*)(A0 + (size_t)row0 * 512 + kb);
        bf16x8 a01 = *(const bf16x8*)(A0 + (size_t)(row0 + 16) * 512 + kb);
        bf16x8 a10 = *(const bf16x8*)(A1 + (size_t)row0 * 512 + kb);
        bf16x8 a11 = *(const bf16x8*)(A1 + (size_t)(row0 + 16) * 512 + kb);
        const u16* tb = &T[ky][(lane15 + kx) * 136 + c4 * 32 + quad * 8];
#pragma unroll
        for (int pc = 0; pc < 4; pc++) {
          bf16x8 b0 = *(const bf16x8*)(tb + (pc * 16) * 136);
          bf16x8 b1 = *(const bf16x8*)(tb + (pc * 16 + 1) * 136);
          acc[0][0][pc] = __builtin_amdgcn_mfma_f32_16x16x32_bf16(a00, b0, acc[0][0][pc], 0, 0, 0);
          acc[0][1][pc] = __builtin_amdgcn_mfma_f32_16x16x32_bf16(a01, b0, acc[0][1][pc], 0, 0, 0);
          acc[1][0][pc] = __builtin_amdgcn_mfma_f32_16x16x32_bf16(a10, b1, acc[1][0][pc], 0, 0, 0);
          acc[1][1][pc] = __builtin_amdgcn_mfma_f32_16x16x32_bf16(a11, b1, acc[1][1][pc], 0, 0, 0);
        }
      }

  // epilogue: C/D col=lane&15 (px), row=quad*4+i (cout). ow = 2*px + q -> float2.
#pragma unroll
  for (int tr = 0; tr < 2; tr++) {
    int o0 = wave * 32 + tr * 16 + quad * 4;
#pragma unroll
    for (int pc = 0; pc < 4; pc++) {
      f32x4 v0 = acc[0][tr][pc];
      f32x4 v1 = acc[1][tr][pc];
      int cw = pc * 32 + 2 * lane15;
#pragma unroll
      for (int i = 0; i < 4; i++) {
        float2 w2;
        w2.x = v0[i];
        w2.y = v1[i];
        *(float2*)&out2[(((size_t)b * COUTC + o0 + i) * OHH + oh) * OWW + cw] = w2;
      }
    }
  }

  // fused bn2 partial stats: this block covers all 128 ch x 128 ow of row oh.
  // Per thread, channel (tr,i): 8 values (2q x 4pc). Reduce across the 16
  // lane15s (shfl_xor 1/2/4/8 stays within the quad's 16-lane group).
  int blk = b * 128 + oh;  // 512 partials per channel
#pragma unroll
  for (int tr = 0; tr < 2; tr++)
#pragma unroll
    for (int i = 0; i < 4; i++) {
      float s = 0.f, s2 = 0.f;
#pragma unroll
      for (int q = 0; q < 2; q++)
#pragma unroll
        for (int pc = 0; pc < 4; pc++) {
          float v = acc[q][tr][pc][i];
          s += v;
          s2 += v * v;
        }
#pragma unroll
      for (int off = 1; off < 16; off <<= 1) {
        s += __shfl_xor(s, off);
        s2 += __shfl_xor(s2, off);
      }
      if (lane15 == 0) {
        int c = wave * 32 + tr * 16 + quad * 4 + i;
        psum2[c * 512 + blk] = s;
        pssq2[c * 512 + blk] = s2;
      }
    }
}

// ---------------- K6: bn2+relu apply (f32 out)
__global__ __launch_bounds__(256) void k6s(const float* __restrict__ out2,
                                           const float* __restrict__ scale2,
                                           const float* __restrict__ shift2,
                                           float* __restrict__ outp) {
  int tid = blockIdx.x * 256 + threadIdx.x;
  if (tid >= BB * COUTC * OHH * OWW) return;
  int c = (tid >> 14) & 127;
  outp[tid] = fmaxf(fmaf(out2[tid], scale2[c], shift2[c]), 0.f);
}

// ---------------- launch
extern "C" void kernel_launch(void* const* d_in, const int* in_sizes, int n_in,
                              void* d_out, int out_size, void* d_ws, size_t ws_size,
                              hipStream_t stream) {
  const float* x     = (const float*)d_in[0];
  const float* off_w = (const float*)d_in[1];
  const float* off_b = (const float*)d_in[2];
  const float* dcn_w = (const float*)d_in[3];
  const float* dcn_b = (const float*)d_in[4];
  const float* bn1_g = (const float*)d_in[5];
  const float* bn1_b = (const float*)d_in[6];
  const float* up_w  = (const float*)d_in[7];
  const float* bn2_g = (const float*)d_in[8];
  const float* bn2_b = (const float*)d_in[9];

  float* ws = (float*)d_ws;
  float* pyg  = ws;                              // 147456
  float* pxg  = pyg + BB * 9 * HH * WW;          // 147456
  float* mg   = pxg + BB * 9 * HH * WW;          // 147456
  float* out1 = mg + BB * 9 * HH * WW;           // 2097152
  float* scale1 = out1 + BB * COUTC * HH * WW;   // 128
  float* shift1 = scale1 + 128;                  // 128
  float* out2 = shift1 + 128;                    // 8388608
  float* scale2 = out2 + BB * COUTC * OHH * OWW; // 128
  float* shift2 = scale2 + 128;                  // 128
  float* w_t = shift2 + 128;                     // 294912 floats reserved
  float* wt4 = w_t + COUTC * CINC * 9;           // 262144 floats (Apk uses as u16)
  float* part2 = wt4 + 4 * COUTC * COUTC * 4;    // 4 * 2097152 floats (scratch)
  u16* wA = (u16*)w_t;                           // 128*2304 bf16 (first half of w_t region)
  u16* wOk = (u16*)(w_t + 147456);               // 2*32*2304 bf16 hi/lo (second half)
  u16* Apk = (u16*)wt4;                          // 4*128*512 bf16 = 512KB
  // hi/lo bf16 planes of x in the out2 region (lifetime k2t..k2m; k2m writes
  // out1 now, so the out2 region is free until k4m).
  u16* xTh = (u16*)out2;                         // 4.2M u16 = 2.1M floats
  u16* xTl = (u16*)(out2 + 2097152);             // 4.2M u16
  // scratch region layout (part2):
  float* psum = part2;                           // up to 128*512 = 65536
  float* pssq = part2 + 65536;                   // up to 65536
  u16* yT = (u16*)(part2 + 131072);              // bf16 4MB (k4a -> k4m)
  float* part1 = part2 + 131072 + 2097152;       // 4*4*32*4096 = 2.1M floats

  const int N4 = BB * COUTC * OHH * OWW;  // 8388608
  const int N2 = BB * COUTC * HH * WW;    // 2097152
  const int N1 = BB * 27 * HH * WW;       // 442368

  // merged weight preprocessing
  k0all<<<(630784 + 255) / 256, 256, 0, stream>>>(dcn_w, off_w, up_w, wA, wOk, Apk);
  // out1 = bias (accumulation base for k2m atomics)
  kinit<<<(N2 + 255) / 256, 256, 0, stream>>>(dcn_b, out1);
  // channel-last transpose of x -> bf16 hi/lo planes (in out2 region)
  k2t<<<dim3(64, 4, 4), 256, 0, stream>>>(x, xTh, xTl);
  // offset conv via MFMA, split-C(4) partials, then reduce+bias+transform
  k1m<<<dim3(64, BB, 4), 256, 0, stream>>>(xTh, xTl, wOk, part1);
  k1r<<<(N1 + 255) / 256, 256, 0, stream>>>(part1, off_b, pyg, pxg, mg);
  // deformable conv via LDS-pipelined MFMA with bf16 gathers; atomic -> out1
  k2m<<<dim3(4, 64, 4), 256, 0, stream>>>(xTh, wA, pyg, pxg, mg, out1);
  // bn1 stats
  bn_part<1024, 8><<<dim3(COUTC, 8), 256, 0, stream>>>(out1, psum, pssq);
  bn_fin<<<COUTC, 256, 0, stream>>>(psum, pssq, bn1_g, bn1_b, scale1, shift1, 8,
                                    1.f / 16384.f);
  // bn1 apply + transpose to bf16 channel-last
  k4a<<<dim3(64, 4), 256, 0, stream>>>(out1, scale1, shift1, yT);
  // transposed conv via MFMA + fused bn2 partial stats
  k4m<<<dim3(128, 4), 256, 0, stream>>>(yT, Apk, out2, psum, pssq);
  bn_fin<<<COUTC, 256, 0, stream>>>(psum, pssq, bn2_g, bn2_b, scale2, shift2, 512,
                                    1.f / 65536.f);
  k6s<<<(N4 + 255) / 256, 256, 0, stream>>>(out2, scale2, shift2, (float*)d_out);
}

// Round 11
// 261.348 us; speedup vs baseline: 1.3081x; 1.0322x over previous
//
#include <hip/hip_runtime.h>
#include <math.h>

// Problem constants
#define BB 4
#define CINC 256
#define COUTC 128
#define HH 64
#define WW 64
#define OHH 128
#define OWW 128

typedef unsigned short u16;
typedef __attribute__((ext_vector_type(8))) short bf16x8;
typedef __attribute__((ext_vector_type(4))) float f32x4;

__device__ __forceinline__ u16 f2bf(float f) {
  unsigned int u = __float_as_uint(f);
  unsigned int r = u + 0x7FFFu + ((u >> 16) & 1u);  // RNE
  return (u16)(r >> 16);
}

__device__ __forceinline__ unsigned pk(float a, float b) {
  return (unsigned)f2bf(a) | ((unsigned)f2bf(b) << 16);
}

__device__ __forceinline__ float bf2f(short h) {
  return __uint_as_float(((unsigned)(unsigned short)h) << 16);
}

// ---------------- K0all: merged weight preprocessing + out1 bias init.
// [0, 294912):        dcn_w -> bf16 wA[o][q*256+c]
// [294912, 368640):   off_w -> hi/lo bf16 wOk (padded to 32 rows)
// [368640, 630784):   up_w  -> 4 parity-class bf16 Apk
// [630784, 630784+2097152): out1 = dcn_b (accumulation base for k2m atomics)
__global__ __launch_bounds__(256) void k0all(const float* __restrict__ dcn_w,
                                             const float* __restrict__ off_w,
                                             const float* __restrict__ up_w,
                                             const float* __restrict__ dcn_b,
                                             u16* __restrict__ wA,
                                             u16* __restrict__ wOk,
                                             u16* __restrict__ Apk,
                                             float* __restrict__ out1) {
  int tid = blockIdx.x * 256 + threadIdx.x;
  if (tid < 294912) {
    int o = tid / 2304;
    int ckr = tid - o * 2304;
    int q = ckr >> 8;
    int c = ckr & 255;
    wA[tid] = f2bf(dcn_w[o * 2304 + c * 9 + q]);
  } else if (tid < 368640) {
    int t2 = tid - 294912;
    int row = t2 / 2304;
    int kr = t2 - row * 2304;
    int q = kr >> 8, c = kr & 255;
    float w = (row < 27) ? off_w[(row * CINC + c) * 9 + q] : 0.f;
    u16 hi = f2bf(w);
    float hf = __uint_as_float((unsigned)hi << 16);
    wOk[t2] = hi;
    wOk[73728 + t2] = f2bf(w - hf);
  } else if (tid < 630784) {
    int t2 = tid - 368640;
    int kp = t2 & 511;
    int o = (t2 >> 9) & 127;
    int pq = t2 >> 16;
    int p = pq >> 1, q = pq & 1;
    int ky = kp >> 8, kx = (kp >> 7) & 1, i = kp & 127;
    float v = up_w[((i * COUTC + o) * 4 + (3 - (p + 2 * ky))) * 4 + (3 - (q + 2 * kx))];
    Apk[t2] = f2bf(v);
  } else if (tid < 630784 + BB * COUTC * HH * WW) {
    int t2 = tid - 630784;
    out1[t2] = dcn_b[(t2 >> 12) & 127];
  }
}

// ---------------- K2t: transpose x -> channel-last hi/lo bf16 planes only.
__global__ __launch_bounds__(256) void k2t(const float* __restrict__ x,
                                           u16* __restrict__ xTh,
                                           u16* __restrict__ xTl) {
  int y = blockIdx.x, cq = blockIdx.y, b = blockIdx.z;
  __shared__ float tile[64][65];
  int t = threadIdx.x;
  int tx = t & 63;
  int tg = t >> 6;
#pragma unroll
  for (int i = 0; i < 16; i++) {
    int c = tg * 16 + i;
    tile[c][tx] = x[((size_t)(b * CINC + cq * 64 + c) * HH + y) * WW + tx];
  }
  __syncthreads();
#pragma unroll
  for (int i = 0; i < 16; i++) {
    int xc = tg * 16 + i;
    size_t idx = ((size_t)(b * HH + y) * WW + xc) * CINC + cq * 64 + tx;
    float v = tile[tx][xc];
    u16 hi = f2bf(v);
    float hf = __uint_as_float((unsigned)hi << 16);
    xTh[idx] = hi;
    xTl[idx] = f2bf(v - hf);
  }
}

// ---------------- K1m: offset conv as MFMA GEMM, split-C(4) partials.
__global__ __launch_bounds__(256) void k1m(const u16* __restrict__ xTh,
                                           const u16* __restrict__ xTl,
                                           const u16* __restrict__ wOk,
                                           float* __restrict__ part1) {
  int h = blockIdx.x, b = blockIdx.y, cs = blockIdx.z;
  int t = threadIdx.x;
  int pt = t >> 6;
  int lane15 = t & 15;
  int quad = (t >> 4) & 3;

  const u16* wh0 = wOk + (size_t)lane15 * 2304 + quad * 8;
  const u16* wh1 = wh0 + 16 * 2304;
  const u16* wl0 = wh0 + 73728;
  const u16* wl1 = wh1 + 73728;

  f32x4 acc[2];
  acc[0] = (f32x4){0.f, 0.f, 0.f, 0.f};
  acc[1] = (f32x4){0.f, 0.f, 0.f, 0.f};

  for (int q = 0; q < 9; q++) {
    int y = h + q / 3 - 1;
    if ((unsigned)y >= 64u) continue;
    int xc = pt * 16 + lane15 + (q % 3) - 1;
    bool xok = (unsigned)xc < 64u;
    int xcc = min(max(xc, 0), 63);
    size_t base = ((size_t)(b * 64 + y) * 64 + xcc) * 256 + cs * 64 + quad * 8;
    const u16* hsrc = xTh + base;
    const u16* lsrc = xTl + base;
#pragma unroll
    for (int c8 = 0; c8 < 2; c8++) {
      bf16x8 xh = *(const bf16x8*)(hsrc + c8 * 32);
      bf16x8 xl = *(const bf16x8*)(lsrc + c8 * 32);
      if (!xok) {
        xh = (bf16x8){0, 0, 0, 0, 0, 0, 0, 0};
        xl = (bf16x8){0, 0, 0, 0, 0, 0, 0, 0};
      }
      int kk = (q * 8 + cs * 2 + c8) * 32;
      bf16x8 ah0 = *(const bf16x8*)(wh0 + kk);
      bf16x8 ah1 = *(const bf16x8*)(wh1 + kk);
      bf16x8 al0 = *(const bf16x8*)(wl0 + kk);
      bf16x8 al1 = *(const bf16x8*)(wl1 + kk);
      acc[0] = __builtin_amdgcn_mfma_f32_16x16x32_bf16(ah0, xh, acc[0], 0, 0, 0);
      acc[0] = __builtin_amdgcn_mfma_f32_16x16x32_bf16(ah0, xl, acc[0], 0, 0, 0);
      acc[0] = __builtin_amdgcn_mfma_f32_16x16x32_bf16(al0, xh, acc[0], 0, 0, 0);
      acc[1] = __builtin_amdgcn_mfma_f32_16x16x32_bf16(ah1, xh, acc[1], 0, 0, 0);
      acc[1] = __builtin_amdgcn_mfma_f32_16x16x32_bf16(ah1, xl, acc[1], 0, 0, 0);
      acc[1] = __builtin_amdgcn_mfma_f32_16x16x32_bf16(al1, xh, acc[1], 0, 0, 0);
    }
  }

  int px = pt * 16 + lane15;
  float* pb = part1 + ((size_t)(cs * BB + b) * 32) * 4096 + h * 64 + px;
#pragma unroll
  for (int tr = 0; tr < 2; tr++)
#pragma unroll
    for (int i = 0; i < 4; i++) {
      int oc = tr * 16 + quad * 4 + i;
      pb[(size_t)oc * 4096] = acc[tr][i];
    }
}

// ---------------- K1r: reduce 4 channel-partials + bias -> py/px/m
__global__ __launch_bounds__(256) void k1r(const float* __restrict__ part1,
                                           const float* __restrict__ off_b,
                                           float* __restrict__ pyg,
                                           float* __restrict__ pxg,
                                           float* __restrict__ mg) {
  int tid = blockIdx.x * 256 + threadIdx.x;
  if (tid >= BB * 27 * HH * WW) return;
  int w = tid & 63;
  int h = (tid >> 6) & 63;
  int oc = (tid >> 12) % 27;
  int b = tid / (27 * 4096);
  int sp = tid & 4095;

  float v = off_b[oc];
#pragma unroll
  for (int cs = 0; cs < 4; cs++)
    v += part1[((size_t)(cs * BB + b) * 32 + oc) * 4096 + sp];

  int k = oc % 9;
  int gi = ((b * 9 + k) * HH + h) * WW + w;
  if (oc < 9) {
    pyg[gi] = v + (float)(oc / 3) - 1.f + (float)h;
  } else if (oc < 18) {
    pxg[gi] = v + (float)((oc - 9) % 3) - 1.f + (float)w;
  } else {
    mg[gi] = 1.f / (1.f + expf(-v));
  }
}

// ---------------- K2m: deformable conv, split-K(4), bf16 MFMA GEMM.
// LDS-dbuf + barrier-pinned prefetch skeleton with LINE-COALESCED bf16 gathers:
// lane remap (wave,lane15=px, quad=ch-slice): instruction (corner,g) has the 4
// quad-lanes of one px fetch quad*16B within ONE 64B line -> 16 distinct lines
// per instr (was 64). Same loads/thread, same bytes, LDS content bit-identical
// to the 58us r9 kernel — only the thread->data assignment changes. TA events
// (the measured ~1.9cy/event limiter) drop 4x. Atomic epilogue -> out1.
__global__ __launch_bounds__(256) void k2m(const u16* __restrict__ xTh,
                                           const u16* __restrict__ wA,
                                           const float* __restrict__ pyg,
                                           const float* __restrict__ pxg,
                                           const float* __restrict__ mg,
                                           float* __restrict__ out1) {
  int ks = blockIdx.x, h = blockIdx.y, b = blockIdx.z;
  __shared__ __align__(16) u16 scolT[2][64 * 72];  // [px][ch 0..63 +8 pad] bf16
  int t = threadIdx.x;
  int wave = t >> 6;
  int lane15 = t & 15;
  int quad = (t >> 4) & 3;
  int gpx = wave * 16 + lane15;  // gather/write px (16 per wave, full 64ch)

  // ---- per-(q,gpx) bilinear descriptors (masked, m-premultiplied) ----
  float dw0[9], dw1[9], dw2[9], dw3[9];
  int doA[9], doB[9];
#pragma unroll
  for (int q = 0; q < 9; q++) {
    int gi = ((b * 9 + q) * HH + h) * WW + gpx;
    float py = pyg[gi], pxx = pxg[gi], m = mg[gi];
    float y0f = floorf(py), x0f = floorf(pxx);
    float wy = py - y0f, wx = pxx - x0f;
    int y0 = (int)y0f, x0 = (int)x0f;
    bool vy0 = (unsigned)y0 < 64u, vy1 = (unsigned)(y0 + 1) < 64u;
    bool vx0 = (unsigned)x0 < 64u, vx1 = (unsigned)(x0 + 1) < 64u;
    int y0c = min(max(y0, 0), 63), y1c = min(max(y0 + 1, 0), 63);
    int x0c = min(max(x0, 0), 63), x1c = min(max(x0 + 1, 0), 63);
    dw0[q] = (vy0 && vx0) ? (1.f - wy) * (1.f - wx) * m : 0.f;
    dw1[q] = (vy0 && vx1) ? (1.f - wy) * wx * m : 0.f;
    dw2[q] = (vy1 && vx0) ? wy * (1.f - wx) * m : 0.f;
    dw3[q] = (vy1 && vx1) ? wy * wx * m : 0.f;
    doA[q] = (y0c * 64 + x0c) | ((y0c * 64 + x1c) << 16);
    doB[q] = (y1c * 64 + x0c) | ((y1c * 64 + x1c) << 16);
  }

  f32x4 acc[8];
#pragma unroll
  for (int i = 0; i < 8; i++) acc[i] = (f32x4){0.f, 0.f, 0.f, 0.f};

  // gather base: block channels ks*64.., thread slice quad*8 (+g*32)
  const u16* xTb = xTh + (size_t)b * 4096 * CINC + ks * 64 + quad * 8;
  const u16* wAr0 = wA + (wave * 32 + lane15) * 2304 + quad * 8;
  const u16* wAr1 = wAr0 + 16 * 2304;

  bf16x8 rx[8];  // 4 corners x {g0: ch quad*8, g1: ch 32+quad*8}
#define GATHER_TAP(qq)                                                       \
  {                                                                          \
    int sA0 = doA[qq] & 0xffff, sA1 = ((unsigned)doA[qq]) >> 16;             \
    int sB0 = doB[qq] & 0xffff, sB1 = ((unsigned)doB[qq]) >> 16;             \
    const u16* p0 = xTb + (size_t)sA0 * CINC;                                \
    const u16* p1 = xTb + (size_t)sA1 * CINC;                                \
    const u16* p2 = xTb + (size_t)sB0 * CINC;                                \
    const u16* p3 = xTb + (size_t)sB1 * CINC;                                \
    rx[0] = *(const bf16x8*)p0;                                              \
    rx[1] = *(const bf16x8*)(p0 + 32);                                       \
    rx[2] = *(const bf16x8*)p1;                                              \
    rx[3] = *(const bf16x8*)(p1 + 32);                                       \
    rx[4] = *(const bf16x8*)p2;                                              \
    rx[5] = *(const bf16x8*)(p2 + 32);                                       \
    rx[6] = *(const bf16x8*)p3;                                              \
    rx[7] = *(const bf16x8*)(p3 + 32);                                       \
  }

  GATHER_TAP(0);

#pragma unroll
  for (int q = 0; q < 9; q++) {
    // combine prefetched corners (f32 interp) -> bf16 pack -> two b128 writes
    float v[16];
#pragma unroll
    for (int j = 0; j < 8; j++) {
      v[j] = dw0[q] * bf2f(rx[0][j]) + dw1[q] * bf2f(rx[2][j]) +
             dw2[q] * bf2f(rx[4][j]) + dw3[q] * bf2f(rx[6][j]);
      v[8 + j] = dw0[q] * bf2f(rx[1][j]) + dw1[q] * bf2f(rx[3][j]) +
                 dw2[q] * bf2f(rx[5][j]) + dw3[q] * bf2f(rx[7][j]);
    }
    u16* sb = &scolT[q & 1][gpx * 72 + quad * 8];
    uint4 s0, s1;
    s0.x = pk(v[0], v[1]);  s0.y = pk(v[2], v[3]);
    s0.z = pk(v[4], v[5]);  s0.w = pk(v[6], v[7]);
    s1.x = pk(v[8], v[9]);  s1.y = pk(v[10], v[11]);
    s1.z = pk(v[12], v[13]); s1.w = pk(v[14], v[15]);
    *(uint4*)sb = s0;          // ch quad*8 .. +8
    *(uint4*)(sb + 32) = s1;   // ch 32+quad*8 .. +8

    // issue next tap's gathers (land during barrier+MFMA)
    if (q < 8) GATHER_TAP(q + 1);

    __syncthreads();  // buf[q&1] visible; prev reads of buf[(q-1)&1] drained
    // MFMA: both 32-ch chunks of this tap; 2 cout rows x 4 px tiles each
#pragma unroll
    for (int c32 = 0; c32 < 2; c32++) {
      int kb = q * 256 + ks * 64 + c32 * 32;
      bf16x8 a0 = *(const bf16x8*)(wAr0 + kb);
      bf16x8 a1 = *(const bf16x8*)(wAr1 + kb);
      const u16* sr = &scolT[q & 1][lane15 * 72 + c32 * 32 + quad * 8];
      bf16x8 b0 = *(const bf16x8*)(sr);
      bf16x8 b1 = *(const bf16x8*)(sr + 16 * 72);
      bf16x8 b2 = *(const bf16x8*)(sr + 32 * 72);
      bf16x8 b3 = *(const bf16x8*)(sr + 48 * 72);
      acc[0] = __builtin_amdgcn_mfma_f32_16x16x32_bf16(a0, b0, acc[0], 0, 0, 0);
      acc[1] = __builtin_amdgcn_mfma_f32_16x16x32_bf16(a0, b1, acc[1], 0, 0, 0);
      acc[2] = __builtin_amdgcn_mfma_f32_16x16x32_bf16(a0, b2, acc[2], 0, 0, 0);
      acc[3] = __builtin_amdgcn_mfma_f32_16x16x32_bf16(a0, b3, acc[3], 0, 0, 0);
      acc[4] = __builtin_amdgcn_mfma_f32_16x16x32_bf16(a1, b0, acc[4], 0, 0, 0);
      acc[5] = __builtin_amdgcn_mfma_f32_16x16x32_bf16(a1, b1, acc[5], 0, 0, 0);
      acc[6] = __builtin_amdgcn_mfma_f32_16x16x32_bf16(a1, b2, acc[6], 0, 0, 0);
      acc[7] = __builtin_amdgcn_mfma_f32_16x16x32_bf16(a1, b3, acc[7], 0, 0, 0);
    }
  }
#undef GATHER_TAP

  // epilogue: accumulate into out1 (pre-initialized with dcn_b) via atomicAdd.
  // C/D: col=lane&15 (px), row=quad*4+i (o)
#pragma unroll
  for (int tr = 0; tr < 2; tr++)
#pragma unroll
    for (int pc = 0; pc < 4; pc++) {
      f32x4 a = acc[tr * 4 + pc];
      int ob = wave * 32 + tr * 16 + quad * 4;
#pragma unroll
      for (int i = 0; i < 4; i++)
        atomicAdd(&out1[((b * COUTC + ob + i) * HH + h) * WW + pc * 16 + lane15], a[i]);
    }
}

// ---------------- BN stats: single-pass split reduction (sum + sumsq).
template <int PLANEF4, int NCHUNK>
__global__ __launch_bounds__(256) void bn_part(const float* __restrict__ src,
                                               float* __restrict__ psum,
                                               float* __restrict__ pssq) {
  int c = blockIdx.x, chunk = blockIdx.y, t = threadIdx.x;
  constexpr int PER = (BB * PLANEF4) / NCHUNK;  // float4s per chunk
  float s = 0.f, s2 = 0.f;
#pragma unroll
  for (int i = 0; i < PER / 256; i++) {
    int f = chunk * PER + i * 256 + t;
    int b = f / PLANEF4;  // compile-time divisor -> shifts
    int sp = f - b * PLANEF4;
    const float4 v = *(const float4*)&src[((size_t)(b * COUTC + c) * PLANEF4 + sp) * 4];
    s += v.x + v.y + v.z + v.w;
    s2 += v.x * v.x + v.y * v.y + v.z * v.z + v.w * v.w;
  }
#pragma unroll
  for (int off = 32; off > 0; off >>= 1) {
    s += __shfl_down(s, off);
    s2 += __shfl_down(s2, off);
  }
  __shared__ float rs[4], rq[4];
  int wv = t >> 6;
  if ((t & 63) == 0) { rs[wv] = s; rq[wv] = s2; }
  __syncthreads();
  if (t == 0) {
    psum[c * NCHUNK + chunk] = rs[0] + rs[1] + rs[2] + rs[3];
    pssq[c * NCHUNK + chunk] = rq[0] + rq[1] + rq[2] + rq[3];
  }
}

// finalize: block-per-channel (grid 128 x 256 thr) — parallel partial reduce
__global__ __launch_bounds__(256) void bn_fin(const float* __restrict__ psum,
                                              const float* __restrict__ pssq,
                                              const float* __restrict__ g,
                                              const float* __restrict__ bt,
                                              float* __restrict__ scale,
                                              float* __restrict__ shift,
                                              int nchunk, float invN) {
  int c = blockIdx.x, t = threadIdx.x;
  float S = 0.f, Q = 0.f;
  for (int i = t; i < nchunk; i += 256) {
    S += psum[c * nchunk + i];
    Q += pssq[c * nchunk + i];
  }
#pragma unroll
  for (int off = 32; off > 0; off >>= 1) {
    S += __shfl_down(S, off);
    Q += __shfl_down(Q, off);
  }
  __shared__ float rs[4], rq[4];
  int wv = t >> 6;
  if ((t & 63) == 0) { rs[wv] = S; rq[wv] = Q; }
  __syncthreads();
  if (t == 0) {
    S = rs[0] + rs[1] + rs[2] + rs[3];
    Q = rq[0] + rq[1] + rq[2] + rq[3];
    float mu = S * invN;
    float var = Q * invN - mu * mu;
    float sc = g[c] * rsqrtf(var + 1e-5f);
    scale[c] = sc;
    shift[c] = bt[c] - mu * sc;
  }
}

// ---------------- K4a: bn1+relu apply, bf16 convert, channel-last transpose.
__global__ __launch_bounds__(256) void k4a(const float* __restrict__ out1,
                                           const float* __restrict__ s1,
                                           const float* __restrict__ sh1,
                                           u16* __restrict__ yT) {
  int m = blockIdx.x, b = blockIdx.y;
  __shared__ __align__(16) u16 T2[64 * 136];
  int t = threadIdx.x;
  for (int e = t; e < 2048; e += 256) {
    int w4 = e & 15, c = e >> 4;
    float4 r = *(const float4*)&out1[((b * COUTC + c) * HH + m) * WW + w4 * 4];
    float sc = s1[c], sh = sh1[c];
    T2[(w4 * 4 + 0) * 136 + c] = f2bf(fmaxf(fmaf(r.x, sc, sh), 0.f));
    T2[(w4 * 4 + 1) * 136 + c] = f2bf(fmaxf(fmaf(r.y, sc, sh), 0.f));
    T2[(w4 * 4 + 2) * 136 + c] = f2bf(fmaxf(fmaf(r.z, sc, sh), 0.f));
    T2[(w4 * 4 + 3) * 136 + c] = f2bf(fmaxf(fmaf(r.w, sc, sh), 0.f));
  }
  __syncthreads();
  for (int e = t; e < 1024; e += 256) {
    int g2 = e * 8;
    int w = g2 >> 7, i = g2 & 127;
    *(bf16x8*)&yT[((size_t)(b * 64 + m) * 64 + w) * 128 + i] =
        *(const bf16x8*)&T2[w * 136 + i];
  }
}

// ---------------- K4m: transposed conv as bf16 MFMA GEMM + fused bn2 partials.
__global__ __launch_bounds__(256) void k4m(const u16* __restrict__ yT,
                                           const u16* __restrict__ Apk,
                                           float* __restrict__ out2,
                                           float* __restrict__ psum2,
                                           float* __restrict__ pssq2) {
  int oh = blockIdx.x, b = blockIdx.y;
  int a = oh >> 1, p = oh & 1;
  __shared__ __align__(16) u16 T[2][66 * 136];
  int t = threadIdx.x;
  int wave = t >> 6, lane15 = t & 15, quad = (t >> 4) & 3;

  // zero border cols: 2 bufs x 2 cols x 128 ch
  for (int e = t; e < 512; e += 256) {
    int ky = e >> 8;
    int rem = e & 255;
    int colp = (rem >> 7) * 65;
    int i = rem & 127;
    T[ky][colp * 136 + i] = 0;
  }
  // stage both tap rows (r = a+p+ky-1); contiguous 16KB copy each
#pragma unroll
  for (int ky = 0; ky < 2; ky++) {
    int r = a + p + ky - 1;
    bool ok = ((unsigned)r < 64u);
    const u16* src = yT + ((size_t)(b * 64 + r) * 64) * 128;
#pragma unroll
    for (int it = 0; it < 4; it++) {
      int g2 = (it * 256 + t) * 8;
      int col = g2 >> 7, i = g2 & 127;
      bf16x8 v = (bf16x8){0, 0, 0, 0, 0, 0, 0, 0};
      if (ok) v = *(const bf16x8*)(src + g2);
      *(bf16x8*)&T[ky][(col + 1) * 136 + i] = v;
    }
  }
  __syncthreads();

  f32x4 acc[2][2][4];  // [q][tr][pc]
#pragma unroll
  for (int q = 0; q < 2; q++)
#pragma unroll
    for (int tr = 0; tr < 2; tr++)
#pragma unroll
      for (int pc = 0; pc < 4; pc++) acc[q][tr][pc] = (f32x4){0.f, 0.f, 0.f, 0.f};

  int row0 = wave * 32 + lane15;
  const u16* A0 = Apk + ((size_t)(p * 2 + 0) * 128) * 512;
  const u16* A1 = Apk + ((size_t)(p * 2 + 1) * 128) * 512;

#pragma unroll
  for (int ky = 0; ky < 2; ky++)
#pragma unroll
    for (int kx = 0; kx < 2; kx++)
#pragma unroll
      for (int c4 = 0; c4 < 4; c4++) {
        int kb = (ky * 2 + kx) * 128 + c4 * 32 + quad * 8;
        bf16x8 a00 = *(const bf16x8*)(A0 + (size_t)row0 * 512 + kb);
        bf16x8 a01 = *(const bf16x8*)(A0 + (size_t)(row0 + 16) * 512 + kb);
        bf16x8 a10 = *(const bf16x8*)(A1 + (size_t)row0 * 512 + kb);
        bf16x8 a11 = *(const bf16x8*)(A1 + (size_t)(row0 + 16) * 512 + kb);
        const u16* tb = &T[ky][(lane15 + kx) * 136 + c4 * 32 + quad * 8];
#pragma unroll
        for (int pc = 0; pc < 4; pc++) {
          bf16x8 b0 = *(const bf16x8*)(tb + (pc * 16) * 136);
          bf16x8 b1 = *(const bf16x8*)(tb + (pc * 16 + 1) * 136);
          acc[0][0][pc] = __builtin_amdgcn_mfma_f32_16x16x32_bf16(a00, b0, acc[0][0][pc], 0, 0, 0);
          acc[0][1][pc] = __builtin_amdgcn_mfma_f32_16x16x32_bf16(a01, b0, acc[0][1][pc], 0, 0, 0);
          acc[1][0][pc] = __builtin_amdgcn_mfma_f32_16x16x32_bf16(a10, b1, acc[1][0][pc], 0, 0, 0);
          acc[1][1][pc] = __builtin_amdgcn_mfma_f32_16x16x32_bf16(a11, b1, acc[1][1][pc], 0, 0, 0);
        }
      }

  // epilogue: C/D col=lane&15 (px), row=quad*4+i (cout). ow = 2*px + q -> float2.
#pragma unroll
  for (int tr = 0; tr < 2; tr++) {
    int o0 = wave * 32 + tr * 16 + quad * 4;
#pragma unroll
    for (int pc = 0; pc < 4; pc++) {
      f32x4 v0 = acc[0][tr][pc];
      f32x4 v1 = acc[1][tr][pc];
      int cw = pc * 32 + 2 * lane15;
#pragma unroll
      for (int i = 0; i < 4; i++) {
        float2 w2;
        w2.x = v0[i];
        w2.y = v1[i];
        *(float2*)&out2[(((size_t)b * COUTC + o0 + i) * OHH + oh) * OWW + cw] = w2;
      }
    }
  }

  // fused bn2 partial stats: reduce across the 16 lane15s per channel.
  int blk = b * 128 + oh;  // 512 partials per channel
#pragma unroll
  for (int tr = 0; tr < 2; tr++)
#pragma unroll
    for (int i = 0; i < 4; i++) {
      float s = 0.f, s2 = 0.f;
#pragma unroll
      for (int q = 0; q < 2; q++)
#pragma unroll
        for (int pc = 0; pc < 4; pc++) {
          float v = acc[q][tr][pc][i];
          s += v;
          s2 += v * v;
        }
#pragma unroll
      for (int off = 1; off < 16; off <<= 1) {
        s += __shfl_xor(s, off);
        s2 += __shfl_xor(s2, off);
      }
      if (lane15 == 0) {
        int c = wave * 32 + tr * 16 + quad * 4 + i;
        psum2[c * 512 + blk] = s;
        pssq2[c * 512 + blk] = s2;
      }
    }
}

// ---------------- K6: bn2+relu apply (f32 out), float4-vectorized
__global__ __launch_bounds__(256) void k6s(const float* __restrict__ out2,
                                           const float* __restrict__ scale2,
                                           const float* __restrict__ shift2,
                                           float* __restrict__ outp) {
  int tid = blockIdx.x * 256 + threadIdx.x;
  if (tid >= (BB * COUTC * OHH * OWW) / 4) return;
  int c = (tid >> 12) & 127;  // (tid*4)>>14
  float sc = scale2[c], sh = shift2[c];
  float4 v = *(const float4*)&out2[tid * 4];
  float4 o;
  o.x = fmaxf(fmaf(v.x, sc, sh), 0.f);
  o.y = fmaxf(fmaf(v.y, sc, sh), 0.f);
  o.z = fmaxf(fmaf(v.z, sc, sh), 0.f);
  o.w = fmaxf(fmaf(v.w, sc, sh), 0.f);
  *(float4*)&outp[tid * 4] = o;
}

// ---------------- launch
extern "C" void kernel_launch(void* const* d_in, const int* in_sizes, int n_in,
                              void* d_out, int out_size, void* d_ws, size_t ws_size,
                              hipStream_t stream) {
  const float* x     = (const float*)d_in[0];
  const float* off_w = (const float*)d_in[1];
  const float* off_b = (const float*)d_in[2];
  const float* dcn_w = (const float*)d_in[3];
  const float* dcn_b = (const float*)d_in[4];
  const float* bn1_g = (const float*)d_in[5];
  const float* bn1_b = (const float*)d_in[6];
  const float* up_w  = (const float*)d_in[7];
  const float* bn2_g = (const float*)d_in[8];
  const float* bn2_b = (const float*)d_in[9];

  float* ws = (float*)d_ws;
  float* pyg  = ws;                              // 147456
  float* pxg  = pyg + BB * 9 * HH * WW;          // 147456
  float* mg   = pxg + BB * 9 * HH * WW;          // 147456
  float* out1 = mg + BB * 9 * HH * WW;           // 2097152
  float* scale1 = out1 + BB * COUTC * HH * WW;   // 128
  float* shift1 = scale1 + 128;                  // 128
  float* out2 = shift1 + 128;                    // 8388608
  float* scale2 = out2 + BB * COUTC * OHH * OWW; // 128
  float* shift2 = scale2 + 128;                  // 128
  float* w_t = shift2 + 128;                     // 294912 floats reserved
  float* wt4 = w_t + COUTC * CINC * 9;           // 262144 floats (Apk uses as u16)
  float* part2 = wt4 + 4 * COUTC * COUTC * 4;    // 4 * 2097152 floats (scratch)
  u16* wA = (u16*)w_t;                           // 128*2304 bf16
  u16* wOk = (u16*)(w_t + 147456);               // 2*32*2304 bf16 hi/lo
  u16* Apk = (u16*)wt4;                          // 4*128*512 bf16 = 512KB
  // hi/lo bf16 planes of x in the out2 region (lifetime k2t..k2m; k2m writes
  // out1, so the out2 region is free until k4m).
  u16* xTh = (u16*)out2;                         // 4.2M u16 = 2.1M floats
  u16* xTl = (u16*)(out2 + 2097152);             // 4.2M u16
  // scratch region layout (part2):
  float* psum = part2;                           // up to 128*512 = 65536
  float* pssq = part2 + 65536;                   // up to 65536
  u16* yT = (u16*)(part2 + 131072);              // bf16 4MB (k4a -> k4m)
  float* part1 = part2 + 131072 + 2097152;       // 4*4*32*4096 = 2.1M floats

  const int N4 = BB * COUTC * OHH * OWW;  // 8388608
  const int N2 = BB * COUTC * HH * WW;    // 2097152
  const int N1 = BB * 27 * HH * WW;       // 442368

  // merged weight preprocessing + out1 bias init
  k0all<<<(630784 + N2 + 255) / 256, 256, 0, stream>>>(dcn_w, off_w, up_w, dcn_b,
                                                       wA, wOk, Apk, out1);
  // channel-last transpose of x -> bf16 hi/lo planes (in out2 region)
  k2t<<<dim3(64, 4, 4), 256, 0, stream>>>(x, xTh, xTl);
  // offset conv via MFMA, split-C(4) partials, then reduce+bias+transform
  k1m<<<dim3(64, BB, 4), 256, 0, stream>>>(xTh, xTl, wOk, part1);
  k1r<<<(N1 + 255) / 256, 256, 0, stream>>>(part1, off_b, pyg, pxg, mg);
  // deformable conv via LDS-pipelined MFMA, line-coalesced gathers; atomic->out1
  k2m<<<dim3(4, 64, 4), 256, 0, stream>>>(xTh, wA, pyg, pxg, mg, out1);
  // bn1 stats
  bn_part<1024, 8><<<dim3(COUTC, 8), 256, 0, stream>>>(out1, psum, pssq);
  bn_fin<<<COUTC, 256, 0, stream>>>(psum, pssq, bn1_g, bn1_b, scale1, shift1, 8,
                                    1.f / 16384.f);
  // bn1 apply + transpose to bf16 channel-last
  k4a<<<dim3(64, 4), 256, 0, stream>>>(out1, scale1, shift1, yT);
  // transposed conv via MFMA + fused bn2 partial stats
  k4m<<<dim3(128, 4), 256, 0, stream>>>(yT, Apk, out2, psum, pssq);
  bn_fin<<<COUTC, 256, 0, stream>>>(psum, pssq, bn2_g, bn2_b, scale2, shift2, 512,
                                    1.f / 65536.f);
  k6s<<<(N4 / 4 + 255) / 256, 256, 0, stream>>>(out2, scale2, shift2, (float*)d_out);
}

// Round 12
// 223.521 us; speedup vs baseline: 1.5295x; 1.1692x over previous
//
#include <hip/hip_runtime.h>
#include <math.h>

// Problem constants
#define BB 4
#define CINC 256
#define COUTC 128
#define HH 64
#define WW 64
#define OHH 128
#define OWW 128

typedef unsigned short u16;
typedef __attribute__((ext_vector_type(8))) short bf16x8;
typedef __attribute__((ext_vector_type(4))) float f32x4;

__device__ __forceinline__ u16 f2bf(float f) {
  unsigned int u = __float_as_uint(f);
  unsigned int r = u + 0x7FFFu + ((u >> 16) & 1u);  // RNE
  return (u16)(r >> 16);
}

__device__ __forceinline__ unsigned pk(float a, float b) {
  return (unsigned)f2bf(a) | ((unsigned)f2bf(b) << 16);
}

__device__ __forceinline__ float bf2f(short h) {
  return __uint_as_float(((unsigned)(unsigned short)h) << 16);
}

// ---------------- K0all: merged weight preprocessing + out1 bias init.
// [0, 294912):        dcn_w -> bf16 wA[o][q*256+c]
// [294912, 442368):   off_w -> W2: frag-major hi/lo bf16, COALESCED k1m reads.
//                     W2[plane][kb][lane][8], plane {h0,h1,l0,l1}, kb=K/32,
//                     lane=(quad<<4)|l15 holds A[row=(plane&1)*16+l15][kb*32+quad*8+j]
// [442368, 704512):   up_w  -> 4 parity-class bf16 Apk
// [704512, +2097152): out1 = dcn_b (accumulation base for k2m atomics)
__global__ __launch_bounds__(256) void k0all(const float* __restrict__ dcn_w,
                                             const float* __restrict__ off_w,
                                             const float* __restrict__ up_w,
                                             const float* __restrict__ dcn_b,
                                             u16* __restrict__ wA,
                                             u16* __restrict__ W2,
                                             u16* __restrict__ Apk,
                                             float* __restrict__ out1) {
  int tid = blockIdx.x * 256 + threadIdx.x;
  if (tid < 294912) {
    int o = tid / 2304;
    int ckr = tid - o * 2304;
    int q = ckr >> 8;
    int c = ckr & 255;
    wA[tid] = f2bf(dcn_w[o * 2304 + c * 9 + q]);
  } else if (tid < 442368) {
    int t2 = tid - 294912;                 // [0, 147456)
    int j = t2 & 7;
    int lane = (t2 >> 3) & 63;
    int kb = (t2 >> 9) % 72;
    int plane = t2 / 36864;
    int l15 = lane & 15, quad = (lane >> 4) & 3;
    int row = (plane & 1) * 16 + l15;
    int kk = kb * 32 + quad * 8 + j;
    int q = kk >> 8, c = kk & 255;
    float w = (row < 27) ? off_w[(row * CINC + c) * 9 + q] : 0.f;
    u16 hi = f2bf(w);
    if (plane < 2) {
      W2[t2] = hi;
    } else {
      float hf = __uint_as_float((unsigned)hi << 16);
      W2[t2] = f2bf(w - hf);
    }
  } else if (tid < 704512) {
    int t2 = tid - 442368;
    int kp = t2 & 511;
    int o = (t2 >> 9) & 127;
    int pq = t2 >> 16;
    int p = pq >> 1, q = pq & 1;
    int ky = kp >> 8, kx = (kp >> 7) & 1, i = kp & 127;
    float v = up_w[((i * COUTC + o) * 4 + (3 - (p + 2 * ky))) * 4 + (3 - (q + 2 * kx))];
    Apk[t2] = f2bf(v);
  } else if (tid < 704512 + BB * COUTC * HH * WW) {
    int t2 = tid - 704512;
    out1[t2] = dcn_b[(t2 >> 12) & 127];
  }
}

// ---------------- K2t: transpose x -> channel-last hi/lo bf16 planes only.
__global__ __launch_bounds__(256) void k2t(const float* __restrict__ x,
                                           u16* __restrict__ xTh,
                                           u16* __restrict__ xTl) {
  int y = blockIdx.x, cq = blockIdx.y, b = blockIdx.z;
  __shared__ float tile[64][65];
  int t = threadIdx.x;
  int tx = t & 63;
  int tg = t >> 6;
#pragma unroll
  for (int i = 0; i < 16; i++) {
    int c = tg * 16 + i;
    tile[c][tx] = x[((size_t)(b * CINC + cq * 64 + c) * HH + y) * WW + tx];
  }
  __syncthreads();
#pragma unroll
  for (int i = 0; i < 16; i++) {
    int xc = tg * 16 + i;
    size_t idx = ((size_t)(b * HH + y) * WW + xc) * CINC + cq * 64 + tx;
    float v = tile[tx][xc];
    u16 hi = f2bf(v);
    float hf = __uint_as_float((unsigned)hi << 16);
    xTh[idx] = hi;
    xTl[idx] = f2bf(v - hf);
  }
}

// ---------------- K1m: offset conv as MFMA GEMM, split-C(4) partials.
// Weight A-frags now read COALESCED from frag-major W2 (lane t -> t*16B of a
// 1KB segment) — removes 72 lane-divergent loads/thread (wOk rows were 4.6KB
// apart per lane). Fragment contents identical; numerics unchanged.
__global__ __launch_bounds__(256) void k1m(const u16* __restrict__ xTh,
                                           const u16* __restrict__ xTl,
                                           const u16* __restrict__ W2,
                                           float* __restrict__ part1) {
  int h = blockIdx.x, b = blockIdx.y, cs = blockIdx.z;
  int t = threadIdx.x;
  int pt = t >> 6;
  int lw = t & 63;
  int lane15 = t & 15;
  int quad = (t >> 4) & 3;

  f32x4 acc[2];
  acc[0] = (f32x4){0.f, 0.f, 0.f, 0.f};
  acc[1] = (f32x4){0.f, 0.f, 0.f, 0.f};

  for (int q = 0; q < 9; q++) {
    int y = h + q / 3 - 1;
    if ((unsigned)y >= 64u) continue;
    int xc = pt * 16 + lane15 + (q % 3) - 1;
    bool xok = (unsigned)xc < 64u;
    int xcc = min(max(xc, 0), 63);
    size_t base = ((size_t)(b * 64 + y) * 64 + xcc) * 256 + cs * 64 + quad * 8;
    const u16* hsrc = xTh + base;
    const u16* lsrc = xTl + base;
#pragma unroll
    for (int c8 = 0; c8 < 2; c8++) {
      bf16x8 xh = *(const bf16x8*)(hsrc + c8 * 32);
      bf16x8 xl = *(const bf16x8*)(lsrc + c8 * 32);
      if (!xok) {
        xh = (bf16x8){0, 0, 0, 0, 0, 0, 0, 0};
        xl = (bf16x8){0, 0, 0, 0, 0, 0, 0, 0};
      }
      int kb = q * 8 + cs * 2 + c8;
      const u16* wb = W2 + (size_t)kb * 512 + lw * 8;
      bf16x8 ah0 = *(const bf16x8*)(wb);
      bf16x8 ah1 = *(const bf16x8*)(wb + 36864);
      bf16x8 al0 = *(const bf16x8*)(wb + 2 * 36864);
      bf16x8 al1 = *(const bf16x8*)(wb + 3 * 36864);
      acc[0] = __builtin_amdgcn_mfma_f32_16x16x32_bf16(ah0, xh, acc[0], 0, 0, 0);
      acc[0] = __builtin_amdgcn_mfma_f32_16x16x32_bf16(ah0, xl, acc[0], 0, 0, 0);
      acc[0] = __builtin_amdgcn_mfma_f32_16x16x32_bf16(al0, xh, acc[0], 0, 0, 0);
      acc[1] = __builtin_amdgcn_mfma_f32_16x16x32_bf16(ah1, xh, acc[1], 0, 0, 0);
      acc[1] = __builtin_amdgcn_mfma_f32_16x16x32_bf16(ah1, xl, acc[1], 0, 0, 0);
      acc[1] = __builtin_amdgcn_mfma_f32_16x16x32_bf16(al1, xh, acc[1], 0, 0, 0);
    }
  }

  int px = pt * 16 + lane15;
  float* pb = part1 + ((size_t)(cs * BB + b) * 32) * 4096 + h * 64 + px;
#pragma unroll
  for (int tr = 0; tr < 2; tr++)
#pragma unroll
    for (int i = 0; i < 4; i++) {
      int oc = tr * 16 + quad * 4 + i;
      pb[(size_t)oc * 4096] = acc[tr][i];
    }
}

// ---------------- K1r: reduce 4 channel-partials + bias -> py/px/m
__global__ __launch_bounds__(256) void k1r(const float* __restrict__ part1,
                                           const float* __restrict__ off_b,
                                           float* __restrict__ pyg,
                                           float* __restrict__ pxg,
                                           float* __restrict__ mg) {
  int tid = blockIdx.x * 256 + threadIdx.x;
  if (tid >= BB * 27 * HH * WW) return;
  int w = tid & 63;
  int h = (tid >> 6) & 63;
  int oc = (tid >> 12) % 27;
  int b = tid / (27 * 4096);
  int sp = tid & 4095;

  float v = off_b[oc];
#pragma unroll
  for (int cs = 0; cs < 4; cs++)
    v += part1[((size_t)(cs * BB + b) * 32 + oc) * 4096 + sp];

  int k = oc % 9;
  int gi = ((b * 9 + k) * HH + h) * WW + w;
  if (oc < 9) {
    pyg[gi] = v + (float)(oc / 3) - 1.f + (float)h;
  } else if (oc < 18) {
    pxg[gi] = v + (float)((oc - 9) % 3) - 1.f + (float)w;
  } else {
    mg[gi] = 1.f / (1.f + expf(-v));
  }
}

// ---------------- K2m: deformable conv, split-K(4), bf16 MFMA GEMM.
// CONSECUTIVE-LANE line coalescing test: gather roles remapped so lanes t&3
// (consecutive, same quarter-wave group) fetch the 4 16B slices of ONE 64B
// line (r10's stride-16 remap was null -> hypothesis: TA coalesces only
// within consecutive lane groups). Gathers route through LDS, so lane roles
// are free; LDS contents + MFMA mapping bit-identical. Atomic epilogue->out1.
__global__ __launch_bounds__(256) void k2m(const u16* __restrict__ xTh,
                                           const u16* __restrict__ wA,
                                           const float* __restrict__ pyg,
                                           const float* __restrict__ pxg,
                                           const float* __restrict__ mg,
                                           float* __restrict__ out1) {
  int ks = blockIdx.x, h = blockIdx.y, b = blockIdx.z;
  __shared__ __align__(16) u16 scolT[2][64 * 72];  // [px][ch 0..63 +8 pad] bf16
  int t = threadIdx.x;
  int wave = t >> 6;
  int lane15 = t & 15;
  int quad = (t >> 4) & 3;
  int gq = t & 3;             // gather channel-slice (consecutive lanes!)
  int gl15 = (t >> 2) & 15;   // gather px within wave tile
  int gpx = wave * 16 + gl15;

  // ---- per-(q,gpx) bilinear descriptors (masked, m-premultiplied) ----
  float dw0[9], dw1[9], dw2[9], dw3[9];
  int doA[9], doB[9];
#pragma unroll
  for (int q = 0; q < 9; q++) {
    int gi = ((b * 9 + q) * HH + h) * WW + gpx;
    float py = pyg[gi], pxx = pxg[gi], m = mg[gi];
    float y0f = floorf(py), x0f = floorf(pxx);
    float wy = py - y0f, wx = pxx - x0f;
    int y0 = (int)y0f, x0 = (int)x0f;
    bool vy0 = (unsigned)y0 < 64u, vy1 = (unsigned)(y0 + 1) < 64u;
    bool vx0 = (unsigned)x0 < 64u, vx1 = (unsigned)(x0 + 1) < 64u;
    int y0c = min(max(y0, 0), 63), y1c = min(max(y0 + 1, 0), 63);
    int x0c = min(max(x0, 0), 63), x1c = min(max(x0 + 1, 0), 63);
    dw0[q] = (vy0 && vx0) ? (1.f - wy) * (1.f - wx) * m : 0.f;
    dw1[q] = (vy0 && vx1) ? (1.f - wy) * wx * m : 0.f;
    dw2[q] = (vy1 && vx0) ? wy * (1.f - wx) * m : 0.f;
    dw3[q] = (vy1 && vx1) ? wy * wx * m : 0.f;
    doA[q] = (y0c * 64 + x0c) | ((y0c * 64 + x1c) << 16);
    doB[q] = (y1c * 64 + x0c) | ((y1c * 64 + x1c) << 16);
  }

  f32x4 acc[8];
#pragma unroll
  for (int i = 0; i < 8; i++) acc[i] = (f32x4){0.f, 0.f, 0.f, 0.f};

  // gather base: block channels ks*64.., thread slice gq*8 (+32 for 2nd load)
  const u16* xTb = xTh + (size_t)b * 4096 * CINC + ks * 64 + gq * 8;
  const u16* wAr0 = wA + (wave * 32 + lane15) * 2304 + quad * 8;
  const u16* wAr1 = wAr0 + 16 * 2304;

  bf16x8 rx[8];  // 4 corners x {g0: ch gq*8, g1: ch 32+gq*8}
#define GATHER_TAP(qq)                                                       \
  {                                                                          \
    int sA0 = doA[qq] & 0xffff, sA1 = ((unsigned)doA[qq]) >> 16;             \
    int sB0 = doB[qq] & 0xffff, sB1 = ((unsigned)doB[qq]) >> 16;             \
    const u16* p0 = xTb + (size_t)sA0 * CINC;                                \
    const u16* p1 = xTb + (size_t)sA1 * CINC;                                \
    const u16* p2 = xTb + (size_t)sB0 * CINC;                                \
    const u16* p3 = xTb + (size_t)sB1 * CINC;                                \
    rx[0] = *(const bf16x8*)p0;                                              \
    rx[1] = *(const bf16x8*)(p0 + 32);                                       \
    rx[2] = *(const bf16x8*)p1;                                              \
    rx[3] = *(const bf16x8*)(p1 + 32);                                       \
    rx[4] = *(const bf16x8*)p2;                                              \
    rx[5] = *(const bf16x8*)(p2 + 32);                                       \
    rx[6] = *(const bf16x8*)p3;                                              \
    rx[7] = *(const bf16x8*)(p3 + 32);                                       \
  }

  GATHER_TAP(0);

#pragma unroll
  for (int q = 0; q < 9; q++) {
    // combine prefetched corners (f32 interp) -> bf16 pack -> two b128 writes
    float v[16];
#pragma unroll
    for (int j = 0; j < 8; j++) {
      v[j] = dw0[q] * bf2f(rx[0][j]) + dw1[q] * bf2f(rx[2][j]) +
             dw2[q] * bf2f(rx[4][j]) + dw3[q] * bf2f(rx[6][j]);
      v[8 + j] = dw0[q] * bf2f(rx[1][j]) + dw1[q] * bf2f(rx[3][j]) +
                 dw2[q] * bf2f(rx[5][j]) + dw3[q] * bf2f(rx[7][j]);
    }
    u16* sb = &scolT[q & 1][gpx * 72 + gq * 8];
    uint4 s0, s1;
    s0.x = pk(v[0], v[1]);  s0.y = pk(v[2], v[3]);
    s0.z = pk(v[4], v[5]);  s0.w = pk(v[6], v[7]);
    s1.x = pk(v[8], v[9]);  s1.y = pk(v[10], v[11]);
    s1.z = pk(v[12], v[13]); s1.w = pk(v[14], v[15]);
    *(uint4*)sb = s0;          // ch gq*8 .. +8
    *(uint4*)(sb + 32) = s1;   // ch 32+gq*8 .. +8

    // issue next tap's gathers (land during barrier+MFMA)
    if (q < 8) GATHER_TAP(q + 1);

    __syncthreads();  // buf[q&1] visible; prev reads of buf[(q-1)&1] drained
    // MFMA: both 32-ch chunks of this tap; 2 cout rows x 4 px tiles each
#pragma unroll
    for (int c32 = 0; c32 < 2; c32++) {
      int kb = q * 256 + ks * 64 + c32 * 32;
      bf16x8 a0 = *(const bf16x8*)(wAr0 + kb);
      bf16x8 a1 = *(const bf16x8*)(wAr1 + kb);
      const u16* sr = &scolT[q & 1][lane15 * 72 + c32 * 32 + quad * 8];
      bf16x8 b0 = *(const bf16x8*)(sr);
      bf16x8 b1 = *(const bf16x8*)(sr + 16 * 72);
      bf16x8 b2 = *(const bf16x8*)(sr + 32 * 72);
      bf16x8 b3 = *(const bf16x8*)(sr + 48 * 72);
      acc[0] = __builtin_amdgcn_mfma_f32_16x16x32_bf16(a0, b0, acc[0], 0, 0, 0);
      acc[1] = __builtin_amdgcn_mfma_f32_16x16x32_bf16(a0, b1, acc[1], 0, 0, 0);
      acc[2] = __builtin_amdgcn_mfma_f32_16x16x32_bf16(a0, b2, acc[2], 0, 0, 0);
      acc[3] = __builtin_amdgcn_mfma_f32_16x16x32_bf16(a0, b3, acc[3], 0, 0, 0);
      acc[4] = __builtin_amdgcn_mfma_f32_16x16x32_bf16(a1, b0, acc[4], 0, 0, 0);
      acc[5] = __builtin_amdgcn_mfma_f32_16x16x32_bf16(a1, b1, acc[5], 0, 0, 0);
      acc[6] = __builtin_amdgcn_mfma_f32_16x16x32_bf16(a1, b2, acc[6], 0, 0, 0);
      acc[7] = __builtin_amdgcn_mfma_f32_16x16x32_bf16(a1, b3, acc[7], 0, 0, 0);
    }
  }
#undef GATHER_TAP

  // epilogue: accumulate into out1 (pre-initialized with dcn_b) via atomicAdd.
#pragma unroll
  for (int tr = 0; tr < 2; tr++)
#pragma unroll
    for (int pc = 0; pc < 4; pc++) {
      f32x4 a = acc[tr * 4 + pc];
      int ob = wave * 32 + tr * 16 + quad * 4;
#pragma unroll
      for (int i = 0; i < 4; i++)
        atomicAdd(&out1[((b * COUTC + ob + i) * HH + h) * WW + pc * 16 + lane15], a[i]);
    }
}

// ---------------- BN stats: single-pass split reduction (sum + sumsq).
template <int PLANEF4, int NCHUNK>
__global__ __launch_bounds__(256) void bn_part(const float* __restrict__ src,
                                               float* __restrict__ psum,
                                               float* __restrict__ pssq) {
  int c = blockIdx.x, chunk = blockIdx.y, t = threadIdx.x;
  constexpr int PER = (BB * PLANEF4) / NCHUNK;  // float4s per chunk
  float s = 0.f, s2 = 0.f;
#pragma unroll
  for (int i = 0; i < PER / 256; i++) {
    int f = chunk * PER + i * 256 + t;
    int b = f / PLANEF4;  // compile-time divisor -> shifts
    int sp = f - b * PLANEF4;
    const float4 v = *(const float4*)&src[((size_t)(b * COUTC + c) * PLANEF4 + sp) * 4];
    s += v.x + v.y + v.z + v.w;
    s2 += v.x * v.x + v.y * v.y + v.z * v.z + v.w * v.w;
  }
#pragma unroll
  for (int off = 32; off > 0; off >>= 1) {
    s += __shfl_down(s, off);
    s2 += __shfl_down(s2, off);
  }
  __shared__ float rs[4], rq[4];
  int wv = t >> 6;
  if ((t & 63) == 0) { rs[wv] = s; rq[wv] = s2; }
  __syncthreads();
  if (t == 0) {
    psum[c * NCHUNK + chunk] = rs[0] + rs[1] + rs[2] + rs[3];
    pssq[c * NCHUNK + chunk] = rq[0] + rq[1] + rq[2] + rq[3];
  }
}

// finalize: block-per-channel — parallel partial reduce (bn1 only)
__global__ __launch_bounds__(256) void bn_fin(const float* __restrict__ psum,
                                              const float* __restrict__ pssq,
                                              const float* __restrict__ g,
                                              const float* __restrict__ bt,
                                              float* __restrict__ scale,
                                              float* __restrict__ shift,
                                              int nchunk, float invN) {
  int c = blockIdx.x, t = threadIdx.x;
  float S = 0.f, Q = 0.f;
  for (int i = t; i < nchunk; i += 256) {
    S += psum[c * nchunk + i];
    Q += pssq[c * nchunk + i];
  }
#pragma unroll
  for (int off = 32; off > 0; off >>= 1) {
    S += __shfl_down(S, off);
    Q += __shfl_down(Q, off);
  }
  __shared__ float rs[4], rq[4];
  int wv = t >> 6;
  if ((t & 63) == 0) { rs[wv] = S; rq[wv] = Q; }
  __syncthreads();
  if (t == 0) {
    S = rs[0] + rs[1] + rs[2] + rs[3];
    Q = rq[0] + rq[1] + rq[2] + rq[3];
    float mu = S * invN;
    float var = Q * invN - mu * mu;
    float sc = g[c] * rsqrtf(var + 1e-5f);
    scale[c] = sc;
    shift[c] = bt[c] - mu * sc;
  }
}

// ---------------- K4a: bn1+relu apply, bf16 convert, channel-last transpose.
__global__ __launch_bounds__(256) void k4a(const float* __restrict__ out1,
                                           const float* __restrict__ s1,
                                           const float* __restrict__ sh1,
                                           u16* __restrict__ yT) {
  int m = blockIdx.x, b = blockIdx.y;
  __shared__ __align__(16) u16 T2[64 * 136];
  int t = threadIdx.x;
  for (int e = t; e < 2048; e += 256) {
    int w4 = e & 15, c = e >> 4;
    float4 r = *(const float4*)&out1[((b * COUTC + c) * HH + m) * WW + w4 * 4];
    float sc = s1[c], sh = sh1[c];
    T2[(w4 * 4 + 0) * 136 + c] = f2bf(fmaxf(fmaf(r.x, sc, sh), 0.f));
    T2[(w4 * 4 + 1) * 136 + c] = f2bf(fmaxf(fmaf(r.y, sc, sh), 0.f));
    T2[(w4 * 4 + 2) * 136 + c] = f2bf(fmaxf(fmaf(r.z, sc, sh), 0.f));
    T2[(w4 * 4 + 3) * 136 + c] = f2bf(fmaxf(fmaf(r.w, sc, sh), 0.f));
  }
  __syncthreads();
  for (int e = t; e < 1024; e += 256) {
    int g2 = e * 8;
    int w = g2 >> 7, i = g2 & 127;
    *(bf16x8*)&yT[((size_t)(b * 64 + m) * 64 + w) * 128 + i] =
        *(const bf16x8*)&T2[w * 136 + i];
  }
}

// ---------------- K4m: transposed conv as bf16 MFMA GEMM + fused bn2 partials.
__global__ __launch_bounds__(256) void k4m(const u16* __restrict__ yT,
                                           const u16* __restrict__ Apk,
                                           float* __restrict__ out2,
                                           float* __restrict__ psum2,
                                           float* __restrict__ pssq2) {
  int oh = blockIdx.x, b = blockIdx.y;
  int a = oh >> 1, p = oh & 1;
  __shared__ __align__(16) u16 T[2][66 * 136];
  int t = threadIdx.x;
  int wave = t >> 6, lane15 = t & 15, quad = (t >> 4) & 3;

  // zero border cols: 2 bufs x 2 cols x 128 ch
  for (int e = t; e < 512; e += 256) {
    int ky = e >> 8;
    int rem = e & 255;
    int colp = (rem >> 7) * 65;
    int i = rem & 127;
    T[ky][colp * 136 + i] = 0;
  }
  // stage both tap rows (r = a+p+ky-1); contiguous 16KB copy each
#pragma unroll
  for (int ky = 0; ky < 2; ky++) {
    int r = a + p + ky - 1;
    bool ok = ((unsigned)r < 64u);
    const u16* src = yT + ((size_t)(b * 64 + r) * 64) * 128;
#pragma unroll
    for (int it = 0; it < 4; it++) {
      int g2 = (it * 256 + t) * 8;
      int col = g2 >> 7, i = g2 & 127;
      bf16x8 v = (bf16x8){0, 0, 0, 0, 0, 0, 0, 0};
      if (ok) v = *(const bf16x8*)(src + g2);
      *(bf16x8*)&T[ky][(col + 1) * 136 + i] = v;
    }
  }
  __syncthreads();

  f32x4 acc[2][2][4];  // [q][tr][pc]
#pragma unroll
  for (int q = 0; q < 2; q++)
#pragma unroll
    for (int tr = 0; tr < 2; tr++)
#pragma unroll
      for (int pc = 0; pc < 4; pc++) acc[q][tr][pc] = (f32x4){0.f, 0.f, 0.f, 0.f};

  int row0 = wave * 32 + lane15;
  const u16* A0 = Apk + ((size_t)(p * 2 + 0) * 128) * 512;
  const u16* A1 = Apk + ((size_t)(p * 2 + 1) * 128) * 512;

#pragma unroll
  for (int ky = 0; ky < 2; ky++)
#pragma unroll
    for (int kx = 0; kx < 2; kx++)
#pragma unroll
      for (int c4 = 0; c4 < 4; c4++) {
        int kb = (ky * 2 + kx) * 128 + c4 * 32 + quad * 8;
        bf16x8 a00 = *(const bf16x8*)(A0 + (size_t)row0 * 512 + kb);
        bf16x8 a01 = *(const bf16x8*)(A0 + (size_t)(row0 + 16) * 512 + kb);
        bf16x8 a10 = *(const bf16x8*)(A1 + (size_t)row0 * 512 + kb);
        bf16x8 a11 = *(const bf16x8*)(A1 + (size_t)(row0 + 16) * 512 + kb);
        const u16* tb = &T[ky][(lane15 + kx) * 136 + c4 * 32 + quad * 8];
#pragma unroll
        for (int pc = 0; pc < 4; pc++) {
          bf16x8 b0 = *(const bf16x8*)(tb + (pc * 16) * 136);
          bf16x8 b1 = *(const bf16x8*)(tb + (pc * 16 + 1) * 136);
          acc[0][0][pc] = __builtin_amdgcn_mfma_f32_16x16x32_bf16(a00, b0, acc[0][0][pc], 0, 0, 0);
          acc[0][1][pc] = __builtin_amdgcn_mfma_f32_16x16x32_bf16(a01, b0, acc[0][1][pc], 0, 0, 0);
          acc[1][0][pc] = __builtin_amdgcn_mfma_f32_16x16x32_bf16(a10, b1, acc[1][0][pc], 0, 0, 0);
          acc[1][1][pc] = __builtin_amdgcn_mfma_f32_16x16x32_bf16(a11, b1, acc[1][1][pc], 0, 0, 0);
        }
      }

  // epilogue: C/D col=lane&15 (px), row=quad*4+i (cout). ow = 2*px + q -> float2.
#pragma unroll
  for (int tr = 0; tr < 2; tr++) {
    int o0 = wave * 32 + tr * 16 + quad * 4;
#pragma unroll
    for (int pc = 0; pc < 4; pc++) {
      f32x4 v0 = acc[0][tr][pc];
      f32x4 v1 = acc[1][tr][pc];
      int cw = pc * 32 + 2 * lane15;
#pragma unroll
      for (int i = 0; i < 4; i++) {
        float2 w2;
        w2.x = v0[i];
        w2.y = v1[i];
        *(float2*)&out2[(((size_t)b * COUTC + o0 + i) * OHH + oh) * OWW + cw] = w2;
      }
    }
  }

  // fused bn2 partial stats: reduce across the 16 lane15s per channel.
  int blk = b * 128 + oh;  // 512 partials per channel
#pragma unroll
  for (int tr = 0; tr < 2; tr++)
#pragma unroll
    for (int i = 0; i < 4; i++) {
      float s = 0.f, s2 = 0.f;
#pragma unroll
      for (int q = 0; q < 2; q++)
#pragma unroll
        for (int pc = 0; pc < 4; pc++) {
          float v = acc[q][tr][pc][i];
          s += v;
          s2 += v * v;
        }
#pragma unroll
      for (int off = 1; off < 16; off <<= 1) {
        s += __shfl_xor(s, off);
        s2 += __shfl_xor(s2, off);
      }
      if (lane15 == 0) {
        int c = wave * 32 + tr * 16 + quad * 4 + i;
        psum2[c * 512 + blk] = s;
        pssq2[c * 512 + blk] = s2;
      }
    }
}

// ---------------- K6f: fused bn2 finalize + apply (f32 out), float4-vectorized.
// Each block covers 1024 float4 = 4096 floats = a contiguous range within ONE
// channel plane (16384 el) -> block reduces that channel's 512 L2-resident
// partials itself (replaces the separate bn_fin launch).
__global__ __launch_bounds__(256) void k6f(const float* __restrict__ out2,
                                           const float* __restrict__ psum2,
                                           const float* __restrict__ pssq2,
                                           const float* __restrict__ g,
                                           const float* __restrict__ bt,
                                           float* __restrict__ outp) {
  int blk = blockIdx.x, t = threadIdx.x;
  int c = (blk >> 2) & 127;  // (blk*4096 >> 14) & 127

  float S = psum2[c * 512 + t] + psum2[c * 512 + 256 + t];
  float Q = pssq2[c * 512 + t] + pssq2[c * 512 + 256 + t];
#pragma unroll
  for (int off = 32; off > 0; off >>= 1) {
    S += __shfl_down(S, off);
    Q += __shfl_down(Q, off);
  }
  __shared__ float rs[4], rq[4], sSC, sSH;
  int wv = t >> 6;
  if ((t & 63) == 0) { rs[wv] = S; rq[wv] = Q; }
  __syncthreads();
  if (t == 0) {
    S = rs[0] + rs[1] + rs[2] + rs[3];
    Q = rq[0] + rq[1] + rq[2] + rq[3];
    float mu = S / 65536.f;
    float var = Q / 65536.f - mu * mu;
    float sc = g[c] * rsqrtf(var + 1e-5f);
    sSC = sc;
    sSH = bt[c] - mu * sc;
  }
  __syncthreads();
  float sc = sSC, sh = sSH;
  int base = blk * 1024;
#pragma unroll
  for (int i = 0; i < 4; i++) {
    int f4 = base + i * 256 + t;
    float4 v = *(const float4*)&out2[f4 * 4];
    float4 o;
    o.x = fmaxf(fmaf(v.x, sc, sh), 0.f);
    o.y = fmaxf(fmaf(v.y, sc, sh), 0.f);
    o.z = fmaxf(fmaf(v.z, sc, sh), 0.f);
    o.w = fmaxf(fmaf(v.w, sc, sh), 0.f);
    *(float4*)&outp[f4 * 4] = o;
  }
}

// ---------------- launch
extern "C" void kernel_launch(void* const* d_in, const int* in_sizes, int n_in,
                              void* d_out, int out_size, void* d_ws, size_t ws_size,
                              hipStream_t stream) {
  const float* x     = (const float*)d_in[0];
  const float* off_w = (const float*)d_in[1];
  const float* off_b = (const float*)d_in[2];
  const float* dcn_w = (const float*)d_in[3];
  const float* dcn_b = (const float*)d_in[4];
  const float* bn1_g = (const float*)d_in[5];
  const float* bn1_b = (const float*)d_in[6];
  const float* up_w  = (const float*)d_in[7];
  const float* bn2_g = (const float*)d_in[8];
  const float* bn2_b = (const float*)d_in[9];

  float* ws = (float*)d_ws;
  float* pyg  = ws;                              // 147456
  float* pxg  = pyg + BB * 9 * HH * WW;          // 147456
  float* mg   = pxg + BB * 9 * HH * WW;          // 147456
  float* out1 = mg + BB * 9 * HH * WW;           // 2097152
  float* scale1 = out1 + BB * COUTC * HH * WW;   // 128
  float* shift1 = scale1 + 128;                  // 128
  float* out2 = shift1 + 128;                    // 8388608
  float* scale2 = out2 + BB * COUTC * OHH * OWW; // 128 (unused now)
  float* shift2 = scale2 + 128;                  // 128 (unused now)
  float* w_t = shift2 + 128;                     // 294912 floats reserved
  float* wt4 = w_t + COUTC * CINC * 9;           // 262144 floats (Apk uses as u16)
  float* part2 = wt4 + 4 * COUTC * COUTC * 4;    // 4 * 2097152 floats (scratch)
  u16* wA = (u16*)w_t;                           // 128*2304 bf16
  u16* W2 = (u16*)(w_t + 147456);                // 4*72*64*8 = 147456 bf16 frag-major
  u16* Apk = (u16*)wt4;                          // 4*128*512 bf16 = 512KB
  // hi/lo bf16 planes of x in the out2 region (lifetime k2t..k2m).
  u16* xTh = (u16*)out2;                         // 4.2M u16 = 2.1M floats
  u16* xTl = (u16*)(out2 + 2097152);             // 4.2M u16
  // scratch region layout (part2):
  float* psum = part2;                           // up to 128*512 = 65536
  float* pssq = part2 + 65536;                   // up to 65536
  u16* yT = (u16*)(part2 + 131072);              // bf16 4MB (k4a -> k4m)
  float* part1 = part2 + 131072 + 2097152;       // 4*4*32*4096 = 2.1M floats

  const int N4 = BB * COUTC * OHH * OWW;  // 8388608
  const int N2 = BB * COUTC * HH * WW;    // 2097152
  const int N1 = BB * 27 * HH * WW;       // 442368

  // merged weight preprocessing (incl. frag-major W2) + out1 bias init
  k0all<<<(704512 + N2 + 255) / 256, 256, 0, stream>>>(dcn_w, off_w, up_w, dcn_b,
                                                       wA, W2, Apk, out1);
  // channel-last transpose of x -> bf16 hi/lo planes (in out2 region)
  k2t<<<dim3(64, 4, 4), 256, 0, stream>>>(x, xTh, xTl);
  // offset conv via MFMA (coalesced W2 A-frags), split-C(4) partials
  k1m<<<dim3(64, BB, 4), 256, 0, stream>>>(xTh, xTl, W2, part1);
  k1r<<<(N1 + 255) / 256, 256, 0, stream>>>(part1, off_b, pyg, pxg, mg);
  // deformable conv; consecutive-lane coalesced gathers; atomic->out1
  k2m<<<dim3(4, 64, 4), 256, 0, stream>>>(xTh, wA, pyg, pxg, mg, out1);
  // bn1 stats
  bn_part<1024, 8><<<dim3(COUTC, 8), 256, 0, stream>>>(out1, psum, pssq);
  bn_fin<<<COUTC, 256, 0, stream>>>(psum, pssq, bn1_g, bn1_b, scale1, shift1, 8,
                                    1.f / 16384.f);
  // bn1 apply + transpose to bf16 channel-last
  k4a<<<dim3(64, 4), 256, 0, stream>>>(out1, scale1, shift1, yT);
  // transposed conv via MFMA + fused bn2 partial stats
  k4m<<<dim3(128, 4), 256, 0, stream>>>(yT, Apk, out2, psum, pssq);
  // fused bn2 finalize + apply
  k6f<<<N4 / 4096, 256, 0, stream>>>(out2, psum, pssq, bn2_g, bn2_b, (float*)d_out);
}

// Round 13
// 213.829 us; speedup vs baseline: 1.5988x; 1.0453x over previous
//
#include <hip/hip_runtime.h>
#include <math.h>

// Problem constants
#define BB 4
#define CINC 256
#define COUTC 128
#define HH 64
#define WW 64
#define OHH 128
#define OWW 128

typedef unsigned short u16;
typedef __attribute__((ext_vector_type(8))) short bf16x8;
typedef __attribute__((ext_vector_type(4))) float f32x4;

__device__ __forceinline__ u16 f2bf(float f) {
  unsigned int u = __float_as_uint(f);
  unsigned int r = u + 0x7FFFu + ((u >> 16) & 1u);  // RNE
  return (u16)(r >> 16);
}

__device__ __forceinline__ unsigned pk(float a, float b) {
  return (unsigned)f2bf(a) | ((unsigned)f2bf(b) << 16);
}

__device__ __forceinline__ float bf2f(short h) {
  return __uint_as_float(((unsigned)(unsigned short)h) << 16);
}

// ---------------- K0all: merged weight preprocessing + out1 bias init.
__global__ __launch_bounds__(256) void k0all(const float* __restrict__ dcn_w,
                                             const float* __restrict__ off_w,
                                             const float* __restrict__ up_w,
                                             const float* __restrict__ dcn_b,
                                             u16* __restrict__ wA,
                                             u16* __restrict__ W2,
                                             u16* __restrict__ Apk,
                                             float* __restrict__ out1) {
  int tid = blockIdx.x * 256 + threadIdx.x;
  if (tid < 294912) {
    int o = tid / 2304;
    int ckr = tid - o * 2304;
    int q = ckr >> 8;
    int c = ckr & 255;
    wA[tid] = f2bf(dcn_w[o * 2304 + c * 9 + q]);
  } else if (tid < 442368) {
    int t2 = tid - 294912;                 // [0, 147456)
    int j = t2 & 7;
    int lane = (t2 >> 3) & 63;
    int kb = (t2 >> 9) % 72;
    int plane = t2 / 36864;
    int l15 = lane & 15, quad = (lane >> 4) & 3;
    int row = (plane & 1) * 16 + l15;
    int kk = kb * 32 + quad * 8 + j;
    int q = kk >> 8, c = kk & 255;
    float w = (row < 27) ? off_w[(row * CINC + c) * 9 + q] : 0.f;
    u16 hi = f2bf(w);
    if (plane < 2) {
      W2[t2] = hi;
    } else {
      float hf = __uint_as_float((unsigned)hi << 16);
      W2[t2] = f2bf(w - hf);
    }
  } else if (tid < 704512) {
    int t2 = tid - 442368;
    int kp = t2 & 511;
    int o = (t2 >> 9) & 127;
    int pq = t2 >> 16;
    int p = pq >> 1, q = pq & 1;
    int ky = kp >> 8, kx = (kp >> 7) & 1, i = kp & 127;
    float v = up_w[((i * COUTC + o) * 4 + (3 - (p + 2 * ky))) * 4 + (3 - (q + 2 * kx))];
    Apk[t2] = f2bf(v);
  } else if (tid < 704512 + BB * COUTC * HH * WW) {
    int t2 = tid - 704512;
    out1[t2] = dcn_b[(t2 >> 12) & 127];
  }
}

// ---------------- K2t: transpose x -> channel-last hi/lo bf16 planes only.
__global__ __launch_bounds__(256) void k2t(const float* __restrict__ x,
                                           u16* __restrict__ xTh,
                                           u16* __restrict__ xTl) {
  int y = blockIdx.x, cq = blockIdx.y, b = blockIdx.z;
  __shared__ float tile[64][65];
  int t = threadIdx.x;
  int tx = t & 63;
  int tg = t >> 6;
#pragma unroll
  for (int i = 0; i < 16; i++) {
    int c = tg * 16 + i;
    tile[c][tx] = x[((size_t)(b * CINC + cq * 64 + c) * HH + y) * WW + tx];
  }
  __syncthreads();
#pragma unroll
  for (int i = 0; i < 16; i++) {
    int xc = tg * 16 + i;
    size_t idx = ((size_t)(b * HH + y) * WW + xc) * CINC + cq * 64 + tx;
    float v = tile[tx][xc];
    u16 hi = f2bf(v);
    float hf = __uint_as_float((unsigned)hi << 16);
    xTh[idx] = hi;
    xTl[idx] = f2bf(v - hf);
  }
}

// ---------------- K1m: offset conv as MFMA GEMM, split-C(4) partials.
// TA-fix (same disease k2m had): x B-frags no longer loaded lane-divergently
// (old: consecutive lanes strode 512B -> 64 lines/instr, ~29us of TA events).
// Now each tap-row [66px][64ch]x2 planes is staged to LDS with SEQUENTIAL-unit
// loads (consecutive lanes read consecutive 16B -> ~16 lines/instr, 11x fewer
// events), frags via ds_read_b128 at dx-shifted pointers. Border masking at
// stage time. Fragment contents bit-identical to r12. Stride-72 pad.
__global__ __launch_bounds__(256) void k1m(const u16* __restrict__ xTh,
                                           const u16* __restrict__ xTl,
                                           const u16* __restrict__ W2,
                                           float* __restrict__ part1) {
  int h = blockIdx.x, b = blockIdx.y, cs = blockIdx.z;
  __shared__ __align__(16) u16 Xs[2][66 * 72];  // [plane][pxi][ch 0..63 +8 pad]
  int t = threadIdx.x;
  int pt = t >> 6;
  int lane15 = t & 15;
  int quad = (t >> 4) & 3;

  f32x4 acc[2];
  acc[0] = (f32x4){0.f, 0.f, 0.f, 0.f};
  acc[1] = (f32x4){0.f, 0.f, 0.f, 0.f};

  const u16* hbase = xTh + (size_t)b * 4096 * CINC + cs * 64;
  const u16* lbase = xTl + (size_t)b * 4096 * CINC + cs * 64;

  for (int r = 0; r < 3; r++) {
    int y = h + r - 1;
    bool yok = (unsigned)y < 64u;
    // stage row y: 66 px x 8 slices x 2 planes = 1056 16B units, sequential
    for (int u = t; u < 1056; u += 256) {
      int plane = u >= 528;
      int uu = u - plane * 528;
      int pxi = uu >> 3;
      int slice = uu & 7;
      int px = pxi - 1;
      bf16x8 v = (bf16x8){0, 0, 0, 0, 0, 0, 0, 0};
      if (yok && (unsigned)px < 64u) {
        const u16* src = (plane ? lbase : hbase) + ((size_t)y * 64 + px) * 256 + slice * 8;
        v = *(const bf16x8*)src;
      }
      *(bf16x8*)&Xs[plane][pxi * 72 + slice * 8] = v;
    }
    __syncthreads();  // row staged

#pragma unroll
    for (int dx = 0; dx < 3; dx++) {
      int q = r * 3 + dx;
      const u16* xr = &Xs[0][(pt * 16 + lane15 + dx) * 72 + quad * 8];
      const u16* lr = &Xs[1][(pt * 16 + lane15 + dx) * 72 + quad * 8];
#pragma unroll
      for (int c8 = 0; c8 < 2; c8++) {
        bf16x8 xh = *(const bf16x8*)(xr + c8 * 32);
        bf16x8 xl = *(const bf16x8*)(lr + c8 * 32);
        int kb = q * 8 + cs * 2 + c8;
        const u16* wb = W2 + (size_t)kb * 512 + (size_t)(t & 63) * 8;
        bf16x8 ah0 = *(const bf16x8*)(wb);
        bf16x8 ah1 = *(const bf16x8*)(wb + 36864);
        bf16x8 al0 = *(const bf16x8*)(wb + 2 * 36864);
        bf16x8 al1 = *(const bf16x8*)(wb + 3 * 36864);
        acc[0] = __builtin_amdgcn_mfma_f32_16x16x32_bf16(ah0, xh, acc[0], 0, 0, 0);
        acc[0] = __builtin_amdgcn_mfma_f32_16x16x32_bf16(ah0, xl, acc[0], 0, 0, 0);
        acc[0] = __builtin_amdgcn_mfma_f32_16x16x32_bf16(al0, xh, acc[0], 0, 0, 0);
        acc[1] = __builtin_amdgcn_mfma_f32_16x16x32_bf16(ah1, xh, acc[1], 0, 0, 0);
        acc[1] = __builtin_amdgcn_mfma_f32_16x16x32_bf16(ah1, xl, acc[1], 0, 0, 0);
        acc[1] = __builtin_amdgcn_mfma_f32_16x16x32_bf16(al1, xh, acc[1], 0, 0, 0);
      }
    }
    __syncthreads();  // reads drained before next row overwrites
  }

  int px = pt * 16 + lane15;
  float* pb = part1 + ((size_t)(cs * BB + b) * 32) * 4096 + h * 64 + px;
#pragma unroll
  for (int tr = 0; tr < 2; tr++)
#pragma unroll
    for (int i = 0; i < 4; i++) {
      int oc = tr * 16 + quad * 4 + i;
      pb[(size_t)oc * 4096] = acc[tr][i];
    }
}

// ---------------- K1r: reduce 4 channel-partials + bias -> py/px/m
__global__ __launch_bounds__(256) void k1r(const float* __restrict__ part1,
                                           const float* __restrict__ off_b,
                                           float* __restrict__ pyg,
                                           float* __restrict__ pxg,
                                           float* __restrict__ mg) {
  int tid = blockIdx.x * 256 + threadIdx.x;
  if (tid >= BB * 27 * HH * WW) return;
  int w = tid & 63;
  int h = (tid >> 6) & 63;
  int oc = (tid >> 12) % 27;
  int b = tid / (27 * 4096);
  int sp = tid & 4095;

  float v = off_b[oc];
#pragma unroll
  for (int cs = 0; cs < 4; cs++)
    v += part1[((size_t)(cs * BB + b) * 32 + oc) * 4096 + sp];

  int k = oc % 9;
  int gi = ((b * 9 + k) * HH + h) * WW + w;
  if (oc < 9) {
    pyg[gi] = v + (float)(oc / 3) - 1.f + (float)h;
  } else if (oc < 18) {
    pxg[gi] = v + (float)((oc - 9) % 3) - 1.f + (float)w;
  } else {
    mg[gi] = 1.f / (1.f + expf(-v));
  }
}

// ---------------- K2m: deformable conv, split-K(4), bf16 MFMA GEMM.
// (r12 proven: 53.6us — consecutive-lane coalesced gathers; unchanged.)
__global__ __launch_bounds__(256) void k2m(const u16* __restrict__ xTh,
                                           const u16* __restrict__ wA,
                                           const float* __restrict__ pyg,
                                           const float* __restrict__ pxg,
                                           const float* __restrict__ mg,
                                           float* __restrict__ out1) {
  int ks = blockIdx.x, h = blockIdx.y, b = blockIdx.z;
  __shared__ __align__(16) u16 scolT[2][64 * 72];  // [px][ch 0..63 +8 pad] bf16
  int t = threadIdx.x;
  int wave = t >> 6;
  int lane15 = t & 15;
  int quad = (t >> 4) & 3;
  int gq = t & 3;             // gather channel-slice (consecutive lanes)
  int gl15 = (t >> 2) & 15;   // gather px within wave tile
  int gpx = wave * 16 + gl15;

  float dw0[9], dw1[9], dw2[9], dw3[9];
  int doA[9], doB[9];
#pragma unroll
  for (int q = 0; q < 9; q++) {
    int gi = ((b * 9 + q) * HH + h) * WW + gpx;
    float py = pyg[gi], pxx = pxg[gi], m = mg[gi];
    float y0f = floorf(py), x0f = floorf(pxx);
    float wy = py - y0f, wx = pxx - x0f;
    int y0 = (int)y0f, x0 = (int)x0f;
    bool vy0 = (unsigned)y0 < 64u, vy1 = (unsigned)(y0 + 1) < 64u;
    bool vx0 = (unsigned)x0 < 64u, vx1 = (unsigned)(x0 + 1) < 64u;
    int y0c = min(max(y0, 0), 63), y1c = min(max(y0 + 1, 0), 63);
    int x0c = min(max(x0, 0), 63), x1c = min(max(x0 + 1, 0), 63);
    dw0[q] = (vy0 && vx0) ? (1.f - wy) * (1.f - wx) * m : 0.f;
    dw1[q] = (vy0 && vx1) ? (1.f - wy) * wx * m : 0.f;
    dw2[q] = (vy1 && vx0) ? wy * (1.f - wx) * m : 0.f;
    dw3[q] = (vy1 && vx1) ? wy * wx * m : 0.f;
    doA[q] = (y0c * 64 + x0c) | ((y0c * 64 + x1c) << 16);
    doB[q] = (y1c * 64 + x0c) | ((y1c * 64 + x1c) << 16);
  }

  f32x4 acc[8];
#pragma unroll
  for (int i = 0; i < 8; i++) acc[i] = (f32x4){0.f, 0.f, 0.f, 0.f};

  const u16* xTb = xTh + (size_t)b * 4096 * CINC + ks * 64 + gq * 8;
  const u16* wAr0 = wA + (wave * 32 + lane15) * 2304 + quad * 8;
  const u16* wAr1 = wAr0 + 16 * 2304;

  bf16x8 rx[8];
#define GATHER_TAP(qq)                                                       \
  {                                                                          \
    int sA0 = doA[qq] & 0xffff, sA1 = ((unsigned)doA[qq]) >> 16;             \
    int sB0 = doB[qq] & 0xffff, sB1 = ((unsigned)doB[qq]) >> 16;             \
    const u16* p0 = xTb + (size_t)sA0 * CINC;                                \
    const u16* p1 = xTb + (size_t)sA1 * CINC;                                \
    const u16* p2 = xTb + (size_t)sB0 * CINC;                                \
    const u16* p3 = xTb + (size_t)sB1 * CINC;                                \
    rx[0] = *(const bf16x8*)p0;                                              \
    rx[1] = *(const bf16x8*)(p0 + 32);                                       \
    rx[2] = *(const bf16x8*)p1;                                              \
    rx[3] = *(const bf16x8*)(p1 + 32);                                       \
    rx[4] = *(const bf16x8*)p2;                                              \
    rx[5] = *(const bf16x8*)(p2 + 32);                                       \
    rx[6] = *(const bf16x8*)p3;                                              \
    rx[7] = *(const bf16x8*)(p3 + 32);                                       \
  }

  GATHER_TAP(0);

#pragma unroll
  for (int q = 0; q < 9; q++) {
    float v[16];
#pragma unroll
    for (int j = 0; j < 8; j++) {
      v[j] = dw0[q] * bf2f(rx[0][j]) + dw1[q] * bf2f(rx[2][j]) +
             dw2[q] * bf2f(rx[4][j]) + dw3[q] * bf2f(rx[6][j]);
      v[8 + j] = dw0[q] * bf2f(rx[1][j]) + dw1[q] * bf2f(rx[3][j]) +
                 dw2[q] * bf2f(rx[5][j]) + dw3[q] * bf2f(rx[7][j]);
    }
    u16* sb = &scolT[q & 1][gpx * 72 + gq * 8];
    uint4 s0, s1;
    s0.x = pk(v[0], v[1]);  s0.y = pk(v[2], v[3]);
    s0.z = pk(v[4], v[5]);  s0.w = pk(v[6], v[7]);
    s1.x = pk(v[8], v[9]);  s1.y = pk(v[10], v[11]);
    s1.z = pk(v[12], v[13]); s1.w = pk(v[14], v[15]);
    *(uint4*)sb = s0;
    *(uint4*)(sb + 32) = s1;

    if (q < 8) GATHER_TAP(q + 1);

    __syncthreads();
#pragma unroll
    for (int c32 = 0; c32 < 2; c32++) {
      int kb = q * 256 + ks * 64 + c32 * 32;
      bf16x8 a0 = *(const bf16x8*)(wAr0 + kb);
      bf16x8 a1 = *(const bf16x8*)(wAr1 + kb);
      const u16* sr = &scolT[q & 1][lane15 * 72 + c32 * 32 + quad * 8];
      bf16x8 b0 = *(const bf16x8*)(sr);
      bf16x8 b1 = *(const bf16x8*)(sr + 16 * 72);
      bf16x8 b2 = *(const bf16x8*)(sr + 32 * 72);
      bf16x8 b3 = *(const bf16x8*)(sr + 48 * 72);
      acc[0] = __builtin_amdgcn_mfma_f32_16x16x32_bf16(a0, b0, acc[0], 0, 0, 0);
      acc[1] = __builtin_amdgcn_mfma_f32_16x16x32_bf16(a0, b1, acc[1], 0, 0, 0);
      acc[2] = __builtin_amdgcn_mfma_f32_16x16x32_bf16(a0, b2, acc[2], 0, 0, 0);
      acc[3] = __builtin_amdgcn_mfma_f32_16x16x32_bf16(a0, b3, acc[3], 0, 0, 0);
      acc[4] = __builtin_amdgcn_mfma_f32_16x16x32_bf16(a1, b0, acc[4], 0, 0, 0);
      acc[5] = __builtin_amdgcn_mfma_f32_16x16x32_bf16(a1, b1, acc[5], 0, 0, 0);
      acc[6] = __builtin_amdgcn_mfma_f32_16x16x32_bf16(a1, b2, acc[6], 0, 0, 0);
      acc[7] = __builtin_amdgcn_mfma_f32_16x16x32_bf16(a1, b3, acc[7], 0, 0, 0);
    }
  }
#undef GATHER_TAP

#pragma unroll
  for (int tr = 0; tr < 2; tr++)
#pragma unroll
    for (int pc = 0; pc < 4; pc++) {
      f32x4 a = acc[tr * 4 + pc];
      int ob = wave * 32 + tr * 16 + quad * 4;
#pragma unroll
      for (int i = 0; i < 4; i++)
        atomicAdd(&out1[((b * COUTC + ob + i) * HH + h) * WW + pc * 16 + lane15], a[i]);
    }
}

// ---------------- BN stats: single-pass split reduction (sum + sumsq).
template <int PLANEF4, int NCHUNK>
__global__ __launch_bounds__(256) void bn_part(const float* __restrict__ src,
                                               float* __restrict__ psum,
                                               float* __restrict__ pssq) {
  int c = blockIdx.x, chunk = blockIdx.y, t = threadIdx.x;
  constexpr int PER = (BB * PLANEF4) / NCHUNK;  // float4s per chunk
  float s = 0.f, s2 = 0.f;
#pragma unroll
  for (int i = 0; i < PER / 256; i++) {
    int f = chunk * PER + i * 256 + t;
    int b = f / PLANEF4;
    int sp = f - b * PLANEF4;
    const float4 v = *(const float4*)&src[((size_t)(b * COUTC + c) * PLANEF4 + sp) * 4];
    s += v.x + v.y + v.z + v.w;
    s2 += v.x * v.x + v.y * v.y + v.z * v.z + v.w * v.w;
  }
#pragma unroll
  for (int off = 32; off > 0; off >>= 1) {
    s += __shfl_down(s, off);
    s2 += __shfl_down(s2, off);
  }
  __shared__ float rs[4], rq[4];
  int wv = t >> 6;
  if ((t & 63) == 0) { rs[wv] = s; rq[wv] = s2; }
  __syncthreads();
  if (t == 0) {
    psum[c * NCHUNK + chunk] = rs[0] + rs[1] + rs[2] + rs[3];
    pssq[c * NCHUNK + chunk] = rq[0] + rq[1] + rq[2] + rq[3];
  }
}

// finalize: block-per-channel — parallel partial reduce (bn1 only)
__global__ __launch_bounds__(256) void bn_fin(const float* __restrict__ psum,
                                              const float* __restrict__ pssq,
                                              const float* __restrict__ g,
                                              const float* __restrict__ bt,
                                              float* __restrict__ scale,
                                              float* __restrict__ shift,
                                              int nchunk, float invN) {
  int c = blockIdx.x, t = threadIdx.x;
  float S = 0.f, Q = 0.f;
  for (int i = t; i < nchunk; i += 256) {
    S += psum[c * nchunk + i];
    Q += pssq[c * nchunk + i];
  }
#pragma unroll
  for (int off = 32; off > 0; off >>= 1) {
    S += __shfl_down(S, off);
    Q += __shfl_down(Q, off);
  }
  __shared__ float rs[4], rq[4];
  int wv = t >> 6;
  if ((t & 63) == 0) { rs[wv] = S; rq[wv] = Q; }
  __syncthreads();
  if (t == 0) {
    S = rs[0] + rs[1] + rs[2] + rs[3];
    Q = rq[0] + rq[1] + rq[2] + rq[3];
    float mu = S * invN;
    float var = Q * invN - mu * mu;
    float sc = g[c] * rsqrtf(var + 1e-5f);
    scale[c] = sc;
    shift[c] = bt[c] - mu * sc;
  }
}

// ---------------- K4a: bn1+relu apply, bf16 convert, channel-last transpose.
__global__ __launch_bounds__(256) void k4a(const float* __restrict__ out1,
                                           const float* __restrict__ s1,
                                           const float* __restrict__ sh1,
                                           u16* __restrict__ yT) {
  int m = blockIdx.x, b = blockIdx.y;
  __shared__ __align__(16) u16 T2[64 * 136];
  int t = threadIdx.x;
  for (int e = t; e < 2048; e += 256) {
    int w4 = e & 15, c = e >> 4;
    float4 r = *(const float4*)&out1[((b * COUTC + c) * HH + m) * WW + w4 * 4];
    float sc = s1[c], sh = sh1[c];
    T2[(w4 * 4 + 0) * 136 + c] = f2bf(fmaxf(fmaf(r.x, sc, sh), 0.f));
    T2[(w4 * 4 + 1) * 136 + c] = f2bf(fmaxf(fmaf(r.y, sc, sh), 0.f));
    T2[(w4 * 4 + 2) * 136 + c] = f2bf(fmaxf(fmaf(r.z, sc, sh), 0.f));
    T2[(w4 * 4 + 3) * 136 + c] = f2bf(fmaxf(fmaf(r.w, sc, sh), 0.f));
  }
  __syncthreads();
  for (int e = t; e < 1024; e += 256) {
    int g2 = e * 8;
    int w = g2 >> 7, i = g2 & 127;
    *(bf16x8*)&yT[((size_t)(b * 64 + m) * 64 + w) * 128 + i] =
        *(const bf16x8*)&T2[w * 136 + i];
  }
}

// ---------------- K4m: transposed conv as bf16 MFMA GEMM + fused bn2 partials.
__global__ __launch_bounds__(256) void k4m(const u16* __restrict__ yT,
                                           const u16* __restrict__ Apk,
                                           float* __restrict__ out2,
                                           float* __restrict__ psum2,
                                           float* __restrict__ pssq2) {
  int oh = blockIdx.x, b = blockIdx.y;
  int a = oh >> 1, p = oh & 1;
  __shared__ __align__(16) u16 T[2][66 * 136];
  int t = threadIdx.x;
  int wave = t >> 6, lane15 = t & 15, quad = (t >> 4) & 3;

  for (int e = t; e < 512; e += 256) {
    int ky = e >> 8;
    int rem = e & 255;
    int colp = (rem >> 7) * 65;
    int i = rem & 127;
    T[ky][colp * 136 + i] = 0;
  }
#pragma unroll
  for (int ky = 0; ky < 2; ky++) {
    int r = a + p + ky - 1;
    bool ok = ((unsigned)r < 64u);
    const u16* src = yT + ((size_t)(b * 64 + r) * 64) * 128;
#pragma unroll
    for (int it = 0; it < 4; it++) {
      int g2 = (it * 256 + t) * 8;
      int col = g2 >> 7, i = g2 & 127;
      bf16x8 v = (bf16x8){0, 0, 0, 0, 0, 0, 0, 0};
      if (ok) v = *(const bf16x8*)(src + g2);
      *(bf16x8*)&T[ky][(col + 1) * 136 + i] = v;
    }
  }
  __syncthreads();

  f32x4 acc[2][2][4];  // [q][tr][pc]
#pragma unroll
  for (int q = 0; q < 2; q++)
#pragma unroll
    for (int tr = 0; tr < 2; tr++)
#pragma unroll
      for (int pc = 0; pc < 4; pc++) acc[q][tr][pc] = (f32x4){0.f, 0.f, 0.f, 0.f};

  int row0 = wave * 32 + lane15;
  const u16* A0 = Apk + ((size_t)(p * 2 + 0) * 128) * 512;
  const u16* A1 = Apk + ((size_t)(p * 2 + 1) * 128) * 512;

#pragma unroll
  for (int ky = 0; ky < 2; ky++)
#pragma unroll
    for (int kx = 0; kx < 2; kx++)
#pragma unroll
      for (int c4 = 0; c4 < 4; c4++) {
        int kb = (ky * 2 + kx) * 128 + c4 * 32 + quad * 8;
        bf16x8 a00 = *(const bf16x8*)(A0 + (size_t)row0 * 512 + kb);
        bf16x8 a01 = *(const bf16x8*)(A0 + (size_t)(row0 + 16) * 512 + kb);
        bf16x8 a10 = *(const bf16x8*)(A1 + (size_t)row0 * 512 + kb);
        bf16x8 a11 = *(const bf16x8*)(A1 + (size_t)(row0 + 16) * 512 + kb);
        const u16* tb = &T[ky][(lane15 + kx) * 136 + c4 * 32 + quad * 8];
#pragma unroll
        for (int pc = 0; pc < 4; pc++) {
          bf16x8 b0 = *(const bf16x8*)(tb + (pc * 16) * 136);
          bf16x8 b1 = *(const bf16x8*)(tb + (pc * 16 + 1) * 136);
          acc[0][0][pc] = __builtin_amdgcn_mfma_f32_16x16x32_bf16(a00, b0, acc[0][0][pc], 0, 0, 0);
          acc[0][1][pc] = __builtin_amdgcn_mfma_f32_16x16x32_bf16(a01, b0, acc[0][1][pc], 0, 0, 0);
          acc[1][0][pc] = __builtin_amdgcn_mfma_f32_16x16x32_bf16(a10, b1, acc[1][0][pc], 0, 0, 0);
          acc[1][1][pc] = __builtin_amdgcn_mfma_f32_16x16x32_bf16(a11, b1, acc[1][1][pc], 0, 0, 0);
        }
      }

#pragma unroll
  for (int tr = 0; tr < 2; tr++) {
    int o0 = wave * 32 + tr * 16 + quad * 4;
#pragma unroll
    for (int pc = 0; pc < 4; pc++) {
      f32x4 v0 = acc[0][tr][pc];
      f32x4 v1 = acc[1][tr][pc];
      int cw = pc * 32 + 2 * lane15;
#pragma unroll
      for (int i = 0; i < 4; i++) {
        float2 w2;
        w2.x = v0[i];
        w2.y = v1[i];
        *(float2*)&out2[(((size_t)b * COUTC + o0 + i) * OHH + oh) * OWW + cw] = w2;
      }
    }
  }

  int blk = b * 128 + oh;
#pragma unroll
  for (int tr = 0; tr < 2; tr++)
#pragma unroll
    for (int i = 0; i < 4; i++) {
      float s = 0.f, s2 = 0.f;
#pragma unroll
      for (int q = 0; q < 2; q++)
#pragma unroll
        for (int pc = 0; pc < 4; pc++) {
          float v = acc[q][tr][pc][i];
          s += v;
          s2 += v * v;
        }
#pragma unroll
      for (int off = 1; off < 16; off <<= 1) {
        s += __shfl_xor(s, off);
        s2 += __shfl_xor(s2, off);
      }
      if (lane15 == 0) {
        int c = wave * 32 + tr * 16 + quad * 4 + i;
        psum2[c * 512 + blk] = s;
        pssq2[c * 512 + blk] = s2;
      }
    }
}

// ---------------- K6f: fused bn2 finalize + apply (f32 out), float4-vectorized.
__global__ __launch_bounds__(256) void k6f(const float* __restrict__ out2,
                                           const float* __restrict__ psum2,
                                           const float* __restrict__ pssq2,
                                           const float* __restrict__ g,
                                           const float* __restrict__ bt,
                                           float* __restrict__ outp) {
  int blk = blockIdx.x, t = threadIdx.x;
  int c = (blk >> 2) & 127;

  float S = psum2[c * 512 + t] + psum2[c * 512 + 256 + t];
  float Q = pssq2[c * 512 + t] + pssq2[c * 512 + 256 + t];
#pragma unroll
  for (int off = 32; off > 0; off >>= 1) {
    S += __shfl_down(S, off);
    Q += __shfl_down(Q, off);
  }
  __shared__ float rs[4], rq[4], sSC, sSH;
  int wv = t >> 6;
  if ((t & 63) == 0) { rs[wv] = S; rq[wv] = Q; }
  __syncthreads();
  if (t == 0) {
    S = rs[0] + rs[1] + rs[2] + rs[3];
    Q = rq[0] + rq[1] + rq[2] + rq[3];
    float mu = S / 65536.f;
    float var = Q / 65536.f - mu * mu;
    float sc = g[c] * rsqrtf(var + 1e-5f);
    sSC = sc;
    sSH = bt[c] - mu * sc;
  }
  __syncthreads();
  float sc = sSC, sh = sSH;
  int base = blk * 1024;
#pragma unroll
  for (int i = 0; i < 4; i++) {
    int f4 = base + i * 256 + t;
    float4 v = *(const float4*)&out2[f4 * 4];
    float4 o;
    o.x = fmaxf(fmaf(v.x, sc, sh), 0.f);
    o.y = fmaxf(fmaf(v.y, sc, sh), 0.f);
    o.z = fmaxf(fmaf(v.z, sc, sh), 0.f);
    o.w = fmaxf(fmaf(v.w, sc, sh), 0.f);
    *(float4*)&outp[f4 * 4] = o;
  }
}

// ---------------- launch
extern "C" void kernel_launch(void* const* d_in, const int* in_sizes, int n_in,
                              void* d_out, int out_size, void* d_ws, size_t ws_size,
                              hipStream_t stream) {
  const float* x     = (const float*)d_in[0];
  const float* off_w = (const float*)d_in[1];
  const float* off_b = (const float*)d_in[2];
  const float* dcn_w = (const float*)d_in[3];
  const float* dcn_b = (const float*)d_in[4];
  const float* bn1_g = (const float*)d_in[5];
  const float* bn1_b = (const float*)d_in[6];
  const float* up_w  = (const float*)d_in[7];
  const float* bn2_g = (const float*)d_in[8];
  const float* bn2_b = (const float*)d_in[9];

  float* ws = (float*)d_ws;
  float* pyg  = ws;                              // 147456
  float* pxg  = pyg + BB * 9 * HH * WW;          // 147456
  float* mg   = pxg + BB * 9 * HH * WW;          // 147456
  float* out1 = mg + BB * 9 * HH * WW;           // 2097152
  float* scale1 = out1 + BB * COUTC * HH * WW;   // 128
  float* shift1 = scale1 + 128;                  // 128
  float* out2 = shift1 + 128;                    // 8388608
  float* scale2 = out2 + BB * COUTC * OHH * OWW; // 128 (unused)
  float* shift2 = scale2 + 128;                  // 128 (unused)
  float* w_t = shift2 + 128;                     // 294912 floats reserved
  float* wt4 = w_t + COUTC * CINC * 9;           // 262144 floats (Apk uses as u16)
  float* part2 = wt4 + 4 * COUTC * COUTC * 4;    // scratch
  u16* wA = (u16*)w_t;
  u16* W2 = (u16*)(w_t + 147456);                // frag-major hi/lo 147456 bf16
  u16* Apk = (u16*)wt4;
  u16* xTh = (u16*)out2;
  u16* xTl = (u16*)(out2 + 2097152);
  float* psum = part2;                           // 128*512
  float* pssq = part2 + 65536;
  u16* yT = (u16*)(part2 + 131072);              // bf16 4MB
  float* part1 = part2 + 131072 + 2097152;       // 2.1M floats

  const int N4 = BB * COUTC * OHH * OWW;  // 8388608
  const int N2 = BB * COUTC * HH * WW;    // 2097152
  const int N1 = BB * 27 * HH * WW;       // 442368

  k0all<<<(704512 + N2 + 255) / 256, 256, 0, stream>>>(dcn_w, off_w, up_w, dcn_b,
                                                       wA, W2, Apk, out1);
  k2t<<<dim3(64, 4, 4), 256, 0, stream>>>(x, xTh, xTl);
  // offset conv: LDS row-staged, TA-coalesced
  k1m<<<dim3(64, BB, 4), 256, 0, stream>>>(xTh, xTl, W2, part1);
  k1r<<<(N1 + 255) / 256, 256, 0, stream>>>(part1, off_b, pyg, pxg, mg);
  k2m<<<dim3(4, 64, 4), 256, 0, stream>>>(xTh, wA, pyg, pxg, mg, out1);
  bn_part<1024, 8><<<dim3(COUTC, 8), 256, 0, stream>>>(out1, psum, pssq);
  bn_fin<<<COUTC, 256, 0, stream>>>(psum, pssq, bn1_g, bn1_b, scale1, shift1, 8,
                                    1.f / 16384.f);
  k4a<<<dim3(64, 4), 256, 0, stream>>>(out1, scale1, shift1, yT);
  k4m<<<dim3(128, 4), 256, 0, stream>>>(yT, Apk, out2, psum, pssq);
  k6f<<<N4 / 4096, 256, 0, stream>>>(out2, psum, pssq, bn2_g, bn2_b, (float*)d_out);
}

// Round 14
// 212.985 us; speedup vs baseline: 1.6051x; 1.0040x over previous
//
#include <hip/hip_runtime.h>
#include <math.h>

// Problem constants
#define BB 4
#define CINC 256
#define COUTC 128
#define HH 64
#define WW 64
#define OHH 128
#define OWW 128

typedef unsigned short u16;
typedef __attribute__((ext_vector_type(8))) short bf16x8;
typedef __attribute__((ext_vector_type(4))) float f32x4;

__device__ __forceinline__ u16 f2bf(float f) {
  unsigned int u = __float_as_uint(f);
  unsigned int r = u + 0x7FFFu + ((u >> 16) & 1u);  // RNE
  return (u16)(r >> 16);
}

__device__ __forceinline__ unsigned pk(float a, float b) {
  return (unsigned)f2bf(a) | ((unsigned)f2bf(b) << 16);
}

__device__ __forceinline__ float bf2f(short h) {
  return __uint_as_float(((unsigned)(unsigned short)h) << 16);
}

// ---------------- K0: merged preprocessing.
// blocks [0,1024): k2t transpose x -> channel-last hi/lo bf16 planes (LDS tile)
// blocks [1024,...): weight prep (wA, W2, Apk) + out1 bias init, flat tid.
__global__ __launch_bounds__(256) void k0(const float* __restrict__ x,
                                          const float* __restrict__ dcn_w,
                                          const float* __restrict__ off_w,
                                          const float* __restrict__ up_w,
                                          const float* __restrict__ dcn_b,
                                          u16* __restrict__ xTh,
                                          u16* __restrict__ xTl,
                                          u16* __restrict__ wA,
                                          u16* __restrict__ W2,
                                          u16* __restrict__ Apk,
                                          float* __restrict__ out1) {
  int bid = blockIdx.x;
  int t = threadIdx.x;
  if (bid < 1024) {
    // ---- k2t part ----
    int y = bid & 63, cq = (bid >> 6) & 3, b = bid >> 8;
    __shared__ float tile[64][65];
    int tx = t & 63;
    int tg = t >> 6;
#pragma unroll
    for (int i = 0; i < 16; i++) {
      int c = tg * 16 + i;
      tile[c][tx] = x[((size_t)(b * CINC + cq * 64 + c) * HH + y) * WW + tx];
    }
    __syncthreads();
#pragma unroll
    for (int i = 0; i < 16; i++) {
      int xc = tg * 16 + i;
      size_t idx = ((size_t)(b * HH + y) * WW + xc) * CINC + cq * 64 + tx;
      float v = tile[tx][xc];
      u16 hi = f2bf(v);
      float hf = __uint_as_float((unsigned)hi << 16);
      xTh[idx] = hi;
      xTl[idx] = f2bf(v - hf);
    }
    return;
  }
  int tid = (bid - 1024) * 256 + t;
  if (tid < 294912) {
    int o = tid / 2304;
    int ckr = tid - o * 2304;
    int q = ckr >> 8;
    int c = ckr & 255;
    wA[tid] = f2bf(dcn_w[o * 2304 + c * 9 + q]);
  } else if (tid < 442368) {
    int t2 = tid - 294912;                 // [0, 147456)
    int j = t2 & 7;
    int lane = (t2 >> 3) & 63;
    int kb = (t2 >> 9) % 72;
    int plane = t2 / 36864;
    int l15 = lane & 15, quad = (lane >> 4) & 3;
    int row = (plane & 1) * 16 + l15;
    int kk = kb * 32 + quad * 8 + j;
    int q = kk >> 8, c = kk & 255;
    float w = (row < 27) ? off_w[(row * CINC + c) * 9 + q] : 0.f;
    u16 hi = f2bf(w);
    if (plane < 2) {
      W2[t2] = hi;
    } else {
      float hf = __uint_as_float((unsigned)hi << 16);
      W2[t2] = f2bf(w - hf);
    }
  } else if (tid < 704512) {
    int t2 = tid - 442368;
    int kp = t2 & 511;
    int o = (t2 >> 9) & 127;
    int pq = t2 >> 16;
    int p = pq >> 1, q = pq & 1;
    int ky = kp >> 8, kx = (kp >> 7) & 1, i = kp & 127;
    float v = up_w[((i * COUTC + o) * 4 + (3 - (p + 2 * ky))) * 4 + (3 - (q + 2 * kx))];
    Apk[t2] = f2bf(v);
  } else if (tid < 704512 + BB * COUTC * HH * WW) {
    int t2 = tid - 704512;
    out1[t2] = dcn_b[(t2 >> 12) & 127];
  }
}

// ---------------- K1m: offset conv as MFMA GEMM, split-C(4) partials.
// LDS row-staged, TA-coalesced (r13 proven).
__global__ __launch_bounds__(256) void k1m(const u16* __restrict__ xTh,
                                           const u16* __restrict__ xTl,
                                           const u16* __restrict__ W2,
                                           float* __restrict__ part1) {
  int h = blockIdx.x, b = blockIdx.y, cs = blockIdx.z;
  __shared__ __align__(16) u16 Xs[2][66 * 72];  // [plane][pxi][ch 0..63 +8 pad]
  int t = threadIdx.x;
  int pt = t >> 6;
  int lane15 = t & 15;
  int quad = (t >> 4) & 3;

  f32x4 acc[2];
  acc[0] = (f32x4){0.f, 0.f, 0.f, 0.f};
  acc[1] = (f32x4){0.f, 0.f, 0.f, 0.f};

  const u16* hbase = xTh + (size_t)b * 4096 * CINC + cs * 64;
  const u16* lbase = xTl + (size_t)b * 4096 * CINC + cs * 64;

  for (int r = 0; r < 3; r++) {
    int y = h + r - 1;
    bool yok = (unsigned)y < 64u;
    for (int u = t; u < 1056; u += 256) {
      int plane = u >= 528;
      int uu = u - plane * 528;
      int pxi = uu >> 3;
      int slice = uu & 7;
      int px = pxi - 1;
      bf16x8 v = (bf16x8){0, 0, 0, 0, 0, 0, 0, 0};
      if (yok && (unsigned)px < 64u) {
        const u16* src = (plane ? lbase : hbase) + ((size_t)y * 64 + px) * 256 + slice * 8;
        v = *(const bf16x8*)src;
      }
      *(bf16x8*)&Xs[plane][pxi * 72 + slice * 8] = v;
    }
    __syncthreads();

#pragma unroll
    for (int dx = 0; dx < 3; dx++) {
      int q = r * 3 + dx;
      const u16* xr = &Xs[0][(pt * 16 + lane15 + dx) * 72 + quad * 8];
      const u16* lr = &Xs[1][(pt * 16 + lane15 + dx) * 72 + quad * 8];
#pragma unroll
      for (int c8 = 0; c8 < 2; c8++) {
        bf16x8 xh = *(const bf16x8*)(xr + c8 * 32);
        bf16x8 xl = *(const bf16x8*)(lr + c8 * 32);
        int kb = q * 8 + cs * 2 + c8;
        const u16* wb = W2 + (size_t)kb * 512 + (size_t)(t & 63) * 8;
        bf16x8 ah0 = *(const bf16x8*)(wb);
        bf16x8 ah1 = *(const bf16x8*)(wb + 36864);
        bf16x8 al0 = *(const bf16x8*)(wb + 2 * 36864);
        bf16x8 al1 = *(const bf16x8*)(wb + 3 * 36864);
        acc[0] = __builtin_amdgcn_mfma_f32_16x16x32_bf16(ah0, xh, acc[0], 0, 0, 0);
        acc[0] = __builtin_amdgcn_mfma_f32_16x16x32_bf16(ah0, xl, acc[0], 0, 0, 0);
        acc[0] = __builtin_amdgcn_mfma_f32_16x16x32_bf16(al0, xh, acc[0], 0, 0, 0);
        acc[1] = __builtin_amdgcn_mfma_f32_16x16x32_bf16(ah1, xh, acc[1], 0, 0, 0);
        acc[1] = __builtin_amdgcn_mfma_f32_16x16x32_bf16(ah1, xl, acc[1], 0, 0, 0);
        acc[1] = __builtin_amdgcn_mfma_f32_16x16x32_bf16(al1, xh, acc[1], 0, 0, 0);
      }
    }
    __syncthreads();
  }

  int px = pt * 16 + lane15;
  float* pb = part1 + ((size_t)(cs * BB + b) * 32) * 4096 + h * 64 + px;
#pragma unroll
  for (int tr = 0; tr < 2; tr++)
#pragma unroll
    for (int i = 0; i < 4; i++) {
      int oc = tr * 16 + quad * 4 + i;
      pb[(size_t)oc * 4096] = acc[tr][i];
    }
}

// ---------------- K1r: reduce 4 channel-partials + bias -> py/px/m
__global__ __launch_bounds__(256) void k1r(const float* __restrict__ part1,
                                           const float* __restrict__ off_b,
                                           float* __restrict__ pyg,
                                           float* __restrict__ pxg,
                                           float* __restrict__ mg) {
  int tid = blockIdx.x * 256 + threadIdx.x;
  if (tid >= BB * 27 * HH * WW) return;
  int w = tid & 63;
  int h = (tid >> 6) & 63;
  int oc = (tid >> 12) % 27;
  int b = tid / (27 * 4096);
  int sp = tid & 4095;

  float v = off_b[oc];
#pragma unroll
  for (int cs = 0; cs < 4; cs++)
    v += part1[((size_t)(cs * BB + b) * 32 + oc) * 4096 + sp];

  int k = oc % 9;
  int gi = ((b * 9 + k) * HH + h) * WW + w;
  if (oc < 9) {
    pyg[gi] = v + (float)(oc / 3) - 1.f + (float)h;
  } else if (oc < 18) {
    pxg[gi] = v + (float)((oc - 9) % 3) - 1.f + (float)w;
  } else {
    mg[gi] = 1.f / (1.f + expf(-v));
  }
}

// ---------------- K2m: deformable conv, split-K(4), bf16 MFMA GEMM.
// r12 structure (consecutive-lane coalesced gathers, 53.6us) + 2-DEEP gather
// pipeline: gathers for tap q+2 issued at tap q land two barrier+MFMA phases
// later (~2x200cy cover vs 1-deep's ~80cy) — barrier-pinned so the compiler
// can't sink them (r5/r6 lesson). rx ping-pong +32 VGPR.
__global__ __launch_bounds__(256) void k2m(const u16* __restrict__ xTh,
                                           const u16* __restrict__ wA,
                                           const float* __restrict__ pyg,
                                           const float* __restrict__ pxg,
                                           const float* __restrict__ mg,
                                           float* __restrict__ out1) {
  int ks = blockIdx.x, h = blockIdx.y, b = blockIdx.z;
  __shared__ __align__(16) u16 scolT[2][64 * 72];  // [px][ch 0..63 +8 pad] bf16
  int t = threadIdx.x;
  int wave = t >> 6;
  int lane15 = t & 15;
  int quad = (t >> 4) & 3;
  int gq = t & 3;             // gather channel-slice (consecutive lanes)
  int gl15 = (t >> 2) & 15;   // gather px within wave tile
  int gpx = wave * 16 + gl15;

  float dw0[9], dw1[9], dw2[9], dw3[9];
  int doA[9], doB[9];
#pragma unroll
  for (int q = 0; q < 9; q++) {
    int gi = ((b * 9 + q) * HH + h) * WW + gpx;
    float py = pyg[gi], pxx = pxg[gi], m = mg[gi];
    float y0f = floorf(py), x0f = floorf(pxx);
    float wy = py - y0f, wx = pxx - x0f;
    int y0 = (int)y0f, x0 = (int)x0f;
    bool vy0 = (unsigned)y0 < 64u, vy1 = (unsigned)(y0 + 1) < 64u;
    bool vx0 = (unsigned)x0 < 64u, vx1 = (unsigned)(x0 + 1) < 64u;
    int y0c = min(max(y0, 0), 63), y1c = min(max(y0 + 1, 0), 63);
    int x0c = min(max(x0, 0), 63), x1c = min(max(x0 + 1, 0), 63);
    dw0[q] = (vy0 && vx0) ? (1.f - wy) * (1.f - wx) * m : 0.f;
    dw1[q] = (vy0 && vx1) ? (1.f - wy) * wx * m : 0.f;
    dw2[q] = (vy1 && vx0) ? wy * (1.f - wx) * m : 0.f;
    dw3[q] = (vy1 && vx1) ? wy * wx * m : 0.f;
    doA[q] = (y0c * 64 + x0c) | ((y0c * 64 + x1c) << 16);
    doB[q] = (y1c * 64 + x0c) | ((y1c * 64 + x1c) << 16);
  }

  f32x4 acc[8];
#pragma unroll
  for (int i = 0; i < 8; i++) acc[i] = (f32x4){0.f, 0.f, 0.f, 0.f};

  const u16* xTb = xTh + (size_t)b * 4096 * CINC + ks * 64 + gq * 8;
  const u16* wAr0 = wA + (wave * 32 + lane15) * 2304 + quad * 8;
  const u16* wAr1 = wAr0 + 16 * 2304;

  bf16x8 rxA[8], rxB[8];  // 2-deep ping-pong
#define GATHER_TAP(qq, r)                                                    \
  {                                                                          \
    int sA0 = doA[qq] & 0xffff, sA1 = ((unsigned)doA[qq]) >> 16;             \
    int sB0 = doB[qq] & 0xffff, sB1 = ((unsigned)doB[qq]) >> 16;             \
    const u16* p0 = xTb + (size_t)sA0 * CINC;                                \
    const u16* p1 = xTb + (size_t)sA1 * CINC;                                \
    const u16* p2 = xTb + (size_t)sB0 * CINC;                                \
    const u16* p3 = xTb + (size_t)sB1 * CINC;                                \
    r[0] = *(const bf16x8*)p0;                                               \
    r[1] = *(const bf16x8*)(p0 + 32);                                        \
    r[2] = *(const bf16x8*)p1;                                               \
    r[3] = *(const bf16x8*)(p1 + 32);                                        \
    r[4] = *(const bf16x8*)p2;                                               \
    r[5] = *(const bf16x8*)(p2 + 32);                                        \
    r[6] = *(const bf16x8*)p3;                                               \
    r[7] = *(const bf16x8*)(p3 + 32);                                        \
  }

  GATHER_TAP(0, rxA);
  GATHER_TAP(1, rxB);

#pragma unroll
  for (int q = 0; q < 9; q++) {
    const bf16x8* rx = (q & 1) ? rxB : rxA;
    float v[16];
#pragma unroll
    for (int j = 0; j < 8; j++) {
      v[j] = dw0[q] * bf2f(rx[0][j]) + dw1[q] * bf2f(rx[2][j]) +
             dw2[q] * bf2f(rx[4][j]) + dw3[q] * bf2f(rx[6][j]);
      v[8 + j] = dw0[q] * bf2f(rx[1][j]) + dw1[q] * bf2f(rx[3][j]) +
                 dw2[q] * bf2f(rx[5][j]) + dw3[q] * bf2f(rx[7][j]);
    }
    u16* sb = &scolT[q & 1][gpx * 72 + gq * 8];
    uint4 s0, s1;
    s0.x = pk(v[0], v[1]);  s0.y = pk(v[2], v[3]);
    s0.z = pk(v[4], v[5]);  s0.w = pk(v[6], v[7]);
    s1.x = pk(v[8], v[9]);  s1.y = pk(v[10], v[11]);
    s1.z = pk(v[12], v[13]); s1.w = pk(v[14], v[15]);
    *(uint4*)sb = s0;
    *(uint4*)(sb + 32) = s1;

    // issue tap q+2's gathers into the buffer just consumed (2 phases of cover)
    if (q < 7) {
      if (q & 1) {
        GATHER_TAP(q + 2, rxB);
      } else {
        GATHER_TAP(q + 2, rxA);
      }
    }

    __syncthreads();
#pragma unroll
    for (int c32 = 0; c32 < 2; c32++) {
      int kb = q * 256 + ks * 64 + c32 * 32;
      bf16x8 a0 = *(const bf16x8*)(wAr0 + kb);
      bf16x8 a1 = *(const bf16x8*)(wAr1 + kb);
      const u16* sr = &scolT[q & 1][lane15 * 72 + c32 * 32 + quad * 8];
      bf16x8 b0 = *(const bf16x8*)(sr);
      bf16x8 b1 = *(const bf16x8*)(sr + 16 * 72);
      bf16x8 b2 = *(const bf16x8*)(sr + 32 * 72);
      bf16x8 b3 = *(const bf16x8*)(sr + 48 * 72);
      acc[0] = __builtin_amdgcn_mfma_f32_16x16x32_bf16(a0, b0, acc[0], 0, 0, 0);
      acc[1] = __builtin_amdgcn_mfma_f32_16x16x32_bf16(a0, b1, acc[1], 0, 0, 0);
      acc[2] = __builtin_amdgcn_mfma_f32_16x16x32_bf16(a0, b2, acc[2], 0, 0, 0);
      acc[3] = __builtin_amdgcn_mfma_f32_16x16x32_bf16(a0, b3, acc[3], 0, 0, 0);
      acc[4] = __builtin_amdgcn_mfma_f32_16x16x32_bf16(a1, b0, acc[4], 0, 0, 0);
      acc[5] = __builtin_amdgcn_mfma_f32_16x16x32_bf16(a1, b1, acc[5], 0, 0, 0);
      acc[6] = __builtin_amdgcn_mfma_f32_16x16x32_bf16(a1, b2, acc[6], 0, 0, 0);
      acc[7] = __builtin_amdgcn_mfma_f32_16x16x32_bf16(a1, b3, acc[7], 0, 0, 0);
    }
  }
#undef GATHER_TAP

#pragma unroll
  for (int tr = 0; tr < 2; tr++)
#pragma unroll
    for (int pc = 0; pc < 4; pc++) {
      f32x4 a = acc[tr * 4 + pc];
      int ob = wave * 32 + tr * 16 + quad * 4;
#pragma unroll
      for (int i = 0; i < 4; i++)
        atomicAdd(&out1[((b * COUTC + ob + i) * HH + h) * WW + pc * 16 + lane15], a[i]);
    }
}

// ---------------- BN stats: single-pass split reduction (sum + sumsq).
template <int PLANEF4, int NCHUNK>
__global__ __launch_bounds__(256) void bn_part(const float* __restrict__ src,
                                               float* __restrict__ psum,
                                               float* __restrict__ pssq) {
  int c = blockIdx.x, chunk = blockIdx.y, t = threadIdx.x;
  constexpr int PER = (BB * PLANEF4) / NCHUNK;
  float s = 0.f, s2 = 0.f;
#pragma unroll
  for (int i = 0; i < PER / 256; i++) {
    int f = chunk * PER + i * 256 + t;
    int b = f / PLANEF4;
    int sp = f - b * PLANEF4;
    const float4 v = *(const float4*)&src[((size_t)(b * COUTC + c) * PLANEF4 + sp) * 4];
    s += v.x + v.y + v.z + v.w;
    s2 += v.x * v.x + v.y * v.y + v.z * v.z + v.w * v.w;
  }
#pragma unroll
  for (int off = 32; off > 0; off >>= 1) {
    s += __shfl_down(s, off);
    s2 += __shfl_down(s2, off);
  }
  __shared__ float rs[4], rq[4];
  int wv = t >> 6;
  if ((t & 63) == 0) { rs[wv] = s; rq[wv] = s2; }
  __syncthreads();
  if (t == 0) {
    psum[c * NCHUNK + chunk] = rs[0] + rs[1] + rs[2] + rs[3];
    pssq[c * NCHUNK + chunk] = rq[0] + rq[1] + rq[2] + rq[3];
  }
}

// finalize: block-per-channel (bn1 only)
__global__ __launch_bounds__(256) void bn_fin(const float* __restrict__ psum,
                                              const float* __restrict__ pssq,
                                              const float* __restrict__ g,
                                              const float* __restrict__ bt,
                                              float* __restrict__ scale,
                                              float* __restrict__ shift,
                                              int nchunk, float invN) {
  int c = blockIdx.x, t = threadIdx.x;
  float S = 0.f, Q = 0.f;
  for (int i = t; i < nchunk; i += 256) {
    S += psum[c * nchunk + i];
    Q += pssq[c * nchunk + i];
  }
#pragma unroll
  for (int off = 32; off > 0; off >>= 1) {
    S += __shfl_down(S, off);
    Q += __shfl_down(Q, off);
  }
  __shared__ float rs[4], rq[4];
  int wv = t >> 6;
  if ((t & 63) == 0) { rs[wv] = S; rq[wv] = Q; }
  __syncthreads();
  if (t == 0) {
    S = rs[0] + rs[1] + rs[2] + rs[3];
    Q = rq[0] + rq[1] + rq[2] + rq[3];
    float mu = S * invN;
    float var = Q * invN - mu * mu;
    float sc = g[c] * rsqrtf(var + 1e-5f);
    scale[c] = sc;
    shift[c] = bt[c] - mu * sc;
  }
}

// ---------------- K4a: bn1+relu apply, bf16 convert, channel-last transpose.
__global__ __launch_bounds__(256) void k4a(const float* __restrict__ out1,
                                           const float* __restrict__ s1,
                                           const float* __restrict__ sh1,
                                           u16* __restrict__ yT) {
  int m = blockIdx.x, b = blockIdx.y;
  __shared__ __align__(16) u16 T2[64 * 136];
  int t = threadIdx.x;
  for (int e = t; e < 2048; e += 256) {
    int w4 = e & 15, c = e >> 4;
    float4 r = *(const float4*)&out1[((b * COUTC + c) * HH + m) * WW + w4 * 4];
    float sc = s1[c], sh = sh1[c];
    T2[(w4 * 4 + 0) * 136 + c] = f2bf(fmaxf(fmaf(r.x, sc, sh), 0.f));
    T2[(w4 * 4 + 1) * 136 + c] = f2bf(fmaxf(fmaf(r.y, sc, sh), 0.f));
    T2[(w4 * 4 + 2) * 136 + c] = f2bf(fmaxf(fmaf(r.z, sc, sh), 0.f));
    T2[(w4 * 4 + 3) * 136 + c] = f2bf(fmaxf(fmaf(r.w, sc, sh), 0.f));
  }
  __syncthreads();
  for (int e = t; e < 1024; e += 256) {
    int g2 = e * 8;
    int w = g2 >> 7, i = g2 & 127;
    *(bf16x8*)&yT[((size_t)(b * 64 + m) * 64 + w) * 128 + i] =
        *(const bf16x8*)&T2[w * 136 + i];
  }
}

// ---------------- K4m: transposed conv as bf16 MFMA GEMM + fused bn2 partials.
__global__ __launch_bounds__(256) void k4m(const u16* __restrict__ yT,
                                           const u16* __restrict__ Apk,
                                           float* __restrict__ out2,
                                           float* __restrict__ psum2,
                                           float* __restrict__ pssq2) {
  int oh = blockIdx.x, b = blockIdx.y;
  int a = oh >> 1, p = oh & 1;
  __shared__ __align__(16) u16 T[2][66 * 136];
  int t = threadIdx.x;
  int wave = t >> 6, lane15 = t & 15, quad = (t >> 4) & 3;

  for (int e = t; e < 512; e += 256) {
    int ky = e >> 8;
    int rem = e & 255;
    int colp = (rem >> 7) * 65;
    int i = rem & 127;
    T[ky][colp * 136 + i] = 0;
  }
#pragma unroll
  for (int ky = 0; ky < 2; ky++) {
    int r = a + p + ky - 1;
    bool ok = ((unsigned)r < 64u);
    const u16* src = yT + ((size_t)(b * 64 + r) * 64) * 128;
#pragma unroll
    for (int it = 0; it < 4; it++) {
      int g2 = (it * 256 + t) * 8;
      int col = g2 >> 7, i = g2 & 127;
      bf16x8 v = (bf16x8){0, 0, 0, 0, 0, 0, 0, 0};
      if (ok) v = *(const bf16x8*)(src + g2);
      *(bf16x8*)&T[ky][(col + 1) * 136 + i] = v;
    }
  }
  __syncthreads();

  f32x4 acc[2][2][4];  // [q][tr][pc]
#pragma unroll
  for (int q = 0; q < 2; q++)
#pragma unroll
    for (int tr = 0; tr < 2; tr++)
#pragma unroll
      for (int pc = 0; pc < 4; pc++) acc[q][tr][pc] = (f32x4){0.f, 0.f, 0.f, 0.f};

  int row0 = wave * 32 + lane15;
  const u16* A0 = Apk + ((size_t)(p * 2 + 0) * 128) * 512;
  const u16* A1 = Apk + ((size_t)(p * 2 + 1) * 128) * 512;

#pragma unroll
  for (int ky = 0; ky < 2; ky++)
#pragma unroll
    for (int kx = 0; kx < 2; kx++)
#pragma unroll
      for (int c4 = 0; c4 < 4; c4++) {
        int kb = (ky * 2 + kx) * 128 + c4 * 32 + quad * 8;
        bf16x8 a00 = *(const bf16x8*)(A0 + (size_t)row0 * 512 + kb);
        bf16x8 a01 = *(const bf16x8*)(A0 + (size_t)(row0 + 16) * 512 + kb);
        bf16x8 a10 = *(const bf16x8*)(A1 + (size_t)row0 * 512 + kb);
        bf16x8 a11 = *(const bf16x8*)(A1 + (size_t)(row0 + 16) * 512 + kb);
        const u16* tb = &T[ky][(lane15 + kx) * 136 + c4 * 32 + quad * 8];
#pragma unroll
        for (int pc = 0; pc < 4; pc++) {
          bf16x8 b0 = *(const bf16x8*)(tb + (pc * 16) * 136);
          bf16x8 b1 = *(const bf16x8*)(tb + (pc * 16 + 1) * 136);
          acc[0][0][pc] = __builtin_amdgcn_mfma_f32_16x16x32_bf16(a00, b0, acc[0][0][pc], 0, 0, 0);
          acc[0][1][pc] = __builtin_amdgcn_mfma_f32_16x16x32_bf16(a01, b0, acc[0][1][pc], 0, 0, 0);
          acc[1][0][pc] = __builtin_amdgcn_mfma_f32_16x16x32_bf16(a10, b1, acc[1][0][pc], 0, 0, 0);
          acc[1][1][pc] = __builtin_amdgcn_mfma_f32_16x16x32_bf16(a11, b1, acc[1][1][pc], 0, 0, 0);
        }
      }

#pragma unroll
  for (int tr = 0; tr < 2; tr++) {
    int o0 = wave * 32 + tr * 16 + quad * 4;
#pragma unroll
    for (int pc = 0; pc < 4; pc++) {
      f32x4 v0 = acc[0][tr][pc];
      f32x4 v1 = acc[1][tr][pc];
      int cw = pc * 32 + 2 * lane15;
#pragma unroll
      for (int i = 0; i < 4; i++) {
        float2 w2;
        w2.x = v0[i];
        w2.y = v1[i];
        *(float2*)&out2[(((size_t)b * COUTC + o0 + i) * OHH + oh) * OWW + cw] = w2;
      }
    }
  }

  int blk = b * 128 + oh;
#pragma unroll
  for (int tr = 0; tr < 2; tr++)
#pragma unroll
    for (int i = 0; i < 4; i++) {
      float s = 0.f, s2 = 0.f;
#pragma unroll
      for (int q = 0; q < 2; q++)
#pragma unroll
        for (int pc = 0; pc < 4; pc++) {
          float v = acc[q][tr][pc][i];
          s += v;
          s2 += v * v;
        }
#pragma unroll
      for (int off = 1; off < 16; off <<= 1) {
        s += __shfl_xor(s, off);
        s2 += __shfl_xor(s2, off);
      }
      if (lane15 == 0) {
        int c = wave * 32 + tr * 16 + quad * 4 + i;
        psum2[c * 512 + blk] = s;
        pssq2[c * 512 + blk] = s2;
      }
    }
}

// ---------------- K6f: fused bn2 finalize + apply (f32 out), float4-vectorized.
__global__ __launch_bounds__(256) void k6f(const float* __restrict__ out2,
                                           const float* __restrict__ psum2,
                                           const float* __restrict__ pssq2,
                                           const float* __restrict__ g,
                                           const float* __restrict__ bt,
                                           float* __restrict__ outp) {
  int blk = blockIdx.x, t = threadIdx.x;
  int c = (blk >> 2) & 127;

  float S = psum2[c * 512 + t] + psum2[c * 512 + 256 + t];
  float Q = pssq2[c * 512 + t] + pssq2[c * 512 + 256 + t];
#pragma unroll
  for (int off = 32; off > 0; off >>= 1) {
    S += __shfl_down(S, off);
    Q += __shfl_down(Q, off);
  }
  __shared__ float rs[4], rq[4], sSC, sSH;
  int wv = t >> 6;
  if ((t & 63) == 0) { rs[wv] = S; rq[wv] = Q; }
  __syncthreads();
  if (t == 0) {
    S = rs[0] + rs[1] + rs[2] + rs[3];
    Q = rq[0] + rq[1] + rq[2] + rq[3];
    float mu = S / 65536.f;
    float var = Q / 65536.f - mu * mu;
    float sc = g[c] * rsqrtf(var + 1e-5f);
    sSC = sc;
    sSH = bt[c] - mu * sc;
  }
  __syncthreads();
  float sc = sSC, sh = sSH;
  int base = blk * 1024;
#pragma unroll
  for (int i = 0; i < 4; i++) {
    int f4 = base + i * 256 + t;
    float4 v = *(const float4*)&out2[f4 * 4];
    float4 o;
    o.x = fmaxf(fmaf(v.x, sc, sh), 0.f);
    o.y = fmaxf(fmaf(v.y, sc, sh), 0.f);
    o.z = fmaxf(fmaf(v.z, sc, sh), 0.f);
    o.w = fmaxf(fmaf(v.w, sc, sh), 0.f);
    *(float4*)&outp[f4 * 4] = o;
  }
}

// ---------------- launch
extern "C" void kernel_launch(void* const* d_in, const int* in_sizes, int n_in,
                              void* d_out, int out_size, void* d_ws, size_t ws_size,
                              hipStream_t stream) {
  const float* x     = (const float*)d_in[0];
  const float* off_w = (const float*)d_in[1];
  const float* off_b = (const float*)d_in[2];
  const float* dcn_w = (const float*)d_in[3];
  const float* dcn_b = (const float*)d_in[4];
  const float* bn1_g = (const float*)d_in[5];
  const float* bn1_b = (const float*)d_in[6];
  const float* up_w  = (const float*)d_in[7];
  const float* bn2_g = (const float*)d_in[8];
  const float* bn2_b = (const float*)d_in[9];

  float* ws = (float*)d_ws;
  float* pyg  = ws;                              // 147456
  float* pxg  = pyg + BB * 9 * HH * WW;          // 147456
  float* mg   = pxg + BB * 9 * HH * WW;          // 147456
  float* out1 = mg + BB * 9 * HH * WW;           // 2097152
  float* scale1 = out1 + BB * COUTC * HH * WW;   // 128
  float* shift1 = scale1 + 128;                  // 128
  float* out2 = shift1 + 128;                    // 8388608
  float* scale2 = out2 + BB * COUTC * OHH * OWW; // 128 (unused)
  float* shift2 = scale2 + 128;                  // 128 (unused)
  float* w_t = shift2 + 128;                     // 294912 floats reserved
  float* wt4 = w_t + COUTC * CINC * 9;           // 262144 floats (Apk uses as u16)
  float* part2 = wt4 + 4 * COUTC * COUTC * 4;    // scratch
  u16* wA = (u16*)w_t;
  u16* W2 = (u16*)(w_t + 147456);                // frag-major hi/lo 147456 bf16
  u16* Apk = (u16*)wt4;
  u16* xTh = (u16*)out2;
  u16* xTl = (u16*)(out2 + 2097152);
  float* psum = part2;                           // 128*512
  float* pssq = part2 + 65536;
  u16* yT = (u16*)(part2 + 131072);              // bf16 4MB
  float* part1 = part2 + 131072 + 2097152;       // 2.1M floats

  const int N4 = BB * COUTC * OHH * OWW;  // 8388608
  const int N2 = BB * COUTC * HH * WW;    // 2097152
  const int N1 = BB * 27 * HH * WW;       // 442368

  // merged preprocessing: k2t transpose (1024 blocks) + weight prep + bias init
  int k0blocks = 1024 + (704512 + N2 + 255) / 256;
  k0<<<k0blocks, 256, 0, stream>>>(x, dcn_w, off_w, up_w, dcn_b,
                                   xTh, xTl, wA, W2, Apk, out1);
  // offset conv: LDS row-staged, TA-coalesced
  k1m<<<dim3(64, BB, 4), 256, 0, stream>>>(xTh, xTl, W2, part1);
  k1r<<<(N1 + 255) / 256, 256, 0, stream>>>(part1, off_b, pyg, pxg, mg);
  // deformable conv: 2-deep gather pipeline, consecutive-lane coalesced
  k2m<<<dim3(4, 64, 4), 256, 0, stream>>>(xTh, wA, pyg, pxg, mg, out1);
  bn_part<1024, 8><<<dim3(COUTC, 8), 256, 0, stream>>>(out1, psum, pssq);
  bn_fin<<<COUTC, 256, 0, stream>>>(psum, pssq, bn1_g, bn1_b, scale1, shift1, 8,
                                    1.f / 16384.f);
  k4a<<<dim3(64, 4), 256, 0, stream>>>(out1, scale1, shift1, yT);
  k4m<<<dim3(128, 4), 256, 0, stream>>>(yT, Apk, out2, psum, pssq);
  k6f<<<N4 / 4096, 256, 0, stream>>>(out2, psum, pssq, bn2_g, bn2_b, (float*)d_out);
}